// Round 10
// baseline (553.859 us; speedup 1.0000x reference)
//
#include <hip/hip_runtime.h>
#include <stdint.h>

#define BB 4
#define LL 2048
#define DMM 256
#define HH 8
#define EE 32
#define NLL 3
#define ITR 16
#define UU 40
#define KC 16                 // split-K chunks
#define KCH 128               // keys per chunk
#define ROWS (BB*LL)          // 8192
#define NELEM (ROWS*DMM)      // 2097152
#define OTR 16                // oproj_tail rows per block (16 -> 512 blocks = 2/CU)

typedef __attribute__((ext_vector_type(8))) short short8;
typedef __attribute__((ext_vector_type(4))) float f32x4;
typedef unsigned long long u64;

#define GLDS16(g, l)                                                        \
  __builtin_amdgcn_global_load_lds(                                         \
      (const __attribute__((address_space(1))) uint32_t*)(g),               \
      (__attribute__((address_space(3))) uint32_t*)(l), 16, 0, 0)

// ---------------- bf16 bit helpers (RNE) ----------------
__device__ __forceinline__ float bfbits(unsigned short u) {
  return __uint_as_float(((uint32_t)u) << 16);
}
__device__ __forceinline__ unsigned short f2b(float f) {
  uint32_t u = __float_as_uint(f);
  uint32_t r = (u + 0x7FFFu + ((u >> 16) & 1u)) >> 16;
  return (unsigned short)r;
}

// ---------------- threefry2x32 (exact JAX semantics) ----------------
__host__ __device__ inline void threefry2x32(uint32_t k0, uint32_t k1,
                                             uint32_t x0, uint32_t x1,
                                             uint32_t* o0, uint32_t* o1) {
  uint32_t ks2 = k0 ^ k1 ^ 0x1BD11BDAu;
  x0 += k0; x1 += k1;
#define TFR(r) { x0 += x1; x1 = (x1 << (r)) | (x1 >> (32 - (r))); x1 ^= x0; }
  TFR(13) TFR(15) TFR(26) TFR(6)
  x0 += k1;  x1 += ks2 + 1u;
  TFR(17) TFR(29) TFR(16) TFR(24)
  x0 += ks2; x1 += k0 + 2u;
  TFR(13) TFR(15) TFR(26) TFR(6)
  x0 += k0;  x1 += k1 + 3u;
  TFR(17) TFR(29) TFR(16) TFR(24)
  x0 += k1;  x1 += ks2 + 4u;
  TFR(13) TFR(15) TFR(26) TFR(6)
  x0 += ks2; x1 += k0 + 5u;
#undef TFR
  *o0 = x0; *o1 = x1;
}

__device__ __forceinline__ float wave_sum(float v) {
#pragma unroll
  for (int off = 32; off > 0; off >>= 1) v += __shfl_xor(v, off);
  return v;
}

// ---------------- mega convert (+hi/lo splits, +dcw repack, +vmp zero, +cheap inline probe) -
struct CvtArgs {
  const void* src[23];
  float* dstF[23];
  unsigned short* dstB[23];
  unsigned short* dstL[23];
  int n[23];
  int blkStart[24];
  unsigned short* dcwT;
  float* vmpZ;     // zero BB*DMM floats
  int* flagOut;    // published dtype flag
};
__global__ __launch_bounds__(256) void mega_cvt(CvtArgs a) {
  // ---- inline dtype probe: 512 shorts (2/thread). bf16 data -> cnt~0; f32 data -> cnt~228.
  __shared__ int cnt;
  if (threadIdx.x == 0) cnt = 0;
  __syncthreads();
  {
    const unsigned short* u = (const unsigned short*)a.src[0];
    int bad = 0;
#pragma unroll
    for (int rep = 0; rep < 2; ++rep) {
      float v = bfbits(u[threadIdx.x + 256 * rep]);
      float av = fabsf(v);
      bool ok = (v == 0.0f) || (av > 1e-4f && av < 100.0f);
      if (!ok) bad++;
    }
    if (bad) atomicAdd(&cnt, bad);
  }
  __syncthreads();
  int isf32 = (cnt > 25) ? 1 : 0;

  int bid = blockIdx.x;
  if (bid == a.blkStart[23]) {
    for (int t = threadIdx.x; t < BB * DMM; t += 256) a.vmpZ[t] = 0.f;
    if (threadIdx.x == 0) *a.flagOut = isf32;
    return;
  }
  int i = 0;
  while (i < 22 && bid >= a.blkStart[i + 1]) ++i;
  int e = (bid - a.blkStart[i]) * 256 + (int)threadIdx.x;
  if (e >= a.n[i]) return;
  float v; unsigned short rw;
  if (isf32) { v = ((const float*)a.src[i])[e]; rw = f2b(v); }
  else       { rw = ((const unsigned short*)a.src[i])[e]; v = bfbits(rw); }
  a.dstF[i][e] = v;
  if (a.dstB[i]) a.dstB[i][e] = rw;
  if (a.dstL[i]) a.dstL[i][e] = f2b(v - bfbits(rw));
  if (i == 17) {  // dcw: [ly][n][k][t] -> [ly][t][n][k] bf16
    int ly = e / 196608;
    int r = e - ly * 196608;
    int n = r / 768;
    int rem = r - n * 768;
    int k = rem / 3, t = rem - k * 3;
    a.dcwT[ly * 196608 + t * 65536 + n * 256 + k] = rw;
  }
}

// ---------------- QKV MFMA GEMM: z=0:Q 1:K (hi/lo 2-pass, f32 out) 2:V (bf16 out + vmean) --
// (round-0 proven version: BK=32, [128][32]/[64][32] LDS)
struct QKVArgs {
  const unsigned short* W[3];
  const float* bias[3];
  float* Cq;
  float* Ck;
  unsigned short* Cv;
  float* vmp;
};
__global__ __launch_bounds__(256) void gemm_qkv(const unsigned short* __restrict__ Ahi,
                                                const unsigned short* __restrict__ Alo,
                                                QKVArgs qa) {
  __shared__ __attribute__((aligned(16))) unsigned short AsH[128][32];
  __shared__ __attribute__((aligned(16))) unsigned short AsL[128][32];
  __shared__ __attribute__((aligned(16))) unsigned short Bs[64][32];
  int z = blockIdx.z;
  const unsigned short* W = qa.W[z];
  const float* bias = qa.bias[z];
  bool twoPass = (z < 2);
  int bm = blockIdx.x * 128, bn = blockIdx.y * 64;
  int tid = threadIdx.x;
  int wv = tid >> 6, lane = tid & 63;
  int wm = wv >> 1, wn = wv & 1;
  int l15 = lane & 15, quad = lane >> 4;
  int lrow = lane >> 2, lseg = lane & 3;
  f32x4 acc[4][2];
#pragma unroll
  for (int i = 0; i < 4; ++i)
#pragma unroll
    for (int j = 0; j < 2; ++j) acc[i][j] = (f32x4){0.f, 0.f, 0.f, 0.f};
  for (int k0 = 0; k0 < 256; k0 += 32) {
    __syncthreads();
#pragma unroll
    for (int s = 0; s < 2; ++s) {
      int brow = (wv + s * 4) * 16;
      size_t goff = (size_t)(bm + brow + lrow) * 256 + k0 + lseg * 8;
      GLDS16(Ahi + goff, &AsH[brow][0]);
      if (twoPass) GLDS16(Alo + goff, &AsL[brow][0]);
    }
    {
      int brow = wv * 16;
      GLDS16(W + (size_t)(bn + brow + lrow) * 256 + k0 + lseg * 8, &Bs[brow][0]);
    }
    __syncthreads();
    short8 ah[4], bfr[2];
#pragma unroll
    for (int mt = 0; mt < 4; ++mt)
      ah[mt] = *(const short8*)(&AsH[wm * 64 + mt * 16 + l15][quad * 8]);
#pragma unroll
    for (int nt = 0; nt < 2; ++nt)
      bfr[nt] = *(const short8*)(&Bs[wn * 32 + nt * 16 + l15][quad * 8]);
#pragma unroll
    for (int mt = 0; mt < 4; ++mt)
#pragma unroll
      for (int nt = 0; nt < 2; ++nt)
        acc[mt][nt] = __builtin_amdgcn_mfma_f32_16x16x32_bf16(ah[mt], bfr[nt],
                                                              acc[mt][nt], 0, 0, 0);
    if (twoPass) {
      short8 al[4];
#pragma unroll
      for (int mt = 0; mt < 4; ++mt)
        al[mt] = *(const short8*)(&AsL[wm * 64 + mt * 16 + l15][quad * 8]);
#pragma unroll
      for (int mt = 0; mt < 4; ++mt)
#pragma unroll
        for (int nt = 0; nt < 2; ++nt)
          acc[mt][nt] = __builtin_amdgcn_mfma_f32_16x16x32_bf16(al[mt], bfr[nt],
                                                                acc[mt][nt], 0, 0, 0);
    }
  }
  float* C = (z == 0) ? qa.Cq : qa.Ck;
#pragma unroll
  for (int nt = 0; nt < 2; ++nt) {
    int n = bn + wn * 32 + nt * 16 + l15;
    float bv = bias[n];
    float csum = 0.f;
#pragma unroll
    for (int mt = 0; mt < 4; ++mt)
#pragma unroll
      for (int r = 0; r < 4; ++r) {
        int m = bm + wm * 64 + mt * 16 + quad * 4 + r;
        float val = acc[mt][nt][r] + bv;
        if (z < 2) {
          C[(size_t)m * 256 + n] = val;
        } else {
          qa.Cv[(size_t)m * 256 + n] = f2b(val);
          csum += val;
        }
      }
    if (z == 2) {
      csum += __shfl_xor(csum, 16);
      csum += __shfl_xor(csum, 32);
      if (quad == 0) {
        int b = bm >> 11;
        atomicAdd(&qa.vmp[b * DMM + n], csum);
      }
    }
  }
}

// ---------------- FUSED O-proj GEMM (OTR=16 rows x 256 cols) + LN1/FFN/LN2 tail -----------
// R9 structure with rows/block halved: grid 512 = 2 blocks/CU so one block's tail overlaps
// the other's GEMM (R9 profile: 1 block/CU, Occ 9%, everything idle -> latency-bound).
// Numerics verbatim: same k0 MFMA chain per (row,col), same ctx-merge math, same tail body.
__global__ __launch_bounds__(256) void oproj_tail(const float* __restrict__ vmp,
                                                  const unsigned char* __restrict__ mapb,
                                                  const float* __restrict__ pm,
                                                  const float* __restrict__ pl,
                                                  const float* __restrict__ po,
                                                  const unsigned short* __restrict__ W,
                                                  const float* __restrict__ bias,
                                                  const float* __restrict__ X,
                                                  const float* __restrict__ g1,
                                                  const float* __restrict__ b1ln,
                                                  const float* __restrict__ w1,
                                                  const float* __restrict__ b1,
                                                  const float* __restrict__ w2,
                                                  const float* __restrict__ b2,
                                                  const float* __restrict__ g2,
                                                  const float* __restrict__ b2ln,
                                                  float* __restrict__ Out,
                                                  unsigned short* __restrict__ OutB,
                                                  unsigned short* __restrict__ OutL,
                                                  const float* __restrict__ fing,
                                                  const float* __restrict__ finb,
                                                  void* __restrict__ finOut,
                                                  const int* __restrict__ flag,
                                                  float* __restrict__ stpZ,
                                                  float* __restrict__ stp2Z) {
  __shared__ __attribute__((aligned(16))) unsigned short As[OTR][32];
  __shared__ __attribute__((aligned(16))) unsigned short Bs[256][32];
  __shared__ float Cs[OTR][DMM];
  __shared__ float xs[4][DMM];
  int tid = threadIdx.x;
  if (blockIdx.x == 0) {
    stpZ[tid] = 0.f;
    stp2Z[tid] = 0.f;
  }
  int bm = blockIdx.x * OTR;
  int wv = tid >> 6, lane = tid & 63;
  int l15 = lane & 15, quad = lane >> 4;
  int b = bm >> 11, l0 = bm & 2047;
  const float invL = 1.0f / (float)LL;
  f32x4 acc[4];
#pragma unroll
  for (int j = 0; j < 4; ++j) acc[j] = (f32x4){0.f, 0.f, 0.f, 0.f};
  for (int k0 = 0; k0 < 256; k0 += 32) {
    int h = k0 >> 5;
    int bh = b * HH + h;
    __syncthreads();
    if (tid < OTR * 4) {  // ctx A-tile: OTR rows x 4 col-groups (verbatim merge math)
      int arow = tid >> 2, adg = tid & 3;
      int l = l0 + arow;
      int q = (int)mapb[bh * 2048 + l];
      unsigned short outv[8];
      if (q) {
        size_t base = ((size_t)bh * UU + (q - 1)) * KC;
        float Mx = -1e30f;
#pragma unroll
        for (int kc = 0; kc < KC; ++kc) Mx = fmaxf(Mx, pm[base + kc]);
        float Ls = 0.f;
        float sc[KC];
#pragma unroll
        for (int kc = 0; kc < KC; ++kc) {
          sc[kc] = expf(pm[base + kc] - Mx);
          Ls += pl[base + kc] * sc[kc];
        }
        float inv = 1.0f / Ls;
#pragma unroll
        for (int j = 0; j < 8; ++j) {
          int dl = adg * 8 + j;
          float o = 0.f;
#pragma unroll
          for (int kc = 0; kc < KC; ++kc) o += po[(base + kc) * 32 + dl] * sc[kc];
          outv[j] = f2b(o * inv);
        }
      } else {
        const float* vp = vmp + b * DMM + h * EE + adg * 8;
#pragma unroll
        for (int j = 0; j < 8; ++j) outv[j] = f2b(vp[j] * invL);
      }
      *(uint4*)(&As[arow][adg * 8]) = *(const uint4*)outv;
    }
    {  // stage all 256 B-rows (wave-uniform GLDS16 pattern, 4 rounds x 4 waves x 16 rows)
      int lrw = lane >> 2, lsg = lane & 3;
#pragma unroll
      for (int s = 0; s < 4; ++s) {
        int brow = s * 64 + wv * 16;
        GLDS16(W + (size_t)(brow + lrw) * 256 + k0 + lsg * 8, &Bs[brow][0]);
      }
    }
    __syncthreads();
    short8 af, bfr[4];
    af = *(const short8*)(&As[l15][quad * 8]);
#pragma unroll
    for (int nt = 0; nt < 4; ++nt)
      bfr[nt] = *(const short8*)(&Bs[wv * 64 + nt * 16 + l15][quad * 8]);
#pragma unroll
    for (int nt = 0; nt < 4; ++nt)
      acc[nt] = __builtin_amdgcn_mfma_f32_16x16x32_bf16(af, bfr[nt], acc[nt], 0, 0, 0);
  }
  // epilogue -> LDS (replaces tmp)
#pragma unroll
  for (int nt = 0; nt < 4; ++nt) {
    int n = wv * 64 + nt * 16 + l15;
    float bv = bias[n];
#pragma unroll
    for (int r = 0; r < 4; ++r)
      Cs[quad * 4 + r][n] = acc[nt][r] + bv;
  }
  __syncthreads();
  // ---- enc_tail body, verbatim, OTR/4 rows per wave ----
  for (int rr = 0; rr < OTR / 4; ++rr) {
    int lr = wv * (OTR / 4) + rr;
    size_t row = (size_t)bm + lr;
    const float* xr = X + row * DMM;
    const float* tr = Cs[lr];
    float v[4];
#pragma unroll
    for (int i = 0; i < 4; ++i) v[i] = xr[lane + 64 * i] + tr[lane + 64 * i];
    float s = wave_sum(v[0] + v[1] + v[2] + v[3]);
    float m = s * (1.0f / (float)DMM);
    float sq = 0.f;
#pragma unroll
    for (int i = 0; i < 4; ++i) { float d = v[i] - m; sq += d * d; }
    sq = wave_sum(sq);
    float rstd = rsqrtf(sq * (1.0f / (float)DMM) + 1e-5f);
    float xv[4];
#pragma unroll
    for (int i = 0; i < 4; ++i) {
      int d = lane + 64 * i;
      xv[i] = (v[i] - m) * rstd * g1[d] + b1ln[d];
      xs[wv][d] = xv[i];
    }
    __syncthreads();
    int f = lane & 15, qtr = lane >> 4;
    const float* w1p = w1 + f * DMM + qtr * 64;
    const float* xq = &xs[wv][qtr * 64];
    float pacc = 0.f;
#pragma unroll 8
    for (int d = 0; d < 64; ++d) pacc += xq[d] * w1p[d];
    pacc += __shfl_xor(pacc, 16);
    pacc += __shfl_xor(pacc, 32);
    float y1 = fmaxf(pacc + b1[f], 0.0f);
    float y1v[16];
#pragma unroll
    for (int ff = 0; ff < 16; ++ff) y1v[ff] = __shfl(y1, ff);
#pragma unroll
    for (int i = 0; i < 4; ++i) {
      int d = lane + 64 * i;
      const float* w2p = w2 + d * ITR;
      float a = b2[d];
#pragma unroll
      for (int ff = 0; ff < 16; ++ff) a += y1v[ff] * w2p[ff];
      v[i] = xv[i] + a;
    }
    s = wave_sum(v[0] + v[1] + v[2] + v[3]);
    m = s * (1.0f / (float)DMM);
    sq = 0.f;
#pragma unroll
    for (int i = 0; i < 4; ++i) { float d = v[i] - m; sq += d * d; }
    sq = wave_sum(sq);
    rstd = rsqrtf(sq * (1.0f / (float)DMM) + 1e-5f);
    float vv[4];
#pragma unroll
    for (int i = 0; i < 4; ++i) {
      int d = lane + 64 * i;
      float val = (v[i] - m) * rstd * g2[d] + b2ln[d];
      vv[i] = val;
      Out[row * DMM + d] = val;
      unsigned short hi = f2b(val);
      OutB[row * DMM + d] = hi;
      OutL[row * DMM + d] = f2b(val - bfbits(hi));
    }
    if (finOut) {
      s = wave_sum(vv[0] + vv[1] + vv[2] + vv[3]);
      m = s * (1.0f / (float)DMM);
      sq = 0.f;
#pragma unroll
      for (int i = 0; i < 4; ++i) { float d = vv[i] - m; sq += d * d; }
      sq = wave_sum(sq);
      rstd = rsqrtf(sq * (1.0f / (float)DMM) + 1e-5f);
      int isf32 = *flag;
#pragma unroll
      for (int i = 0; i < 4; ++i) {
        int d = lane + 64 * i;
        float val = (vv[i] - m) * rstd * fing[d] + finb[d];
        if (isf32) ((float*)finOut)[row * DMM + d] = val;
        else       ((unsigned short*)finOut)[row * DMM + d] = f2b(val);
      }
    }
  }
}

// ---------------- conv GEMM: A window staged once per k0, 3 taps from LDS ----------------
__global__ __launch_bounds__(256) void gemm_conv(const unsigned short* __restrict__ A,
                                                 const unsigned short* __restrict__ W,
                                                 const float* __restrict__ bias,
                                                 float* __restrict__ C,
                                                 float* __restrict__ stp,
                                                 float* __restrict__ stp2) {
  __shared__ __attribute__((aligned(16))) unsigned short As[80][32];
  __shared__ __attribute__((aligned(16))) unsigned short Bs[192][32];
  int bm = blockIdx.x * 64, bn = blockIdx.y * 64;
  int tid = threadIdx.x;
  int wv = tid >> 6, lane = tid & 63;
  int wm = wv >> 1, wn = wv & 1;
  int l15 = lane & 15, quad = lane >> 4;
  int lrow = lane >> 2, lseg = lane & 3;
  int bbase = bm & ~2047, l0 = bm & 2047;
  f32x4 acc[2][2];
#pragma unroll
  for (int i = 0; i < 2; ++i)
#pragma unroll
    for (int j = 0; j < 2; ++j) acc[i][j] = (f32x4){0.f, 0.f, 0.f, 0.f};
  for (int k0 = 0; k0 < 256; k0 += 32) {
    __syncthreads();
    for (int c = wv; c < 5; c += 4) {
      int i0 = c * 16;
      int l = (l0 - 1 + i0 + lrow + 2048) & 2047;
      GLDS16(A + (size_t)(bbase | l) * 256 + k0 + lseg * 8, &As[i0][0]);
    }
    for (int c = wv; c < 12; c += 4) {
      int i0 = c * 16;
      int tap = c >> 2, brow = (c & 3) * 16;
      GLDS16(W + (size_t)tap * 65536 + (size_t)(bn + brow + lrow) * 256 + k0 + lseg * 8,
             &Bs[i0][0]);
    }
    __syncthreads();
#pragma unroll
    for (int tap = 0; tap < 3; ++tap) {
      short8 af[2], bfr[2];
#pragma unroll
      for (int mt = 0; mt < 2; ++mt)
        af[mt] = *(const short8*)(&As[wm * 32 + mt * 16 + l15 + tap][quad * 8]);
#pragma unroll
      for (int nt = 0; nt < 2; ++nt)
        bfr[nt] = *(const short8*)(&Bs[tap * 64 + wn * 32 + nt * 16 + l15][quad * 8]);
#pragma unroll
      for (int mt = 0; mt < 2; ++mt)
#pragma unroll
        for (int nt = 0; nt < 2; ++nt)
          acc[mt][nt] = __builtin_amdgcn_mfma_f32_16x16x32_bf16(af[mt], bfr[nt],
                                                                acc[mt][nt], 0, 0, 0);
    }
  }
#pragma unroll
  for (int nt = 0; nt < 2; ++nt) {
    int n = bn + wn * 32 + nt * 16 + l15;
    float bv = bias[n];
    float s = 0.f, s2 = 0.f;
#pragma unroll
    for (int mt = 0; mt < 2; ++mt)
#pragma unroll
      for (int r = 0; r < 4; ++r) {
        int m = bm + wm * 32 + mt * 16 + quad * 4 + r;
        float val = acc[mt][nt][r] + bv;
        C[(size_t)m * 256 + n] = val;
        s += val;
        s2 += val * val;
      }
    s  += __shfl_xor(s, 16);   s  += __shfl_xor(s, 32);
    s2 += __shfl_xor(s2, 16);  s2 += __shfl_xor(s2, 32);
    if (quad == 0) {
      atomicAdd(&stp[n], s);
      atomicAdd(&stp2[n], s2);
    }
  }
}

// ---------------- M scores: wave per (b,l), inline threefry, XCD-affinity swizzle ----------
__global__ __launch_bounds__(256) void m_kernel3(const float* __restrict__ Q,
                                                 const float* __restrict__ K,
                                                 uint32_t k20, uint32_t k21,
                                                 float* __restrict__ M) {
  int bid = blockIdx.x;
  int blk = (bid & 7) * 256 + (bid >> 3);   // XCD-affinity remap (pure perf, no semantics)
  int b = blk >> 9, lc = blk & 511;
  int wave = threadIdx.x >> 6, lane = threadIdx.x & 63;
  int l = lc * 4 + wave;
  int myidx = 0;
  if (lane < UU) {
    int j = l * UU + lane;
    uint32_t o0, o1;
    const int half = (LL * UU) / 2;  // 40960
    if (j < half) {
      threefry2x32(k20, k21, (uint32_t)j, (uint32_t)(j + half), &o0, &o1);
      myidx = (int)(o0 & (LL - 1));
    } else {
      threefry2x32(k20, k21, (uint32_t)(j - half), (uint32_t)j, &o0, &o1);
      myidx = (int)(o1 & (LL - 1));
    }
  }
  float4 q4 = *(const float4*)(Q + ((size_t)(b * LL + l)) * DMM + lane * 4);
  const float* Kb = K + (size_t)b * LL * DMM;
  float mx = -1e30f, sm = 0.f;
#pragma unroll 8
  for (int u = 0; u < UU; ++u) {
    int kidx = __shfl(myidx, u);
    float4 k4 = *(const float4*)(Kb + (size_t)kidx * DMM + lane * 4);
    float s = q4.x * k4.x + q4.y * k4.y + q4.z * k4.z + q4.w * k4.w;
    s += __shfl_xor(s, 1);
    s += __shfl_xor(s, 2);
    s += __shfl_xor(s, 4);
    mx = fmaxf(mx, s);
    sm += s;
  }
  if ((lane & 7) == 0) {
    int h = lane >> 3;
    M[((size_t)(b * HH + h)) * LL + l] = mx - sm * (1.0f / (float)LL);
  }
}

// ---------------- fused topk + split-K flash attention (R8-proven) ------------------------
__global__ __launch_bounds__(256) void attn_part(const float* __restrict__ Q,
                                                 const float* __restrict__ K,
                                                 const unsigned short* __restrict__ Vbf,
                                                 const float* __restrict__ M,
                                                 unsigned char* __restrict__ mapb,
                                                 float* __restrict__ pm,
                                                 float* __restrict__ pl,
                                                 float* __restrict__ po) {
  __shared__ float Qs[40][32];
  __shared__ unsigned short ps[40][KCH];
  __shared__ unsigned short Vs[KCH][40];
  __shared__ int qrows[40];
  __shared__ unsigned int hist[256];
  __shared__ unsigned int sA[256];
  __shared__ unsigned int sB[256];
  __shared__ unsigned int tbv;
  int kc = blockIdx.x, bh = blockIdx.y;
  int h = bh & 7, b = bh >> 3;
  int tid = threadIdx.x;
  int wv = tid >> 6, lane = tid & 63;

  // ---- independent loads issued first (overlap with radix latency) ----
  {
    int row = tid >> 1, half = tid & 1;
    const unsigned short* vsrc =
        Vbf + (size_t)(b * LL + kc * KCH + row) * DMM + h * EE + half * 16;
    *(uint4*)(&Vs[row][half * 16]) = *(const uint4*)vsrc;
    *(uint4*)(&Vs[row][half * 16 + 8]) = *(const uint4*)(vsrc + 8);
  }
  int kk = tid & (KCH - 1), qh = tid >> 7;  // 2 threads/key, 20 queries each
  float4 kr[8];
  {
    const float4* kp =
        (const float4*)(K + ((size_t)(b * LL + kc * KCH + kk)) * DMM + h * EE);
#pragma unroll
    for (int j = 0; j < 8; ++j) kr[j] = kp[j];
  }

  // ---- exact top-40 radix select on M[bh] (R7-proven rounds) ----
  u64 kreg[8];
#pragma unroll
  for (int r = 0; r < 8; ++r) {
    int l = tid + 256 * r;
    float v = M[(size_t)bh * LL + l];
    uint32_t bits = __float_as_uint(v);
    uint32_t kv = (bits & 0x80000000u) ? ~bits : (bits | 0x80000000u);
    kreg[r] = ((u64)kv << 32) | (uint32_t)(2047 - l);
  }
  u64 prefix = 0;
  int rank = UU;
  for (int round = 0; round < 8; ++round) {
    int shift = 56 - 8 * round;
    u64 maskTop = (round == 0) ? 0ull : (~0ull << (64 - 8 * round));
    hist[tid] = 0;
    __syncthreads();
#pragma unroll
    for (int r = 0; r < 8; ++r) {
      u64 k = kreg[r];
      if ((k & maskTop) == prefix)
        atomicAdd(&hist[(unsigned int)((k >> shift) & 0xFFu)], 1u);
    }
    __syncthreads();
    sA[tid] = hist[tid];
    __syncthreads();
    unsigned int* src = sA;
    unsigned int* dst = sB;
    for (int off = 1; off < 256; off <<= 1) {
      unsigned int v = src[tid] + ((tid + off < 256) ? src[tid + off] : 0u);
      dst[tid] = v;
      __syncthreads();
      unsigned int* tmpp = src; src = dst; dst = tmpp;
    }
    unsigned int Sb = src[tid];
    unsigned int Snext = (tid < 255) ? src[tid + 1] : 0u;
    if (Sb >= (unsigned int)rank && Snext < (unsigned int)rank) tbv = (unsigned int)tid;
    __syncthreads();
    unsigned int tb = tbv;
    unsigned int above = (tb < 255u) ? src[tb + 1] : 0u;
    rank -= (int)above;
    prefix |= ((u64)tb) << shift;
    __syncthreads();
  }
  u64 T = prefix;   // exact 40th-largest key
  // ---- deterministic rank: exclusive prefix over tid of per-thread selected counts ----
  int myCnt = 0;
#pragma unroll
  for (int r = 0; r < 8; ++r) myCnt += (kreg[r] >= T) ? 1 : 0;
  sA[tid] = (unsigned int)myCnt;
  __syncthreads();
  {
    unsigned int* src = sA;
    unsigned int* dst = sB;
    for (int off = 1; off < 256; off <<= 1) {
      unsigned int v = src[tid] + ((tid >= off) ? src[tid - off] : 0u);
      dst[tid] = v;
      __syncthreads();
      unsigned int* tmpp = src; src = dst; dst = tmpp;
    }
    int pos = (int)src[tid] - myCnt;   // exclusive prefix
    bool wmap = (kc == 0);
#pragma unroll
    for (int r = 0; r < 8; ++r) {
      u64 k = kreg[r];
      int l = 2047 - (int)(uint32_t)(k & 0xFFFFFFFFu);
      unsigned char mv = 0;
      if (k >= T) {
        qrows[pos] = l;
        mv = (unsigned char)(pos + 1);
        pos++;
      }
      if (wmap) mapb[bh * 2048 + l] = mv;
    }
  }
  __syncthreads();

  // ---- Q staging for the 40 selected rows ----
  for (int t = tid; t < 40 * 32; t += 256) {
    int q = t >> 5, d = t & 31;
    Qs[q][d] = Q[((size_t)(b * LL + qrows[q])) * DMM + h * EE + d];
  }
  __syncthreads();
  // ---- scores ----
  {
    const float scale = 0.17677669529663687f;
    for (int q = qh * 20; q < qh * 20 + 20; ++q) {
      const float4* qp = (const float4*)Qs[q];
      float s = 0.f;
#pragma unroll
      for (int j = 0; j < 8; ++j) {
        float4 qv = qp[j];
        s += qv.x * kr[j].x + qv.y * kr[j].y + qv.z * kr[j].z + qv.w * kr[j].w;
      }
      ps[q][kk] = f2b(s * scale);
    }
  }
  __syncthreads();
  int kg = lane >> 5, d = lane & 31;
  for (int qq = 0; qq < 10; ++qq) {
    int q = wv * 10 + qq;
    float mx = fmaxf(bfbits(ps[q][lane]), bfbits(ps[q][lane + 64]));
#pragma unroll
    for (int off = 32; off > 0; off >>= 1) mx = fmaxf(mx, __shfl_xor(mx, off));
    float e0 = expf(bfbits(ps[q][lane]) - mx);
    float e1 = expf(bfbits(ps[q][lane + 64]) - mx);
    ps[q][lane] = f2b(e0);
    ps[q][lane + 64] = f2b(e1);
    float sum = wave_sum(e0 + e1);
    float o = 0.f;
#pragma unroll 8
    for (int j = 0; j < KCH / 2; ++j) {
      int r = 2 * j + kg;
      o += bfbits(ps[q][r]) * bfbits(Vs[r][d]);
    }
    o += __shfl_xor(o, 32);
    size_t base = ((size_t)bh * UU + q) * KC + kc;
    if (lane == 0) { pm[base] = mx; pl[base] = sum; }
    if (lane < 32) po[base * 32 + d] = o;
  }
}

// ---------------- bn+elu from atomic stats (+vmp zero for next layer) ----------------
__global__ __launch_bounds__(256) void bn_elu(const float* __restrict__ Y,
                                              const float* __restrict__ stp,
                                              const float* __restrict__ stp2,
                                              const float* __restrict__ g,
                                              const float* __restrict__ bb,
                                              float* __restrict__ X,
                                              unsigned short* __restrict__ XB,
                                              unsigned short* __restrict__ XL,
                                              float* __restrict__ vmpZ) {
  int gid = blockIdx.x * 256 + threadIdx.x;
  if (gid < BB * DMM) vmpZ[gid] = 0.f;
  int d = gid & 255;
  float mean = stp[d] * (1.0f / (float)ROWS);
  float var = stp2[d] * (1.0f / (float)ROWS) - mean * mean;
  float rstd = rsqrtf(var + 1e-5f);
  float v = (Y[gid] - mean) * rstd * g[d] + bb[d];
  float r = v > 0.f ? v : expm1f(v);
  X[gid] = r;
  unsigned short hi = f2b(r);
  XB[gid] = hi;
  XL[gid] = f2b(r - bfbits(hi));
}

extern "C" void kernel_launch(void* const* d_in, const int* in_sizes, int n_in,
                              void* d_out, int out_size, void* d_ws, size_t ws_size,
                              hipStream_t stream) {
  (void)in_sizes; (void)n_in; (void)out_size; (void)ws_size;

  // ---- workspace layout ----
  float* xbuf = (float*)d_ws;
  float* kb   = xbuf + NELEM;
  float* qb   = kb + NELEM;   // aliases tmp (Q dead after attn_part)
  float* tmp  = qb;
  float* Mbuf = qb + NELEM;
  float* vmp  = Mbuf + BB * HH * LL;
  float* stp  = vmp + BB * DMM;
  float* stp2 = stp + DMM;
  float* wp   = stp2 + DMM;
  const int wsz[23] = {
      NELEM,
      NLL * DMM * DMM, NLL * DMM,
      NLL * DMM * DMM, NLL * DMM,
      NLL * DMM * DMM, NLL * DMM,
      NLL * DMM * DMM, NLL * DMM,
      NLL * ITR * DMM, NLL * ITR,
      NLL * DMM * ITR, NLL * DMM,
      NLL * DMM, NLL * DMM,
      NLL * DMM, NLL * DMM,
      (NLL - 1) * DMM * DMM * 3, (NLL - 1) * DMM,
      (NLL - 1) * DMM, (NLL - 1) * DMM,
      DMM, DMM
  };
  float* fptr[23];
  fptr[0] = xbuf;
  for (int i = 1; i < 23; ++i) { fptr[i] = wp; wp += wsz[i]; }
  float* pm = wp;
  float* pl = pm + 32 * UU * KC;
  float* po = pl + 32 * UU * KC;
  unsigned short* xbf   = (unsigned short*)(po + 32 * UU * KC * 32);
  unsigned short* xlo   = xbf + NELEM;
  unsigned short* vbf   = xlo + NELEM;
  unsigned short* wqbf  = vbf + NELEM;
  unsigned short* wkbf  = wqbf + NLL * DMM * DMM;
  unsigned short* wvbf  = wkbf + NLL * DMM * DMM;
  unsigned short* wobf  = wvbf + NLL * DMM * DMM;
  unsigned short* dcwT  = wobf + NLL * DMM * DMM;
  u64* cand = (u64*)(dcwT + (NLL - 1) * 3 * DMM * DMM);  // layout kept (unused now)
  int* topb = (int*)(cand + 256 * 40);                    // layout kept (unused now)
  int* flag = topb + BB * HH * UU;
  unsigned char* mapb = (unsigned char*)(flag + 1);  // 32*2048

  // ---- convert (+cheap inline dtype probe, +dcw repack, +vmp zero, +flag publish) ----
  CvtArgs ca;
  int totalBlk = 0;
  for (int i = 0; i < 23; ++i) {
    ca.src[i] = d_in[i];
    ca.dstF[i] = fptr[i];
    ca.dstB[i] = nullptr;
    ca.dstL[i] = nullptr;
    ca.n[i] = wsz[i];
    ca.blkStart[i] = totalBlk;
    totalBlk += (wsz[i] + 255) / 256;
  }
  ca.blkStart[23] = totalBlk;
  ca.dstB[0] = xbf;  ca.dstL[0] = xlo;
  ca.dstB[1] = wqbf;
  ca.dstB[3] = wkbf;
  ca.dstB[5] = wvbf;
  ca.dstB[7] = wobf;
  ca.dcwT = dcwT;
  ca.vmpZ = vmp;
  ca.flagOut = flag;
  mega_cvt<<<totalBlk + 1, 256, 0, stream>>>(ca);

  dim3 gqkv(ROWS / 128, DMM / 64, 3);
  dim3 g64(ROWS / 64, DMM / 64);

  for (int i = 0; i < NLL; ++i) {
    QKVArgs qa;
    qa.W[0] = wqbf + (size_t)i * DMM * DMM;
    qa.W[1] = wkbf + (size_t)i * DMM * DMM;
    qa.W[2] = wvbf + (size_t)i * DMM * DMM;
    qa.bias[0] = fptr[2] + i * DMM;
    qa.bias[1] = fptr[4] + i * DMM;
    qa.bias[2] = fptr[6] + i * DMM;
    qa.Cq = qb; qa.Ck = kb; qa.Cv = vbf;
    qa.vmp = vmp;
    gemm_qkv<<<gqkv, 256, 0, stream>>>(xbf, xlo, qa);

    uint32_t ki0, ki1, a0, a1, b0, b1;
    threefry2x32(0u, 42u, 0u, (uint32_t)i, &ki0, &ki1);
    threefry2x32(ki0, ki1, 0u, 2u, &a0, &a1);
    threefry2x32(ki0, ki1, 1u, 3u, &b0, &b1);
    (void)a0; (void)b0;

    m_kernel3<<<BB * 512, 256, 0, stream>>>(qb, kb, a1, b1, Mbuf);
    attn_part<<<dim3(KC, BB * HH), 256, 0, stream>>>(qb, kb, vbf, Mbuf, mapb,
                                                     pm, pl, po);

    bool last = (i == NLL - 1);
    oproj_tail<<<ROWS / OTR, 256, 0, stream>>>(
        vmp, mapb, pm, pl, po,
        wobf + (size_t)i * DMM * DMM, fptr[8] + i * DMM,
        xbuf,
        fptr[13] + i * DMM, fptr[14] + i * DMM,
        fptr[9] + (size_t)i * ITR * DMM, fptr[10] + i * ITR,
        fptr[11] + (size_t)i * DMM * ITR, fptr[12] + i * DMM,
        fptr[15] + i * DMM, fptr[16] + i * DMM,
        xbuf, xbf, xlo,
        fptr[21], fptr[22], last ? d_out : nullptr, flag, stp, stp2);

    if (!last) {
      gemm_conv<<<g64, 256, 0, stream>>>(xbf, dcwT + (size_t)i * 3 * DMM * DMM,
                                         fptr[18] + i * DMM, tmp, stp, stp2);
      bn_elu<<<NELEM / 256, 256, 0, stream>>>(tmp, stp, stp2, fptr[19] + i * DMM,
                                              fptr[20] + i * DMM, xbuf, xbf, xlo, vmp);
    }
  }
}

// Round 11
// 505.071 us; speedup vs baseline: 1.0966x; 1.0966x over previous
//
#include <hip/hip_runtime.h>
#include <stdint.h>

#define BB 4
#define LL 2048
#define DMM 256
#define HH 8
#define EE 32
#define NLL 3
#define ITR 16
#define UU 40
#define KC 16                 // split-K chunks
#define KCH 128               // keys per chunk
#define ROWS (BB*LL)          // 8192
#define NELEM (ROWS*DMM)      // 2097152
#define OTR 32                // oproj_tail rows per block (32 -> 256 blocks, 512 thr each)

typedef __attribute__((ext_vector_type(8))) short short8;
typedef __attribute__((ext_vector_type(4))) float f32x4;
typedef unsigned long long u64;

#define GLDS16(g, l)                                                        \
  __builtin_amdgcn_global_load_lds(                                         \
      (const __attribute__((address_space(1))) uint32_t*)(g),               \
      (__attribute__((address_space(3))) uint32_t*)(l), 16, 0, 0)

// ---------------- bf16 bit helpers (RNE) ----------------
__device__ __forceinline__ float bfbits(unsigned short u) {
  return __uint_as_float(((uint32_t)u) << 16);
}
__device__ __forceinline__ unsigned short f2b(float f) {
  uint32_t u = __float_as_uint(f);
  uint32_t r = (u + 0x7FFFu + ((u >> 16) & 1u)) >> 16;
  return (unsigned short)r;
}

// ---------------- threefry2x32 (exact JAX semantics) ----------------
__host__ __device__ inline void threefry2x32(uint32_t k0, uint32_t k1,
                                             uint32_t x0, uint32_t x1,
                                             uint32_t* o0, uint32_t* o1) {
  uint32_t ks2 = k0 ^ k1 ^ 0x1BD11BDAu;
  x0 += k0; x1 += k1;
#define TFR(r) { x0 += x1; x1 = (x1 << (r)) | (x1 >> (32 - (r))); x1 ^= x0; }
  TFR(13) TFR(15) TFR(26) TFR(6)
  x0 += k1;  x1 += ks2 + 1u;
  TFR(17) TFR(29) TFR(16) TFR(24)
  x0 += ks2; x1 += k0 + 2u;
  TFR(13) TFR(15) TFR(26) TFR(6)
  x0 += k0;  x1 += k1 + 3u;
  TFR(17) TFR(29) TFR(16) TFR(24)
  x0 += k1;  x1 += ks2 + 4u;
  TFR(13) TFR(15) TFR(26) TFR(6)
  x0 += ks2; x1 += k0 + 5u;
#undef TFR
  *o0 = x0; *o1 = x1;
}

__device__ __forceinline__ float wave_sum(float v) {
#pragma unroll
  for (int off = 32; off > 0; off >>= 1) v += __shfl_xor(v, off);
  return v;
}

// ---------------- mega convert (+hi/lo splits, +dcw repack, +vmp zero, +cheap inline probe) -
struct CvtArgs {
  const void* src[23];
  float* dstF[23];
  unsigned short* dstB[23];
  unsigned short* dstL[23];
  int n[23];
  int blkStart[24];
  unsigned short* dcwT;
  float* vmpZ;     // zero BB*DMM floats
  int* flagOut;    // published dtype flag
};
__global__ __launch_bounds__(256) void mega_cvt(CvtArgs a) {
  // ---- inline dtype probe: 512 shorts (2/thread). bf16 data -> cnt~0; f32 data -> cnt~228.
  __shared__ int cnt;
  if (threadIdx.x == 0) cnt = 0;
  __syncthreads();
  {
    const unsigned short* u = (const unsigned short*)a.src[0];
    int bad = 0;
#pragma unroll
    for (int rep = 0; rep < 2; ++rep) {
      float v = bfbits(u[threadIdx.x + 256 * rep]);
      float av = fabsf(v);
      bool ok = (v == 0.0f) || (av > 1e-4f && av < 100.0f);
      if (!ok) bad++;
    }
    if (bad) atomicAdd(&cnt, bad);
  }
  __syncthreads();
  int isf32 = (cnt > 25) ? 1 : 0;

  int bid = blockIdx.x;
  if (bid == a.blkStart[23]) {
    for (int t = threadIdx.x; t < BB * DMM; t += 256) a.vmpZ[t] = 0.f;
    if (threadIdx.x == 0) *a.flagOut = isf32;
    return;
  }
  int i = 0;
  while (i < 22 && bid >= a.blkStart[i + 1]) ++i;
  int e = (bid - a.blkStart[i]) * 256 + (int)threadIdx.x;
  if (e >= a.n[i]) return;
  float v; unsigned short rw;
  if (isf32) { v = ((const float*)a.src[i])[e]; rw = f2b(v); }
  else       { rw = ((const unsigned short*)a.src[i])[e]; v = bfbits(rw); }
  a.dstF[i][e] = v;
  if (a.dstB[i]) a.dstB[i][e] = rw;
  if (a.dstL[i]) a.dstL[i][e] = f2b(v - bfbits(rw));
  if (i == 17) {  // dcw: [ly][n][k][t] -> [ly][t][n][k] bf16
    int ly = e / 196608;
    int r = e - ly * 196608;
    int n = r / 768;
    int rem = r - n * 768;
    int k = rem / 3, t = rem - k * 3;
    a.dcwT[ly * 196608 + t * 65536 + n * 256 + k] = rw;
  }
}

// ---------------- QKV MFMA GEMM: z=0:Q 1:K (hi/lo 2-pass, f32 out) 2:V (bf16 out + vmean) --
// (round-0 proven version: BK=32, [128][32]/[64][32] LDS)
struct QKVArgs {
  const unsigned short* W[3];
  const float* bias[3];
  float* Cq;
  float* Ck;
  unsigned short* Cv;
  float* vmp;
};
__global__ __launch_bounds__(256) void gemm_qkv(const unsigned short* __restrict__ Ahi,
                                                const unsigned short* __restrict__ Alo,
                                                QKVArgs qa) {
  __shared__ __attribute__((aligned(16))) unsigned short AsH[128][32];
  __shared__ __attribute__((aligned(16))) unsigned short AsL[128][32];
  __shared__ __attribute__((aligned(16))) unsigned short Bs[64][32];
  int z = blockIdx.z;
  const unsigned short* W = qa.W[z];
  const float* bias = qa.bias[z];
  bool twoPass = (z < 2);
  int bm = blockIdx.x * 128, bn = blockIdx.y * 64;
  int tid = threadIdx.x;
  int wv = tid >> 6, lane = tid & 63;
  int wm = wv >> 1, wn = wv & 1;
  int l15 = lane & 15, quad = lane >> 4;
  int lrow = lane >> 2, lseg = lane & 3;
  f32x4 acc[4][2];
#pragma unroll
  for (int i = 0; i < 4; ++i)
#pragma unroll
    for (int j = 0; j < 2; ++j) acc[i][j] = (f32x4){0.f, 0.f, 0.f, 0.f};
  for (int k0 = 0; k0 < 256; k0 += 32) {
    __syncthreads();
#pragma unroll
    for (int s = 0; s < 2; ++s) {
      int brow = (wv + s * 4) * 16;
      size_t goff = (size_t)(bm + brow + lrow) * 256 + k0 + lseg * 8;
      GLDS16(Ahi + goff, &AsH[brow][0]);
      if (twoPass) GLDS16(Alo + goff, &AsL[brow][0]);
    }
    {
      int brow = wv * 16;
      GLDS16(W + (size_t)(bn + brow + lrow) * 256 + k0 + lseg * 8, &Bs[brow][0]);
    }
    __syncthreads();
    short8 ah[4], bfr[2];
#pragma unroll
    for (int mt = 0; mt < 4; ++mt)
      ah[mt] = *(const short8*)(&AsH[wm * 64 + mt * 16 + l15][quad * 8]);
#pragma unroll
    for (int nt = 0; nt < 2; ++nt)
      bfr[nt] = *(const short8*)(&Bs[wn * 32 + nt * 16 + l15][quad * 8]);
#pragma unroll
    for (int mt = 0; mt < 4; ++mt)
#pragma unroll
      for (int nt = 0; nt < 2; ++nt)
        acc[mt][nt] = __builtin_amdgcn_mfma_f32_16x16x32_bf16(ah[mt], bfr[nt],
                                                              acc[mt][nt], 0, 0, 0);
    if (twoPass) {
      short8 al[4];
#pragma unroll
      for (int mt = 0; mt < 4; ++mt)
        al[mt] = *(const short8*)(&AsL[wm * 64 + mt * 16 + l15][quad * 8]);
#pragma unroll
      for (int mt = 0; mt < 4; ++mt)
#pragma unroll
        for (int nt = 0; nt < 2; ++nt)
          acc[mt][nt] = __builtin_amdgcn_mfma_f32_16x16x32_bf16(al[mt], bfr[nt],
                                                                acc[mt][nt], 0, 0, 0);
    }
  }
  float* C = (z == 0) ? qa.Cq : qa.Ck;
#pragma unroll
  for (int nt = 0; nt < 2; ++nt) {
    int n = bn + wn * 32 + nt * 16 + l15;
    float bv = bias[n];
    float csum = 0.f;
#pragma unroll
    for (int mt = 0; mt < 4; ++mt)
#pragma unroll
      for (int r = 0; r < 4; ++r) {
        int m = bm + wm * 64 + mt * 16 + quad * 4 + r;
        float val = acc[mt][nt][r] + bv;
        if (z < 2) {
          C[(size_t)m * 256 + n] = val;
        } else {
          qa.Cv[(size_t)m * 256 + n] = f2b(val);
          csum += val;
        }
      }
    if (z == 2) {
      csum += __shfl_xor(csum, 16);
      csum += __shfl_xor(csum, 32);
      if (quad == 0) {
        int b = bm >> 11;
        atomicAdd(&qa.vmp[b * DMM + n], csum);
      }
    }
  }
}

// ---------------- FUSED O-proj GEMM (32 rows x 256 cols, 512 thr / 8 waves) + tail --------
// R9 geometry (B staged once per 32 rows) but 8 waves/block: GEMM N-slice 32 cols/wave,
// tail 4 rows/wave (halves the serial dependent-chain), 8 waves/CU of latency hiding.
// Numerics verbatim: same k0 MFMA chain per (row,col), same ctx-merge math, same tail body.
__global__ __launch_bounds__(512) void oproj_tail(const float* __restrict__ vmp,
                                                  const unsigned char* __restrict__ mapb,
                                                  const float* __restrict__ pm,
                                                  const float* __restrict__ pl,
                                                  const float* __restrict__ po,
                                                  const unsigned short* __restrict__ W,
                                                  const float* __restrict__ bias,
                                                  const float* __restrict__ X,
                                                  const float* __restrict__ g1,
                                                  const float* __restrict__ b1ln,
                                                  const float* __restrict__ w1,
                                                  const float* __restrict__ b1,
                                                  const float* __restrict__ w2,
                                                  const float* __restrict__ b2,
                                                  const float* __restrict__ g2,
                                                  const float* __restrict__ b2ln,
                                                  float* __restrict__ Out,
                                                  unsigned short* __restrict__ OutB,
                                                  unsigned short* __restrict__ OutL,
                                                  const float* __restrict__ fing,
                                                  const float* __restrict__ finb,
                                                  void* __restrict__ finOut,
                                                  const int* __restrict__ flag,
                                                  float* __restrict__ stpZ,
                                                  float* __restrict__ stp2Z) {
  __shared__ __attribute__((aligned(16))) unsigned short As[OTR][32];
  __shared__ __attribute__((aligned(16))) unsigned short Bs[256][32];
  __shared__ float Cs[OTR][DMM];
  __shared__ float xs[8][DMM];
  int tid = threadIdx.x;
  if (blockIdx.x == 0 && tid < DMM) {
    stpZ[tid] = 0.f;
    stp2Z[tid] = 0.f;
  }
  int bm = blockIdx.x * OTR;
  int wv = tid >> 6, lane = tid & 63;
  int l15 = lane & 15, quad = lane >> 4;
  int b = bm >> 11, l0 = bm & 2047;
  const float invL = 1.0f / (float)LL;
  f32x4 acc[2][2];
#pragma unroll
  for (int i = 0; i < 2; ++i)
#pragma unroll
    for (int j = 0; j < 2; ++j) acc[i][j] = (f32x4){0.f, 0.f, 0.f, 0.f};
  for (int k0 = 0; k0 < 256; k0 += 32) {
    int h = k0 >> 5;
    int bh = b * HH + h;
    __syncthreads();
    if (tid < OTR * 4) {  // ctx A-tile: 32 rows x 4 col-groups (verbatim merge math)
      int arow = tid >> 2, adg = tid & 3;
      int l = l0 + arow;
      int q = (int)mapb[bh * 2048 + l];
      unsigned short outv[8];
      if (q) {
        size_t base = ((size_t)bh * UU + (q - 1)) * KC;
        float Mx = -1e30f;
#pragma unroll
        for (int kc = 0; kc < KC; ++kc) Mx = fmaxf(Mx, pm[base + kc]);
        float Ls = 0.f;
        float sc[KC];
#pragma unroll
        for (int kc = 0; kc < KC; ++kc) {
          sc[kc] = expf(pm[base + kc] - Mx);
          Ls += pl[base + kc] * sc[kc];
        }
        float inv = 1.0f / Ls;
#pragma unroll
        for (int j = 0; j < 8; ++j) {
          int dl = adg * 8 + j;
          float o = 0.f;
#pragma unroll
          for (int kc = 0; kc < KC; ++kc) o += po[(base + kc) * 32 + dl] * sc[kc];
          outv[j] = f2b(o * inv);
        }
      } else {
        const float* vp = vmp + b * DMM + h * EE + adg * 8;
#pragma unroll
        for (int j = 0; j < 8; ++j) outv[j] = f2b(vp[j] * invL);
      }
      *(uint4*)(&As[arow][adg * 8]) = *(const uint4*)outv;
    }
    {  // stage all 256 B-rows once per block (8 waves x 2 rounds x 16 rows)
      int lrw = lane >> 2, lsg = lane & 3;
#pragma unroll
      for (int s = 0; s < 2; ++s) {
        int brow = s * 128 + wv * 16;
        GLDS16(W + (size_t)(brow + lrw) * 256 + k0 + lsg * 8, &Bs[brow][0]);
      }
    }
    __syncthreads();
    short8 af[2], bfr[2];
#pragma unroll
    for (int mt = 0; mt < 2; ++mt)
      af[mt] = *(const short8*)(&As[mt * 16 + l15][quad * 8]);
#pragma unroll
    for (int nt = 0; nt < 2; ++nt)
      bfr[nt] = *(const short8*)(&Bs[wv * 32 + nt * 16 + l15][quad * 8]);
#pragma unroll
    for (int mt = 0; mt < 2; ++mt)
#pragma unroll
      for (int nt = 0; nt < 2; ++nt)
        acc[mt][nt] = __builtin_amdgcn_mfma_f32_16x16x32_bf16(af[mt], bfr[nt],
                                                              acc[mt][nt], 0, 0, 0);
  }
  // epilogue -> LDS (replaces tmp)
#pragma unroll
  for (int nt = 0; nt < 2; ++nt) {
    int n = wv * 32 + nt * 16 + l15;
    float bv = bias[n];
#pragma unroll
    for (int mt = 0; mt < 2; ++mt)
#pragma unroll
      for (int r = 0; r < 4; ++r)
        Cs[mt * 16 + quad * 4 + r][n] = acc[mt][nt][r] + bv;
  }
  __syncthreads();
  // ---- enc_tail body, verbatim, 4 rows per wave ----
  for (int rr = 0; rr < 4; ++rr) {
    int lr = wv * 4 + rr;
    size_t row = (size_t)bm + lr;
    const float* xr = X + row * DMM;
    const float* tr = Cs[lr];
    float v[4];
#pragma unroll
    for (int i = 0; i < 4; ++i) v[i] = xr[lane + 64 * i] + tr[lane + 64 * i];
    float s = wave_sum(v[0] + v[1] + v[2] + v[3]);
    float m = s * (1.0f / (float)DMM);
    float sq = 0.f;
#pragma unroll
    for (int i = 0; i < 4; ++i) { float d = v[i] - m; sq += d * d; }
    sq = wave_sum(sq);
    float rstd = rsqrtf(sq * (1.0f / (float)DMM) + 1e-5f);
    float xv[4];
#pragma unroll
    for (int i = 0; i < 4; ++i) {
      int d = lane + 64 * i;
      xv[i] = (v[i] - m) * rstd * g1[d] + b1ln[d];
      xs[wv][d] = xv[i];
    }
    __syncthreads();
    int f = lane & 15, qtr = lane >> 4;
    const float* w1p = w1 + f * DMM + qtr * 64;
    const float* xq = &xs[wv][qtr * 64];
    float pacc = 0.f;
#pragma unroll 8
    for (int d = 0; d < 64; ++d) pacc += xq[d] * w1p[d];
    pacc += __shfl_xor(pacc, 16);
    pacc += __shfl_xor(pacc, 32);
    float y1 = fmaxf(pacc + b1[f], 0.0f);
    float y1v[16];
#pragma unroll
    for (int ff = 0; ff < 16; ++ff) y1v[ff] = __shfl(y1, ff);
#pragma unroll
    for (int i = 0; i < 4; ++i) {
      int d = lane + 64 * i;
      const float* w2p = w2 + d * ITR;
      float a = b2[d];
#pragma unroll
      for (int ff = 0; ff < 16; ++ff) a += y1v[ff] * w2p[ff];
      v[i] = xv[i] + a;
    }
    s = wave_sum(v[0] + v[1] + v[2] + v[3]);
    m = s * (1.0f / (float)DMM);
    sq = 0.f;
#pragma unroll
    for (int i = 0; i < 4; ++i) { float d = v[i] - m; sq += d * d; }
    sq = wave_sum(sq);
    rstd = rsqrtf(sq * (1.0f / (float)DMM) + 1e-5f);
    float vv[4];
#pragma unroll
    for (int i = 0; i < 4; ++i) {
      int d = lane + 64 * i;
      float val = (v[i] - m) * rstd * g2[d] + b2ln[d];
      vv[i] = val;
      Out[row * DMM + d] = val;
      unsigned short hi = f2b(val);
      OutB[row * DMM + d] = hi;
      OutL[row * DMM + d] = f2b(val - bfbits(hi));
    }
    if (finOut) {
      s = wave_sum(vv[0] + vv[1] + vv[2] + vv[3]);
      m = s * (1.0f / (float)DMM);
      sq = 0.f;
#pragma unroll
      for (int i = 0; i < 4; ++i) { float d = vv[i] - m; sq += d * d; }
      sq = wave_sum(sq);
      rstd = rsqrtf(sq * (1.0f / (float)DMM) + 1e-5f);
      int isf32 = *flag;
#pragma unroll
      for (int i = 0; i < 4; ++i) {
        int d = lane + 64 * i;
        float val = (vv[i] - m) * rstd * fing[d] + finb[d];
        if (isf32) ((float*)finOut)[row * DMM + d] = val;
        else       ((unsigned short*)finOut)[row * DMM + d] = f2b(val);
      }
    }
  }
}

// ---------------- conv GEMM: A window staged once per k0, 3 taps from LDS ----------------
__global__ __launch_bounds__(256) void gemm_conv(const unsigned short* __restrict__ A,
                                                 const unsigned short* __restrict__ W,
                                                 const float* __restrict__ bias,
                                                 float* __restrict__ C,
                                                 float* __restrict__ stp,
                                                 float* __restrict__ stp2) {
  __shared__ __attribute__((aligned(16))) unsigned short As[80][32];
  __shared__ __attribute__((aligned(16))) unsigned short Bs[192][32];
  int bm = blockIdx.x * 64, bn = blockIdx.y * 64;
  int tid = threadIdx.x;
  int wv = tid >> 6, lane = tid & 63;
  int wm = wv >> 1, wn = wv & 1;
  int l15 = lane & 15, quad = lane >> 4;
  int lrow = lane >> 2, lseg = lane & 3;
  int bbase = bm & ~2047, l0 = bm & 2047;
  f32x4 acc[2][2];
#pragma unroll
  for (int i = 0; i < 2; ++i)
#pragma unroll
    for (int j = 0; j < 2; ++j) acc[i][j] = (f32x4){0.f, 0.f, 0.f, 0.f};
  for (int k0 = 0; k0 < 256; k0 += 32) {
    __syncthreads();
    for (int c = wv; c < 5; c += 4) {
      int i0 = c * 16;
      int l = (l0 - 1 + i0 + lrow + 2048) & 2047;
      GLDS16(A + (size_t)(bbase | l) * 256 + k0 + lseg * 8, &As[i0][0]);
    }
    for (int c = wv; c < 12; c += 4) {
      int i0 = c * 16;
      int tap = c >> 2, brow = (c & 3) * 16;
      GLDS16(W + (size_t)tap * 65536 + (size_t)(bn + brow + lrow) * 256 + k0 + lseg * 8,
             &Bs[i0][0]);
    }
    __syncthreads();
#pragma unroll
    for (int tap = 0; tap < 3; ++tap) {
      short8 af[2], bfr[2];
#pragma unroll
      for (int mt = 0; mt < 2; ++mt)
        af[mt] = *(const short8*)(&As[wm * 32 + mt * 16 + l15 + tap][quad * 8]);
#pragma unroll
      for (int nt = 0; nt < 2; ++nt)
        bfr[nt] = *(const short8*)(&Bs[tap * 64 + wn * 32 + nt * 16 + l15][quad * 8]);
#pragma unroll
      for (int mt = 0; mt < 2; ++mt)
#pragma unroll
        for (int nt = 0; nt < 2; ++nt)
          acc[mt][nt] = __builtin_amdgcn_mfma_f32_16x16x32_bf16(af[mt], bfr[nt],
                                                                acc[mt][nt], 0, 0, 0);
    }
  }
#pragma unroll
  for (int nt = 0; nt < 2; ++nt) {
    int n = bn + wn * 32 + nt * 16 + l15;
    float bv = bias[n];
    float s = 0.f, s2 = 0.f;
#pragma unroll
    for (int mt = 0; mt < 2; ++mt)
#pragma unroll
      for (int r = 0; r < 4; ++r) {
        int m = bm + wm * 32 + mt * 16 + quad * 4 + r;
        float val = acc[mt][nt][r] + bv;
        C[(size_t)m * 256 + n] = val;
        s += val;
        s2 += val * val;
      }
    s  += __shfl_xor(s, 16);   s  += __shfl_xor(s, 32);
    s2 += __shfl_xor(s2, 16);  s2 += __shfl_xor(s2, 32);
    if (quad == 0) {
      atomicAdd(&stp[n], s);
      atomicAdd(&stp2[n], s2);
    }
  }
}

// ---------------- M scores: wave per (b,l), inline threefry, XCD-affinity swizzle ----------
__global__ __launch_bounds__(256) void m_kernel3(const float* __restrict__ Q,
                                                 const float* __restrict__ K,
                                                 uint32_t k20, uint32_t k21,
                                                 float* __restrict__ M) {
  int bid = blockIdx.x;
  int blk = (bid & 7) * 256 + (bid >> 3);   // XCD-affinity remap (pure perf, no semantics)
  int b = blk >> 9, lc = blk & 511;
  int wave = threadIdx.x >> 6, lane = threadIdx.x & 63;
  int l = lc * 4 + wave;
  int myidx = 0;
  if (lane < UU) {
    int j = l * UU + lane;
    uint32_t o0, o1;
    const int half = (LL * UU) / 2;  // 40960
    if (j < half) {
      threefry2x32(k20, k21, (uint32_t)j, (uint32_t)(j + half), &o0, &o1);
      myidx = (int)(o0 & (LL - 1));
    } else {
      threefry2x32(k20, k21, (uint32_t)(j - half), (uint32_t)j, &o0, &o1);
      myidx = (int)(o1 & (LL - 1));
    }
  }
  float4 q4 = *(const float4*)(Q + ((size_t)(b * LL + l)) * DMM + lane * 4);
  const float* Kb = K + (size_t)b * LL * DMM;
  float mx = -1e30f, sm = 0.f;
#pragma unroll 8
  for (int u = 0; u < UU; ++u) {
    int kidx = __shfl(myidx, u);
    float4 k4 = *(const float4*)(Kb + (size_t)kidx * DMM + lane * 4);
    float s = q4.x * k4.x + q4.y * k4.y + q4.z * k4.z + q4.w * k4.w;
    s += __shfl_xor(s, 1);
    s += __shfl_xor(s, 2);
    s += __shfl_xor(s, 4);
    mx = fmaxf(mx, s);
    sm += s;
  }
  if ((lane & 7) == 0) {
    int h = lane >> 3;
    M[((size_t)(b * HH + h)) * LL + l] = mx - sm * (1.0f / (float)LL);
  }
}

// ---------------- fused topk + split-K flash attention (R8-proven) ------------------------
__global__ __launch_bounds__(256) void attn_part(const float* __restrict__ Q,
                                                 const float* __restrict__ K,
                                                 const unsigned short* __restrict__ Vbf,
                                                 const float* __restrict__ M,
                                                 unsigned char* __restrict__ mapb,
                                                 float* __restrict__ pm,
                                                 float* __restrict__ pl,
                                                 float* __restrict__ po) {
  __shared__ float Qs[40][32];
  __shared__ unsigned short ps[40][KCH];
  __shared__ unsigned short Vs[KCH][40];
  __shared__ int qrows[40];
  __shared__ unsigned int hist[256];
  __shared__ unsigned int sA[256];
  __shared__ unsigned int sB[256];
  __shared__ unsigned int tbv;
  int kc = blockIdx.x, bh = blockIdx.y;
  int h = bh & 7, b = bh >> 3;
  int tid = threadIdx.x;
  int wv = tid >> 6, lane = tid & 63;

  // ---- independent loads issued first (overlap with radix latency) ----
  {
    int row = tid >> 1, half = tid & 1;
    const unsigned short* vsrc =
        Vbf + (size_t)(b * LL + kc * KCH + row) * DMM + h * EE + half * 16;
    *(uint4*)(&Vs[row][half * 16]) = *(const uint4*)vsrc;
    *(uint4*)(&Vs[row][half * 16 + 8]) = *(const uint4*)(vsrc + 8);
  }
  int kk = tid & (KCH - 1), qh = tid >> 7;  // 2 threads/key, 20 queries each
  float4 kr[8];
  {
    const float4* kp =
        (const float4*)(K + ((size_t)(b * LL + kc * KCH + kk)) * DMM + h * EE);
#pragma unroll
    for (int j = 0; j < 8; ++j) kr[j] = kp[j];
  }

  // ---- exact top-40 radix select on M[bh] (R7-proven rounds) ----
  u64 kreg[8];
#pragma unroll
  for (int r = 0; r < 8; ++r) {
    int l = tid + 256 * r;
    float v = M[(size_t)bh * LL + l];
    uint32_t bits = __float_as_uint(v);
    uint32_t kv = (bits & 0x80000000u) ? ~bits : (bits | 0x80000000u);
    kreg[r] = ((u64)kv << 32) | (uint32_t)(2047 - l);
  }
  u64 prefix = 0;
  int rank = UU;
  for (int round = 0; round < 8; ++round) {
    int shift = 56 - 8 * round;
    u64 maskTop = (round == 0) ? 0ull : (~0ull << (64 - 8 * round));
    hist[tid] = 0;
    __syncthreads();
#pragma unroll
    for (int r = 0; r < 8; ++r) {
      u64 k = kreg[r];
      if ((k & maskTop) == prefix)
        atomicAdd(&hist[(unsigned int)((k >> shift) & 0xFFu)], 1u);
    }
    __syncthreads();
    sA[tid] = hist[tid];
    __syncthreads();
    unsigned int* src = sA;
    unsigned int* dst = sB;
    for (int off = 1; off < 256; off <<= 1) {
      unsigned int v = src[tid] + ((tid + off < 256) ? src[tid + off] : 0u);
      dst[tid] = v;
      __syncthreads();
      unsigned int* tmpp = src; src = dst; dst = tmpp;
    }
    unsigned int Sb = src[tid];
    unsigned int Snext = (tid < 255) ? src[tid + 1] : 0u;
    if (Sb >= (unsigned int)rank && Snext < (unsigned int)rank) tbv = (unsigned int)tid;
    __syncthreads();
    unsigned int tb = tbv;
    unsigned int above = (tb < 255u) ? src[tb + 1] : 0u;
    rank -= (int)above;
    prefix |= ((u64)tb) << shift;
    __syncthreads();
  }
  u64 T = prefix;   // exact 40th-largest key
  // ---- deterministic rank: exclusive prefix over tid of per-thread selected counts ----
  int myCnt = 0;
#pragma unroll
  for (int r = 0; r < 8; ++r) myCnt += (kreg[r] >= T) ? 1 : 0;
  sA[tid] = (unsigned int)myCnt;
  __syncthreads();
  {
    unsigned int* src = sA;
    unsigned int* dst = sB;
    for (int off = 1; off < 256; off <<= 1) {
      unsigned int v = src[tid] + ((tid >= off) ? src[tid - off] : 0u);
      dst[tid] = v;
      __syncthreads();
      unsigned int* tmpp = src; src = dst; dst = tmpp;
    }
    int pos = (int)src[tid] - myCnt;   // exclusive prefix
    bool wmap = (kc == 0);
#pragma unroll
    for (int r = 0; r < 8; ++r) {
      u64 k = kreg[r];
      int l = 2047 - (int)(uint32_t)(k & 0xFFFFFFFFu);
      unsigned char mv = 0;
      if (k >= T) {
        qrows[pos] = l;
        mv = (unsigned char)(pos + 1);
        pos++;
      }
      if (wmap) mapb[bh * 2048 + l] = mv;
    }
  }
  __syncthreads();

  // ---- Q staging for the 40 selected rows ----
  for (int t = tid; t < 40 * 32; t += 256) {
    int q = t >> 5, d = t & 31;
    Qs[q][d] = Q[((size_t)(b * LL + qrows[q])) * DMM + h * EE + d];
  }
  __syncthreads();
  // ---- scores ----
  {
    const float scale = 0.17677669529663687f;
    for (int q = qh * 20; q < qh * 20 + 20; ++q) {
      const float4* qp = (const float4*)Qs[q];
      float s = 0.f;
#pragma unroll
      for (int j = 0; j < 8; ++j) {
        float4 qv = qp[j];
        s += qv.x * kr[j].x + qv.y * kr[j].y + qv.z * kr[j].z + qv.w * kr[j].w;
      }
      ps[q][kk] = f2b(s * scale);
    }
  }
  __syncthreads();
  int kg = lane >> 5, d = lane & 31;
  for (int qq = 0; qq < 10; ++qq) {
    int q = wv * 10 + qq;
    float mx = fmaxf(bfbits(ps[q][lane]), bfbits(ps[q][lane + 64]));
#pragma unroll
    for (int off = 32; off > 0; off >>= 1) mx = fmaxf(mx, __shfl_xor(mx, off));
    float e0 = expf(bfbits(ps[q][lane]) - mx);
    float e1 = expf(bfbits(ps[q][lane + 64]) - mx);
    ps[q][lane] = f2b(e0);
    ps[q][lane + 64] = f2b(e1);
    float sum = wave_sum(e0 + e1);
    float o = 0.f;
#pragma unroll 8
    for (int j = 0; j < KCH / 2; ++j) {
      int r = 2 * j + kg;
      o += bfbits(ps[q][r]) * bfbits(Vs[r][d]);
    }
    o += __shfl_xor(o, 32);
    size_t base = ((size_t)bh * UU + q) * KC + kc;
    if (lane == 0) { pm[base] = mx; pl[base] = sum; }
    if (lane < 32) po[base * 32 + d] = o;
  }
}

// ---------------- bn+elu from atomic stats (+vmp zero for next layer) ----------------
__global__ __launch_bounds__(256) void bn_elu(const float* __restrict__ Y,
                                              const float* __restrict__ stp,
                                              const float* __restrict__ stp2,
                                              const float* __restrict__ g,
                                              const float* __restrict__ bb,
                                              float* __restrict__ X,
                                              unsigned short* __restrict__ XB,
                                              unsigned short* __restrict__ XL,
                                              float* __restrict__ vmpZ) {
  int gid = blockIdx.x * 256 + threadIdx.x;
  if (gid < BB * DMM) vmpZ[gid] = 0.f;
  int d = gid & 255;
  float mean = stp[d] * (1.0f / (float)ROWS);
  float var = stp2[d] * (1.0f / (float)ROWS) - mean * mean;
  float rstd = rsqrtf(var + 1e-5f);
  float v = (Y[gid] - mean) * rstd * g[d] + bb[d];
  float r = v > 0.f ? v : expm1f(v);
  X[gid] = r;
  unsigned short hi = f2b(r);
  XB[gid] = hi;
  XL[gid] = f2b(r - bfbits(hi));
}

extern "C" void kernel_launch(void* const* d_in, const int* in_sizes, int n_in,
                              void* d_out, int out_size, void* d_ws, size_t ws_size,
                              hipStream_t stream) {
  (void)in_sizes; (void)n_in; (void)out_size; (void)ws_size;

  // ---- workspace layout ----
  float* xbuf = (float*)d_ws;
  float* kb   = xbuf + NELEM;
  float* qb   = kb + NELEM;   // aliases tmp (Q dead after attn_part)
  float* tmp  = qb;
  float* Mbuf = qb + NELEM;
  float* vmp  = Mbuf + BB * HH * LL;
  float* stp  = vmp + BB * DMM;
  float* stp2 = stp + DMM;
  float* wp   = stp2 + DMM;
  const int wsz[23] = {
      NELEM,
      NLL * DMM * DMM, NLL * DMM,
      NLL * DMM * DMM, NLL * DMM,
      NLL * DMM * DMM, NLL * DMM,
      NLL * DMM * DMM, NLL * DMM,
      NLL * ITR * DMM, NLL * ITR,
      NLL * DMM * ITR, NLL * DMM,
      NLL * DMM, NLL * DMM,
      NLL * DMM, NLL * DMM,
      (NLL - 1) * DMM * DMM * 3, (NLL - 1) * DMM,
      (NLL - 1) * DMM, (NLL - 1) * DMM,
      DMM, DMM
  };
  float* fptr[23];
  fptr[0] = xbuf;
  for (int i = 1; i < 23; ++i) { fptr[i] = wp; wp += wsz[i]; }
  float* pm = wp;
  float* pl = pm + 32 * UU * KC;
  float* po = pl + 32 * UU * KC;
  unsigned short* xbf   = (unsigned short*)(po + 32 * UU * KC * 32);
  unsigned short* xlo   = xbf + NELEM;
  unsigned short* vbf   = xlo + NELEM;
  unsigned short* wqbf  = vbf + NELEM;
  unsigned short* wkbf  = wqbf + NLL * DMM * DMM;
  unsigned short* wvbf  = wkbf + NLL * DMM * DMM;
  unsigned short* wobf  = wvbf + NLL * DMM * DMM;
  unsigned short* dcwT  = wobf + NLL * DMM * DMM;
  u64* cand = (u64*)(dcwT + (NLL - 1) * 3 * DMM * DMM);  // layout kept (unused now)
  int* topb = (int*)(cand + 256 * 40);                    // layout kept (unused now)
  int* flag = topb + BB * HH * UU;
  unsigned char* mapb = (unsigned char*)(flag + 1);  // 32*2048

  // ---- convert (+cheap inline dtype probe, +dcw repack, +vmp zero, +flag publish) ----
  CvtArgs ca;
  int totalBlk = 0;
  for (int i = 0; i < 23; ++i) {
    ca.src[i] = d_in[i];
    ca.dstF[i] = fptr[i];
    ca.dstB[i] = nullptr;
    ca.dstL[i] = nullptr;
    ca.n[i] = wsz[i];
    ca.blkStart[i] = totalBlk;
    totalBlk += (wsz[i] + 255) / 256;
  }
  ca.blkStart[23] = totalBlk;
  ca.dstB[0] = xbf;  ca.dstL[0] = xlo;
  ca.dstB[1] = wqbf;
  ca.dstB[3] = wkbf;
  ca.dstB[5] = wvbf;
  ca.dstB[7] = wobf;
  ca.dcwT = dcwT;
  ca.vmpZ = vmp;
  ca.flagOut = flag;
  mega_cvt<<<totalBlk + 1, 256, 0, stream>>>(ca);

  dim3 gqkv(ROWS / 128, DMM / 64, 3);
  dim3 g64(ROWS / 64, DMM / 64);

  for (int i = 0; i < NLL; ++i) {
    QKVArgs qa;
    qa.W[0] = wqbf + (size_t)i * DMM * DMM;
    qa.W[1] = wkbf + (size_t)i * DMM * DMM;
    qa.W[2] = wvbf + (size_t)i * DMM * DMM;
    qa.bias[0] = fptr[2] + i * DMM;
    qa.bias[1] = fptr[4] + i * DMM;
    qa.bias[2] = fptr[6] + i * DMM;
    qa.Cq = qb; qa.Ck = kb; qa.Cv = vbf;
    qa.vmp = vmp;
    gemm_qkv<<<gqkv, 256, 0, stream>>>(xbf, xlo, qa);

    uint32_t ki0, ki1, a0, a1, b0, b1;
    threefry2x32(0u, 42u, 0u, (uint32_t)i, &ki0, &ki1);
    threefry2x32(ki0, ki1, 0u, 2u, &a0, &a1);
    threefry2x32(ki0, ki1, 1u, 3u, &b0, &b1);
    (void)a0; (void)b0;

    m_kernel3<<<BB * 512, 256, 0, stream>>>(qb, kb, a1, b1, Mbuf);
    attn_part<<<dim3(KC, BB * HH), 256, 0, stream>>>(qb, kb, vbf, Mbuf, mapb,
                                                     pm, pl, po);

    bool last = (i == NLL - 1);
    oproj_tail<<<ROWS / OTR, 512, 0, stream>>>(
        vmp, mapb, pm, pl, po,
        wobf + (size_t)i * DMM * DMM, fptr[8] + i * DMM,
        xbuf,
        fptr[13] + i * DMM, fptr[14] + i * DMM,
        fptr[9] + (size_t)i * ITR * DMM, fptr[10] + i * ITR,
        fptr[11] + (size_t)i * DMM * ITR, fptr[12] + i * DMM,
        fptr[15] + i * DMM, fptr[16] + i * DMM,
        xbuf, xbf, xlo,
        fptr[21], fptr[22], last ? d_out : nullptr, flag, stp, stp2);

    if (!last) {
      gemm_conv<<<g64, 256, 0, stream>>>(xbf, dcwT + (size_t)i * 3 * DMM * DMM,
                                         fptr[18] + i * DMM, tmp, stp, stp2);
      bn_elu<<<NELEM / 256, 256, 0, stream>>>(tmp, stp, stp2, fptr[19] + i * DMM,
                                              fptr[20] + i * DMM, xbuf, xbf, xlo, vmp);
    }
  }
}

// Round 12
// 487.234 us; speedup vs baseline: 1.1367x; 1.0366x over previous
//
#include <hip/hip_runtime.h>
#include <stdint.h>

#define BB 4
#define LL 2048
#define DMM 256
#define HH 8
#define EE 32
#define NLL 3
#define ITR 16
#define UU 40
#define KC 16                 // split-K chunks
#define KCH 128               // keys per chunk
#define ROWS (BB*LL)          // 8192
#define NELEM (ROWS*DMM)      // 2097152
#define OTR 32                // oproj_tail rows per block (32 -> 256 blocks, 512 thr each)

typedef __attribute__((ext_vector_type(8))) short short8;
typedef __attribute__((ext_vector_type(4))) float f32x4;
typedef unsigned long long u64;

#define GLDS16(g, l)                                                        \
  __builtin_amdgcn_global_load_lds(                                         \
      (const __attribute__((address_space(1))) uint32_t*)(g),               \
      (__attribute__((address_space(3))) uint32_t*)(l), 16, 0, 0)

// ---------------- bf16 bit helpers (RNE) ----------------
__device__ __forceinline__ float bfbits(unsigned short u) {
  return __uint_as_float(((uint32_t)u) << 16);
}
__device__ __forceinline__ unsigned short f2b(float f) {
  uint32_t u = __float_as_uint(f);
  uint32_t r = (u + 0x7FFFu + ((u >> 16) & 1u)) >> 16;
  return (unsigned short)r;
}

// ---------------- threefry2x32 (exact JAX semantics) ----------------
__host__ __device__ inline void threefry2x32(uint32_t k0, uint32_t k1,
                                             uint32_t x0, uint32_t x1,
                                             uint32_t* o0, uint32_t* o1) {
  uint32_t ks2 = k0 ^ k1 ^ 0x1BD11BDAu;
  x0 += k0; x1 += k1;
#define TFR(r) { x0 += x1; x1 = (x1 << (r)) | (x1 >> (32 - (r))); x1 ^= x0; }
  TFR(13) TFR(15) TFR(26) TFR(6)
  x0 += k1;  x1 += ks2 + 1u;
  TFR(17) TFR(29) TFR(16) TFR(24)
  x0 += ks2; x1 += k0 + 2u;
  TFR(13) TFR(15) TFR(26) TFR(6)
  x0 += k0;  x1 += k1 + 3u;
  TFR(17) TFR(29) TFR(16) TFR(24)
  x0 += k1;  x1 += ks2 + 4u;
  TFR(13) TFR(15) TFR(26) TFR(6)
  x0 += ks2; x1 += k0 + 5u;
#undef TFR
  *o0 = x0; *o1 = x1;
}

__device__ __forceinline__ float wave_sum(float v) {
#pragma unroll
  for (int off = 32; off > 0; off >>= 1) v += __shfl_xor(v, off);
  return v;
}

// ---------------- mega convert (+hi/lo splits, +dcw repack, +vmp zero, +cheap inline probe) -
struct CvtArgs {
  const void* src[23];
  float* dstF[23];
  unsigned short* dstB[23];
  unsigned short* dstL[23];
  int n[23];
  int blkStart[24];
  unsigned short* dcwT;
  float* vmpZ;     // zero BB*DMM floats
  int* flagOut;    // published dtype flag
};
__global__ __launch_bounds__(256) void mega_cvt(CvtArgs a) {
  // ---- inline dtype probe: 512 shorts (2/thread). bf16 data -> cnt~0; f32 data -> cnt~228.
  __shared__ int cnt;
  if (threadIdx.x == 0) cnt = 0;
  __syncthreads();
  {
    const unsigned short* u = (const unsigned short*)a.src[0];
    int bad = 0;
#pragma unroll
    for (int rep = 0; rep < 2; ++rep) {
      float v = bfbits(u[threadIdx.x + 256 * rep]);
      float av = fabsf(v);
      bool ok = (v == 0.0f) || (av > 1e-4f && av < 100.0f);
      if (!ok) bad++;
    }
    if (bad) atomicAdd(&cnt, bad);
  }
  __syncthreads();
  int isf32 = (cnt > 25) ? 1 : 0;

  int bid = blockIdx.x;
  if (bid == a.blkStart[23]) {
    for (int t = threadIdx.x; t < BB * DMM; t += 256) a.vmpZ[t] = 0.f;
    if (threadIdx.x == 0) *a.flagOut = isf32;
    return;
  }
  int i = 0;
  while (i < 22 && bid >= a.blkStart[i + 1]) ++i;
  int e = (bid - a.blkStart[i]) * 256 + (int)threadIdx.x;
  if (e >= a.n[i]) return;
  float v; unsigned short rw;
  if (isf32) { v = ((const float*)a.src[i])[e]; rw = f2b(v); }
  else       { rw = ((const unsigned short*)a.src[i])[e]; v = bfbits(rw); }
  a.dstF[i][e] = v;
  if (a.dstB[i]) a.dstB[i][e] = rw;
  if (a.dstL[i]) a.dstL[i][e] = f2b(v - bfbits(rw));
  if (i == 17) {  // dcw: [ly][n][k][t] -> [ly][t][n][k] bf16
    int ly = e / 196608;
    int r = e - ly * 196608;
    int n = r / 768;
    int rem = r - n * 768;
    int k = rem / 3, t = rem - k * 3;
    a.dcwT[ly * 196608 + t * 65536 + n * 256 + k] = rw;
  }
}

// ---------------- QKV MFMA GEMM: z=0:Q 1:K (hi/lo 2-pass, f32 out) 2:V (bf16 out + vmean) --
// (round-0 proven version: BK=32, [128][32]/[64][32] LDS)
struct QKVArgs {
  const unsigned short* W[3];
  const float* bias[3];
  float* Cq;
  float* Ck;
  unsigned short* Cv;
  float* vmp;
};
__global__ __launch_bounds__(256) void gemm_qkv(const unsigned short* __restrict__ Ahi,
                                                const unsigned short* __restrict__ Alo,
                                                QKVArgs qa) {
  __shared__ __attribute__((aligned(16))) unsigned short AsH[128][32];
  __shared__ __attribute__((aligned(16))) unsigned short AsL[128][32];
  __shared__ __attribute__((aligned(16))) unsigned short Bs[64][32];
  int z = blockIdx.z;
  const unsigned short* W = qa.W[z];
  const float* bias = qa.bias[z];
  bool twoPass = (z < 2);
  int bm = blockIdx.x * 128, bn = blockIdx.y * 64;
  int tid = threadIdx.x;
  int wv = tid >> 6, lane = tid & 63;
  int wm = wv >> 1, wn = wv & 1;
  int l15 = lane & 15, quad = lane >> 4;
  int lrow = lane >> 2, lseg = lane & 3;
  f32x4 acc[4][2];
#pragma unroll
  for (int i = 0; i < 4; ++i)
#pragma unroll
    for (int j = 0; j < 2; ++j) acc[i][j] = (f32x4){0.f, 0.f, 0.f, 0.f};
  for (int k0 = 0; k0 < 256; k0 += 32) {
    __syncthreads();
#pragma unroll
    for (int s = 0; s < 2; ++s) {
      int brow = (wv + s * 4) * 16;
      size_t goff = (size_t)(bm + brow + lrow) * 256 + k0 + lseg * 8;
      GLDS16(Ahi + goff, &AsH[brow][0]);
      if (twoPass) GLDS16(Alo + goff, &AsL[brow][0]);
    }
    {
      int brow = wv * 16;
      GLDS16(W + (size_t)(bn + brow + lrow) * 256 + k0 + lseg * 8, &Bs[brow][0]);
    }
    __syncthreads();
    short8 ah[4], bfr[2];
#pragma unroll
    for (int mt = 0; mt < 4; ++mt)
      ah[mt] = *(const short8*)(&AsH[wm * 64 + mt * 16 + l15][quad * 8]);
#pragma unroll
    for (int nt = 0; nt < 2; ++nt)
      bfr[nt] = *(const short8*)(&Bs[wn * 32 + nt * 16 + l15][quad * 8]);
#pragma unroll
    for (int mt = 0; mt < 4; ++mt)
#pragma unroll
      for (int nt = 0; nt < 2; ++nt)
        acc[mt][nt] = __builtin_amdgcn_mfma_f32_16x16x32_bf16(ah[mt], bfr[nt],
                                                              acc[mt][nt], 0, 0, 0);
    if (twoPass) {
      short8 al[4];
#pragma unroll
      for (int mt = 0; mt < 4; ++mt)
        al[mt] = *(const short8*)(&AsL[wm * 64 + mt * 16 + l15][quad * 8]);
#pragma unroll
      for (int mt = 0; mt < 4; ++mt)
#pragma unroll
        for (int nt = 0; nt < 2; ++nt)
          acc[mt][nt] = __builtin_amdgcn_mfma_f32_16x16x32_bf16(al[mt], bfr[nt],
                                                                acc[mt][nt], 0, 0, 0);
    }
  }
  float* C = (z == 0) ? qa.Cq : qa.Ck;
#pragma unroll
  for (int nt = 0; nt < 2; ++nt) {
    int n = bn + wn * 32 + nt * 16 + l15;
    float bv = bias[n];
    float csum = 0.f;
#pragma unroll
    for (int mt = 0; mt < 4; ++mt)
#pragma unroll
      for (int r = 0; r < 4; ++r) {
        int m = bm + wm * 64 + mt * 16 + quad * 4 + r;
        float val = acc[mt][nt][r] + bv;
        if (z < 2) {
          C[(size_t)m * 256 + n] = val;
        } else {
          qa.Cv[(size_t)m * 256 + n] = f2b(val);
          csum += val;
        }
      }
    if (z == 2) {
      csum += __shfl_xor(csum, 16);
      csum += __shfl_xor(csum, 32);
      if (quad == 0) {
        int b = bm >> 11;
        atomicAdd(&qa.vmp[b * DMM + n], csum);
      }
    }
  }
}

// ---------------- FUSED O-proj GEMM (32x256, 512 thr) + tail, ctx-merge HOISTED -----------
// R11 structure, but the ctx A-panel (all 8 heads) is computed ONCE before the K-loop at
// full 512-thread parallelism (1024 units, 2/thread) into As[32][256]. The K-loop becomes
// pure {stage B, MFMA} — the 8x barrier-fenced 128-thread merge phases are gone from the
// critical path. Same merge math per (row,head), same MFMA chain -> bitwise-identical.
__global__ __launch_bounds__(512) void oproj_tail(const float* __restrict__ vmp,
                                                  const unsigned char* __restrict__ mapb,
                                                  const float* __restrict__ pm,
                                                  const float* __restrict__ pl,
                                                  const float* __restrict__ po,
                                                  const unsigned short* __restrict__ W,
                                                  const float* __restrict__ bias,
                                                  const float* __restrict__ X,
                                                  const float* __restrict__ g1,
                                                  const float* __restrict__ b1ln,
                                                  const float* __restrict__ w1,
                                                  const float* __restrict__ b1,
                                                  const float* __restrict__ w2,
                                                  const float* __restrict__ b2,
                                                  const float* __restrict__ g2,
                                                  const float* __restrict__ b2ln,
                                                  float* __restrict__ Out,
                                                  unsigned short* __restrict__ OutB,
                                                  unsigned short* __restrict__ OutL,
                                                  const float* __restrict__ fing,
                                                  const float* __restrict__ finb,
                                                  void* __restrict__ finOut,
                                                  const int* __restrict__ flag,
                                                  float* __restrict__ stpZ,
                                                  float* __restrict__ stp2Z) {
  __shared__ __attribute__((aligned(16))) unsigned short As[OTR][DMM];  // full ctx panel
  __shared__ __attribute__((aligned(16))) unsigned short Bs[256][32];
  __shared__ float Cs[OTR][DMM];
  __shared__ float xs[8][DMM];
  int tid = threadIdx.x;
  if (blockIdx.x == 0 && tid < DMM) {
    stpZ[tid] = 0.f;
    stp2Z[tid] = 0.f;
  }
  int bm = blockIdx.x * OTR;
  int wv = tid >> 6, lane = tid & 63;
  int l15 = lane & 15, quad = lane >> 4;
  int b = bm >> 11, l0 = bm & 2047;
  const float invL = 1.0f / (float)LL;

  // ---- phase 1: ctx A-panel for all 8 heads, once, full-block parallel ----
#pragma unroll
  for (int uu = 0; uu < 2; ++uu) {
    int u = tid * 2 + uu;            // 0..1023
    int arow = u >> 5;               // 32 rows
    int sub = u & 31;
    int h = sub >> 2, adg = sub & 3; // 8 heads x 4 col-groups
    int bh = b * HH + h;
    int l = l0 + arow;
    int q = (int)mapb[bh * 2048 + l];
    unsigned short outv[8];
    if (q) {
      size_t base = ((size_t)bh * UU + (q - 1)) * KC;
      float Mx = -1e30f;
#pragma unroll
      for (int kc = 0; kc < KC; ++kc) Mx = fmaxf(Mx, pm[base + kc]);
      float Ls = 0.f;
      float sc[KC];
#pragma unroll
      for (int kc = 0; kc < KC; ++kc) {
        sc[kc] = expf(pm[base + kc] - Mx);
        Ls += pl[base + kc] * sc[kc];
      }
      float inv = 1.0f / Ls;
#pragma unroll
      for (int j = 0; j < 8; ++j) {
        int dl = adg * 8 + j;
        float o = 0.f;
#pragma unroll
        for (int kc = 0; kc < KC; ++kc) o += po[(base + kc) * 32 + dl] * sc[kc];
        outv[j] = f2b(o * inv);
      }
    } else {
      const float* vp = vmp + b * DMM + h * EE + adg * 8;
#pragma unroll
      for (int j = 0; j < 8; ++j) outv[j] = f2b(vp[j] * invL);
    }
    *(uint4*)(&As[arow][h * EE + adg * 8]) = *(const uint4*)outv;
  }
  __syncthreads();

  // ---- phase 2: GEMM loop (pure stage+MFMA) ----
  f32x4 acc[2][2];
#pragma unroll
  for (int i = 0; i < 2; ++i)
#pragma unroll
    for (int j = 0; j < 2; ++j) acc[i][j] = (f32x4){0.f, 0.f, 0.f, 0.f};
  for (int k0 = 0; k0 < 256; k0 += 32) {
    if (k0) __syncthreads();
    {  // stage all 256 B-rows once per block (8 waves x 2 rounds x 16 rows)
      int lrw = lane >> 2, lsg = lane & 3;
#pragma unroll
      for (int s = 0; s < 2; ++s) {
        int brow = s * 128 + wv * 16;
        GLDS16(W + (size_t)(brow + lrw) * 256 + k0 + lsg * 8, &Bs[brow][0]);
      }
    }
    __syncthreads();
    short8 af[2], bfr[2];
#pragma unroll
    for (int mt = 0; mt < 2; ++mt)
      af[mt] = *(const short8*)(&As[mt * 16 + l15][k0 + quad * 8]);
#pragma unroll
    for (int nt = 0; nt < 2; ++nt)
      bfr[nt] = *(const short8*)(&Bs[wv * 32 + nt * 16 + l15][quad * 8]);
#pragma unroll
    for (int mt = 0; mt < 2; ++mt)
#pragma unroll
      for (int nt = 0; nt < 2; ++nt)
        acc[mt][nt] = __builtin_amdgcn_mfma_f32_16x16x32_bf16(af[mt], bfr[nt],
                                                              acc[mt][nt], 0, 0, 0);
  }
  // epilogue -> LDS (replaces tmp)
#pragma unroll
  for (int nt = 0; nt < 2; ++nt) {
    int n = wv * 32 + nt * 16 + l15;
    float bv = bias[n];
#pragma unroll
    for (int mt = 0; mt < 2; ++mt)
#pragma unroll
      for (int r = 0; r < 4; ++r)
        Cs[mt * 16 + quad * 4 + r][n] = acc[mt][nt][r] + bv;
  }
  __syncthreads();
  // ---- enc_tail body, verbatim, 4 rows per wave ----
  for (int rr = 0; rr < 4; ++rr) {
    int lr = wv * 4 + rr;
    size_t row = (size_t)bm + lr;
    const float* xr = X + row * DMM;
    const float* tr = Cs[lr];
    float v[4];
#pragma unroll
    for (int i = 0; i < 4; ++i) v[i] = xr[lane + 64 * i] + tr[lane + 64 * i];
    float s = wave_sum(v[0] + v[1] + v[2] + v[3]);
    float m = s * (1.0f / (float)DMM);
    float sq = 0.f;
#pragma unroll
    for (int i = 0; i < 4; ++i) { float d = v[i] - m; sq += d * d; }
    sq = wave_sum(sq);
    float rstd = rsqrtf(sq * (1.0f / (float)DMM) + 1e-5f);
    float xv[4];
#pragma unroll
    for (int i = 0; i < 4; ++i) {
      int d = lane + 64 * i;
      xv[i] = (v[i] - m) * rstd * g1[d] + b1ln[d];
      xs[wv][d] = xv[i];
    }
    __syncthreads();
    int f = lane & 15, qtr = lane >> 4;
    const float* w1p = w1 + f * DMM + qtr * 64;
    const float* xq = &xs[wv][qtr * 64];
    float pacc = 0.f;
#pragma unroll 8
    for (int d = 0; d < 64; ++d) pacc += xq[d] * w1p[d];
    pacc += __shfl_xor(pacc, 16);
    pacc += __shfl_xor(pacc, 32);
    float y1 = fmaxf(pacc + b1[f], 0.0f);
    float y1v[16];
#pragma unroll
    for (int ff = 0; ff < 16; ++ff) y1v[ff] = __shfl(y1, ff);
#pragma unroll
    for (int i = 0; i < 4; ++i) {
      int d = lane + 64 * i;
      const float* w2p = w2 + d * ITR;
      float a = b2[d];
#pragma unroll
      for (int ff = 0; ff < 16; ++ff) a += y1v[ff] * w2p[ff];
      v[i] = xv[i] + a;
    }
    s = wave_sum(v[0] + v[1] + v[2] + v[3]);
    m = s * (1.0f / (float)DMM);
    sq = 0.f;
#pragma unroll
    for (int i = 0; i < 4; ++i) { float d = v[i] - m; sq += d * d; }
    sq = wave_sum(sq);
    rstd = rsqrtf(sq * (1.0f / (float)DMM) + 1e-5f);
    float vv[4];
#pragma unroll
    for (int i = 0; i < 4; ++i) {
      int d = lane + 64 * i;
      float val = (v[i] - m) * rstd * g2[d] + b2ln[d];
      vv[i] = val;
      Out[row * DMM + d] = val;
      unsigned short hi = f2b(val);
      OutB[row * DMM + d] = hi;
      OutL[row * DMM + d] = f2b(val - bfbits(hi));
    }
    if (finOut) {
      s = wave_sum(vv[0] + vv[1] + vv[2] + vv[3]);
      m = s * (1.0f / (float)DMM);
      sq = 0.f;
#pragma unroll
      for (int i = 0; i < 4; ++i) { float d = vv[i] - m; sq += d * d; }
      sq = wave_sum(sq);
      rstd = rsqrtf(sq * (1.0f / (float)DMM) + 1e-5f);
      int isf32 = *flag;
#pragma unroll
      for (int i = 0; i < 4; ++i) {
        int d = lane + 64 * i;
        float val = (vv[i] - m) * rstd * fing[d] + finb[d];
        if (isf32) ((float*)finOut)[row * DMM + d] = val;
        else       ((unsigned short*)finOut)[row * DMM + d] = f2b(val);
      }
    }
  }
}

// ---------------- conv GEMM: A window staged once per k0, 3 taps from LDS ----------------
__global__ __launch_bounds__(256) void gemm_conv(const unsigned short* __restrict__ A,
                                                 const unsigned short* __restrict__ W,
                                                 const float* __restrict__ bias,
                                                 float* __restrict__ C,
                                                 float* __restrict__ stp,
                                                 float* __restrict__ stp2) {
  __shared__ __attribute__((aligned(16))) unsigned short As[80][32];
  __shared__ __attribute__((aligned(16))) unsigned short Bs[192][32];
  int bm = blockIdx.x * 64, bn = blockIdx.y * 64;
  int tid = threadIdx.x;
  int wv = tid >> 6, lane = tid & 63;
  int wm = wv >> 1, wn = wv & 1;
  int l15 = lane & 15, quad = lane >> 4;
  int lrow = lane >> 2, lseg = lane & 3;
  int bbase = bm & ~2047, l0 = bm & 2047;
  f32x4 acc[2][2];
#pragma unroll
  for (int i = 0; i < 2; ++i)
#pragma unroll
    for (int j = 0; j < 2; ++j) acc[i][j] = (f32x4){0.f, 0.f, 0.f, 0.f};
  for (int k0 = 0; k0 < 256; k0 += 32) {
    __syncthreads();
    for (int c = wv; c < 5; c += 4) {
      int i0 = c * 16;
      int l = (l0 - 1 + i0 + lrow + 2048) & 2047;
      GLDS16(A + (size_t)(bbase | l) * 256 + k0 + lseg * 8, &As[i0][0]);
    }
    for (int c = wv; c < 12; c += 4) {
      int i0 = c * 16;
      int tap = c >> 2, brow = (c & 3) * 16;
      GLDS16(W + (size_t)tap * 65536 + (size_t)(bn + brow + lrow) * 256 + k0 + lseg * 8,
             &Bs[i0][0]);
    }
    __syncthreads();
#pragma unroll
    for (int tap = 0; tap < 3; ++tap) {
      short8 af[2], bfr[2];
#pragma unroll
      for (int mt = 0; mt < 2; ++mt)
        af[mt] = *(const short8*)(&As[wm * 32 + mt * 16 + l15 + tap][quad * 8]);
#pragma unroll
      for (int nt = 0; nt < 2; ++nt)
        bfr[nt] = *(const short8*)(&Bs[tap * 64 + wn * 32 + nt * 16 + l15][quad * 8]);
#pragma unroll
      for (int mt = 0; mt < 2; ++mt)
#pragma unroll
        for (int nt = 0; nt < 2; ++nt)
          acc[mt][nt] = __builtin_amdgcn_mfma_f32_16x16x32_bf16(af[mt], bfr[nt],
                                                                acc[mt][nt], 0, 0, 0);
    }
  }
#pragma unroll
  for (int nt = 0; nt < 2; ++nt) {
    int n = bn + wn * 32 + nt * 16 + l15;
    float bv = bias[n];
    float s = 0.f, s2 = 0.f;
#pragma unroll
    for (int mt = 0; mt < 2; ++mt)
#pragma unroll
      for (int r = 0; r < 4; ++r) {
        int m = bm + wm * 32 + mt * 16 + quad * 4 + r;
        float val = acc[mt][nt][r] + bv;
        C[(size_t)m * 256 + n] = val;
        s += val;
        s2 += val * val;
      }
    s  += __shfl_xor(s, 16);   s  += __shfl_xor(s, 32);
    s2 += __shfl_xor(s2, 16);  s2 += __shfl_xor(s2, 32);
    if (quad == 0) {
      atomicAdd(&stp[n], s);
      atomicAdd(&stp2[n], s2);
    }
  }
}

// ---------------- M scores: wave per (b,l), inline threefry, XCD-affinity swizzle ----------
__global__ __launch_bounds__(256) void m_kernel3(const float* __restrict__ Q,
                                                 const float* __restrict__ K,
                                                 uint32_t k20, uint32_t k21,
                                                 float* __restrict__ M) {
  int bid = blockIdx.x;
  int blk = (bid & 7) * 256 + (bid >> 3);   // XCD-affinity remap (pure perf, no semantics)
  int b = blk >> 9, lc = blk & 511;
  int wave = threadIdx.x >> 6, lane = threadIdx.x & 63;
  int l = lc * 4 + wave;
  int myidx = 0;
  if (lane < UU) {
    int j = l * UU + lane;
    uint32_t o0, o1;
    const int half = (LL * UU) / 2;  // 40960
    if (j < half) {
      threefry2x32(k20, k21, (uint32_t)j, (uint32_t)(j + half), &o0, &o1);
      myidx = (int)(o0 & (LL - 1));
    } else {
      threefry2x32(k20, k21, (uint32_t)(j - half), (uint32_t)j, &o0, &o1);
      myidx = (int)(o1 & (LL - 1));
    }
  }
  float4 q4 = *(const float4*)(Q + ((size_t)(b * LL + l)) * DMM + lane * 4);
  const float* Kb = K + (size_t)b * LL * DMM;
  float mx = -1e30f, sm = 0.f;
#pragma unroll 8
  for (int u = 0; u < UU; ++u) {
    int kidx = __shfl(myidx, u);
    float4 k4 = *(const float4*)(Kb + (size_t)kidx * DMM + lane * 4);
    float s = q4.x * k4.x + q4.y * k4.y + q4.z * k4.z + q4.w * k4.w;
    s += __shfl_xor(s, 1);
    s += __shfl_xor(s, 2);
    s += __shfl_xor(s, 4);
    mx = fmaxf(mx, s);
    sm += s;
  }
  if ((lane & 7) == 0) {
    int h = lane >> 3;
    M[((size_t)(b * HH + h)) * LL + l] = mx - sm * (1.0f / (float)LL);
  }
}

// ---------------- fused topk + split-K flash attention (R8-proven) ------------------------
__global__ __launch_bounds__(256) void attn_part(const float* __restrict__ Q,
                                                 const float* __restrict__ K,
                                                 const unsigned short* __restrict__ Vbf,
                                                 const float* __restrict__ M,
                                                 unsigned char* __restrict__ mapb,
                                                 float* __restrict__ pm,
                                                 float* __restrict__ pl,
                                                 float* __restrict__ po) {
  __shared__ float Qs[40][32];
  __shared__ unsigned short ps[40][KCH];
  __shared__ unsigned short Vs[KCH][40];
  __shared__ int qrows[40];
  __shared__ unsigned int hist[256];
  __shared__ unsigned int sA[256];
  __shared__ unsigned int sB[256];
  __shared__ unsigned int tbv;
  int kc = blockIdx.x, bh = blockIdx.y;
  int h = bh & 7, b = bh >> 3;
  int tid = threadIdx.x;
  int wv = tid >> 6, lane = tid & 63;

  // ---- independent loads issued first (overlap with radix latency) ----
  {
    int row = tid >> 1, half = tid & 1;
    const unsigned short* vsrc =
        Vbf + (size_t)(b * LL + kc * KCH + row) * DMM + h * EE + half * 16;
    *(uint4*)(&Vs[row][half * 16]) = *(const uint4*)vsrc;
    *(uint4*)(&Vs[row][half * 16 + 8]) = *(const uint4*)(vsrc + 8);
  }
  int kk = tid & (KCH - 1), qh = tid >> 7;  // 2 threads/key, 20 queries each
  float4 kr[8];
  {
    const float4* kp =
        (const float4*)(K + ((size_t)(b * LL + kc * KCH + kk)) * DMM + h * EE);
#pragma unroll
    for (int j = 0; j < 8; ++j) kr[j] = kp[j];
  }

  // ---- exact top-40 radix select on M[bh] (R7-proven rounds) ----
  u64 kreg[8];
#pragma unroll
  for (int r = 0; r < 8; ++r) {
    int l = tid + 256 * r;
    float v = M[(size_t)bh * LL + l];
    uint32_t bits = __float_as_uint(v);
    uint32_t kv = (bits & 0x80000000u) ? ~bits : (bits | 0x80000000u);
    kreg[r] = ((u64)kv << 32) | (uint32_t)(2047 - l);
  }
  u64 prefix = 0;
  int rank = UU;
  for (int round = 0; round < 8; ++round) {
    int shift = 56 - 8 * round;
    u64 maskTop = (round == 0) ? 0ull : (~0ull << (64 - 8 * round));
    hist[tid] = 0;
    __syncthreads();
#pragma unroll
    for (int r = 0; r < 8; ++r) {
      u64 k = kreg[r];
      if ((k & maskTop) == prefix)
        atomicAdd(&hist[(unsigned int)((k >> shift) & 0xFFu)], 1u);
    }
    __syncthreads();
    sA[tid] = hist[tid];
    __syncthreads();
    unsigned int* src = sA;
    unsigned int* dst = sB;
    for (int off = 1; off < 256; off <<= 1) {
      unsigned int v = src[tid] + ((tid + off < 256) ? src[tid + off] : 0u);
      dst[tid] = v;
      __syncthreads();
      unsigned int* tmpp = src; src = dst; dst = tmpp;
    }
    unsigned int Sb = src[tid];
    unsigned int Snext = (tid < 255) ? src[tid + 1] : 0u;
    if (Sb >= (unsigned int)rank && Snext < (unsigned int)rank) tbv = (unsigned int)tid;
    __syncthreads();
    unsigned int tb = tbv;
    unsigned int above = (tb < 255u) ? src[tb + 1] : 0u;
    rank -= (int)above;
    prefix |= ((u64)tb) << shift;
    __syncthreads();
  }
  u64 T = prefix;   // exact 40th-largest key
  // ---- deterministic rank: exclusive prefix over tid of per-thread selected counts ----
  int myCnt = 0;
#pragma unroll
  for (int r = 0; r < 8; ++r) myCnt += (kreg[r] >= T) ? 1 : 0;
  sA[tid] = (unsigned int)myCnt;
  __syncthreads();
  {
    unsigned int* src = sA;
    unsigned int* dst = sB;
    for (int off = 1; off < 256; off <<= 1) {
      unsigned int v = src[tid] + ((tid >= off) ? src[tid - off] : 0u);
      dst[tid] = v;
      __syncthreads();
      unsigned int* tmpp = src; src = dst; dst = tmpp;
    }
    int pos = (int)src[tid] - myCnt;   // exclusive prefix
    bool wmap = (kc == 0);
#pragma unroll
    for (int r = 0; r < 8; ++r) {
      u64 k = kreg[r];
      int l = 2047 - (int)(uint32_t)(k & 0xFFFFFFFFu);
      unsigned char mv = 0;
      if (k >= T) {
        qrows[pos] = l;
        mv = (unsigned char)(pos + 1);
        pos++;
      }
      if (wmap) mapb[bh * 2048 + l] = mv;
    }
  }
  __syncthreads();

  // ---- Q staging for the 40 selected rows ----
  for (int t = tid; t < 40 * 32; t += 256) {
    int q = t >> 5, d = t & 31;
    Qs[q][d] = Q[((size_t)(b * LL + qrows[q])) * DMM + h * EE + d];
  }
  __syncthreads();
  // ---- scores ----
  {
    const float scale = 0.17677669529663687f;
    for (int q = qh * 20; q < qh * 20 + 20; ++q) {
      const float4* qp = (const float4*)Qs[q];
      float s = 0.f;
#pragma unroll
      for (int j = 0; j < 8; ++j) {
        float4 qv = qp[j];
        s += qv.x * kr[j].x + qv.y * kr[j].y + qv.z * kr[j].z + qv.w * kr[j].w;
      }
      ps[q][kk] = f2b(s * scale);
    }
  }
  __syncthreads();
  int kg = lane >> 5, d = lane & 31;
  for (int qq = 0; qq < 10; ++qq) {
    int q = wv * 10 + qq;
    float mx = fmaxf(bfbits(ps[q][lane]), bfbits(ps[q][lane + 64]));
#pragma unroll
    for (int off = 32; off > 0; off >>= 1) mx = fmaxf(mx, __shfl_xor(mx, off));
    float e0 = expf(bfbits(ps[q][lane]) - mx);
    float e1 = expf(bfbits(ps[q][lane + 64]) - mx);
    ps[q][lane] = f2b(e0);
    ps[q][lane + 64] = f2b(e1);
    float sum = wave_sum(e0 + e1);
    float o = 0.f;
#pragma unroll 8
    for (int j = 0; j < KCH / 2; ++j) {
      int r = 2 * j + kg;
      o += bfbits(ps[q][r]) * bfbits(Vs[r][d]);
    }
    o += __shfl_xor(o, 32);
    size_t base = ((size_t)bh * UU + q) * KC + kc;
    if (lane == 0) { pm[base] = mx; pl[base] = sum; }
    if (lane < 32) po[base * 32 + d] = o;
  }
}

// ---------------- bn+elu from atomic stats (+vmp zero for next layer) ----------------
__global__ __launch_bounds__(256) void bn_elu(const float* __restrict__ Y,
                                              const float* __restrict__ stp,
                                              const float* __restrict__ stp2,
                                              const float* __restrict__ g,
                                              const float* __restrict__ bb,
                                              float* __restrict__ X,
                                              unsigned short* __restrict__ XB,
                                              unsigned short* __restrict__ XL,
                                              float* __restrict__ vmpZ) {
  int gid = blockIdx.x * 256 + threadIdx.x;
  if (gid < BB * DMM) vmpZ[gid] = 0.f;
  int d = gid & 255;
  float mean = stp[d] * (1.0f / (float)ROWS);
  float var = stp2[d] * (1.0f / (float)ROWS) - mean * mean;
  float rstd = rsqrtf(var + 1e-5f);
  float v = (Y[gid] - mean) * rstd * g[d] + bb[d];
  float r = v > 0.f ? v : expm1f(v);
  X[gid] = r;
  unsigned short hi = f2b(r);
  XB[gid] = hi;
  XL[gid] = f2b(r - bfbits(hi));
}

extern "C" void kernel_launch(void* const* d_in, const int* in_sizes, int n_in,
                              void* d_out, int out_size, void* d_ws, size_t ws_size,
                              hipStream_t stream) {
  (void)in_sizes; (void)n_in; (void)out_size; (void)ws_size;

  // ---- workspace layout ----
  float* xbuf = (float*)d_ws;
  float* kb   = xbuf + NELEM;
  float* qb   = kb + NELEM;   // aliases tmp (Q dead after attn_part)
  float* tmp  = qb;
  float* Mbuf = qb + NELEM;
  float* vmp  = Mbuf + BB * HH * LL;
  float* stp  = vmp + BB * DMM;
  float* stp2 = stp + DMM;
  float* wp   = stp2 + DMM;
  const int wsz[23] = {
      NELEM,
      NLL * DMM * DMM, NLL * DMM,
      NLL * DMM * DMM, NLL * DMM,
      NLL * DMM * DMM, NLL * DMM,
      NLL * DMM * DMM, NLL * DMM,
      NLL * ITR * DMM, NLL * ITR,
      NLL * DMM * ITR, NLL * DMM,
      NLL * DMM, NLL * DMM,
      NLL * DMM, NLL * DMM,
      (NLL - 1) * DMM * DMM * 3, (NLL - 1) * DMM,
      (NLL - 1) * DMM, (NLL - 1) * DMM,
      DMM, DMM
  };
  float* fptr[23];
  fptr[0] = xbuf;
  for (int i = 1; i < 23; ++i) { fptr[i] = wp; wp += wsz[i]; }
  float* pm = wp;
  float* pl = pm + 32 * UU * KC;
  float* po = pl + 32 * UU * KC;
  unsigned short* xbf   = (unsigned short*)(po + 32 * UU * KC * 32);
  unsigned short* xlo   = xbf + NELEM;
  unsigned short* vbf   = xlo + NELEM;
  unsigned short* wqbf  = vbf + NELEM;
  unsigned short* wkbf  = wqbf + NLL * DMM * DMM;
  unsigned short* wvbf  = wkbf + NLL * DMM * DMM;
  unsigned short* wobf  = wvbf + NLL * DMM * DMM;
  unsigned short* dcwT  = wobf + NLL * DMM * DMM;
  u64* cand = (u64*)(dcwT + (NLL - 1) * 3 * DMM * DMM);  // layout kept (unused now)
  int* topb = (int*)(cand + 256 * 40);                    // layout kept (unused now)
  int* flag = topb + BB * HH * UU;
  unsigned char* mapb = (unsigned char*)(flag + 1);  // 32*2048

  // ---- convert (+cheap inline dtype probe, +dcw repack, +vmp zero, +flag publish) ----
  CvtArgs ca;
  int totalBlk = 0;
  for (int i = 0; i < 23; ++i) {
    ca.src[i] = d_in[i];
    ca.dstF[i] = fptr[i];
    ca.dstB[i] = nullptr;
    ca.dstL[i] = nullptr;
    ca.n[i] = wsz[i];
    ca.blkStart[i] = totalBlk;
    totalBlk += (wsz[i] + 255) / 256;
  }
  ca.blkStart[23] = totalBlk;
  ca.dstB[0] = xbf;  ca.dstL[0] = xlo;
  ca.dstB[1] = wqbf;
  ca.dstB[3] = wkbf;
  ca.dstB[5] = wvbf;
  ca.dstB[7] = wobf;
  ca.dcwT = dcwT;
  ca.vmpZ = vmp;
  ca.flagOut = flag;
  mega_cvt<<<totalBlk + 1, 256, 0, stream>>>(ca);

  dim3 gqkv(ROWS / 128, DMM / 64, 3);
  dim3 g64(ROWS / 64, DMM / 64);

  for (int i = 0; i < NLL; ++i) {
    QKVArgs qa;
    qa.W[0] = wqbf + (size_t)i * DMM * DMM;
    qa.W[1] = wkbf + (size_t)i * DMM * DMM;
    qa.W[2] = wvbf + (size_t)i * DMM * DMM;
    qa.bias[0] = fptr[2] + i * DMM;
    qa.bias[1] = fptr[4] + i * DMM;
    qa.bias[2] = fptr[6] + i * DMM;
    qa.Cq = qb; qa.Ck = kb; qa.Cv = vbf;
    qa.vmp = vmp;
    gemm_qkv<<<gqkv, 256, 0, stream>>>(xbf, xlo, qa);

    uint32_t ki0, ki1, a0, a1, b0, b1;
    threefry2x32(0u, 42u, 0u, (uint32_t)i, &ki0, &ki1);
    threefry2x32(ki0, ki1, 0u, 2u, &a0, &a1);
    threefry2x32(ki0, ki1, 1u, 3u, &b0, &b1);
    (void)a0; (void)b0;

    m_kernel3<<<BB * 512, 256, 0, stream>>>(qb, kb, a1, b1, Mbuf);
    attn_part<<<dim3(KC, BB * HH), 256, 0, stream>>>(qb, kb, vbf, Mbuf, mapb,
                                                     pm, pl, po);

    bool last = (i == NLL - 1);
    oproj_tail<<<ROWS / OTR, 512, 0, stream>>>(
        vmp, mapb, pm, pl, po,
        wobf + (size_t)i * DMM * DMM, fptr[8] + i * DMM,
        xbuf,
        fptr[13] + i * DMM, fptr[14] + i * DMM,
        fptr[9] + (size_t)i * ITR * DMM, fptr[10] + i * ITR,
        fptr[11] + (size_t)i * DMM * ITR, fptr[12] + i * DMM,
        fptr[15] + i * DMM, fptr[16] + i * DMM,
        xbuf, xbf, xlo,
        fptr[21], fptr[22], last ? d_out : nullptr, flag, stp, stp2);

    if (!last) {
      gemm_conv<<<g64, 256, 0, stream>>>(xbf, dcwT + (size_t)i * 3 * DMM * DMM,
                                         fptr[18] + i * DMM, tmp, stp, stp2);
      bn_elu<<<NELEM / 256, 256, 0, stream>>>(tmp, stp, stp2, fptr[19] + i * DMM,
                                              fptr[20] + i * DMM, xbuf, xbf, xlo, vmp);
    }
  }
}

// Round 14
// 477.723 us; speedup vs baseline: 1.1594x; 1.0199x over previous
//
#include <hip/hip_runtime.h>
#include <stdint.h>

#define BB 4
#define LL 2048
#define DMM 256
#define HH 8
#define EE 32
#define NLL 3
#define ITR 16
#define UU 40
#define KC 16                 // split-K chunks
#define KCH 128               // keys per chunk
#define ROWS (BB*LL)          // 8192
#define NELEM (ROWS*DMM)      // 2097152
#define OTR 32                // oproj_tail rows per block (32 -> 256 blocks, 512 thr each)

typedef __attribute__((ext_vector_type(8))) short short8;
typedef __attribute__((ext_vector_type(4))) float f32x4;
typedef unsigned long long u64;

#define GLDS16(g, l)                                                        \
  __builtin_amdgcn_global_load_lds(                                         \
      (const __attribute__((address_space(1))) uint32_t*)(g),               \
      (__attribute__((address_space(3))) uint32_t*)(l), 16, 0, 0)

// ---------------- bf16 bit helpers (RNE) ----------------
__device__ __forceinline__ float bfbits(unsigned short u) {
  return __uint_as_float(((uint32_t)u) << 16);
}
__device__ __forceinline__ unsigned short f2b(float f) {
  uint32_t u = __float_as_uint(f);
  uint32_t r = (u + 0x7FFFu + ((u >> 16) & 1u)) >> 16;
  return (unsigned short)r;
}

// ---------------- threefry2x32 (exact JAX semantics) ----------------
__host__ __device__ inline void threefry2x32(uint32_t k0, uint32_t k1,
                                             uint32_t x0, uint32_t x1,
                                             uint32_t* o0, uint32_t* o1) {
  uint32_t ks2 = k0 ^ k1 ^ 0x1BD11BDAu;
  x0 += k0; x1 += k1;
#define TFR(r) { x0 += x1; x1 = (x1 << (r)) | (x1 >> (32 - (r))); x1 ^= x0; }
  TFR(13) TFR(15) TFR(26) TFR(6)
  x0 += k1;  x1 += ks2 + 1u;
  TFR(17) TFR(29) TFR(16) TFR(24)
  x0 += ks2; x1 += k0 + 2u;
  TFR(13) TFR(15) TFR(26) TFR(6)
  x0 += k0;  x1 += k1 + 3u;
  TFR(17) TFR(29) TFR(16) TFR(24)
  x0 += k1;  x1 += ks2 + 4u;
  TFR(13) TFR(15) TFR(26) TFR(6)
  x0 += ks2; x1 += k0 + 5u;
#undef TFR
  *o0 = x0; *o1 = x1;
}

__device__ __forceinline__ float wave_sum(float v) {
#pragma unroll
  for (int off = 32; off > 0; off >>= 1) v += __shfl_xor(v, off);
  return v;
}

// ---------------- mega convert (+hi/lo splits, +dcw repack, +vmp zero, +cheap inline probe) -
struct CvtArgs {
  const void* src[23];
  float* dstF[23];
  unsigned short* dstB[23];
  unsigned short* dstL[23];
  int n[23];
  int blkStart[24];
  unsigned short* dcwT;
  float* vmpZ;     // zero BB*DMM floats
  int* flagOut;    // published dtype flag
};
__global__ __launch_bounds__(256) void mega_cvt(CvtArgs a) {
  // ---- inline dtype probe: 512 shorts (2/thread). bf16 data -> cnt~0; f32 data -> cnt~228.
  __shared__ int cnt;
  if (threadIdx.x == 0) cnt = 0;
  __syncthreads();
  {
    const unsigned short* u = (const unsigned short*)a.src[0];
    int bad = 0;
#pragma unroll
    for (int rep = 0; rep < 2; ++rep) {
      float v = bfbits(u[threadIdx.x + 256 * rep]);
      float av = fabsf(v);
      bool ok = (v == 0.0f) || (av > 1e-4f && av < 100.0f);
      if (!ok) bad++;
    }
    if (bad) atomicAdd(&cnt, bad);
  }
  __syncthreads();
  int isf32 = (cnt > 25) ? 1 : 0;

  int bid = blockIdx.x;
  if (bid == a.blkStart[23]) {
    for (int t = threadIdx.x; t < BB * DMM; t += 256) a.vmpZ[t] = 0.f;
    if (threadIdx.x == 0) *a.flagOut = isf32;
    return;
  }
  int i = 0;
  while (i < 22 && bid >= a.blkStart[i + 1]) ++i;
  int e = (bid - a.blkStart[i]) * 256 + (int)threadIdx.x;
  if (e >= a.n[i]) return;
  float v; unsigned short rw;
  if (isf32) { v = ((const float*)a.src[i])[e]; rw = f2b(v); }
  else       { rw = ((const unsigned short*)a.src[i])[e]; v = bfbits(rw); }
  a.dstF[i][e] = v;
  if (a.dstB[i]) a.dstB[i][e] = rw;
  if (a.dstL[i]) a.dstL[i][e] = f2b(v - bfbits(rw));
  if (i == 17) {  // dcw: [ly][n][k][t] -> [ly][t][n][k] bf16
    int ly = e / 196608;
    int r = e - ly * 196608;
    int n = r / 768;
    int rem = r - n * 768;
    int k = rem / 3, t = rem - k * 3;
    a.dcwT[ly * 196608 + t * 65536 + n * 256 + k] = rw;
  }
}

// ---------------- QKV MFMA GEMM: z=0:Q 1:K (hi/lo 2-pass, f32 out) 2:V (bf16 out + vmean) --
// (round-0 proven version: BK=32, [128][32]/[64][32] LDS)
struct QKVArgs {
  const unsigned short* W[3];
  const float* bias[3];
  float* Cq;
  float* Ck;
  unsigned short* Cv;
  float* vmp;
};
__global__ __launch_bounds__(256) void gemm_qkv(const unsigned short* __restrict__ Ahi,
                                                const unsigned short* __restrict__ Alo,
                                                QKVArgs qa) {
  __shared__ __attribute__((aligned(16))) unsigned short AsH[128][32];
  __shared__ __attribute__((aligned(16))) unsigned short AsL[128][32];
  __shared__ __attribute__((aligned(16))) unsigned short Bs[64][32];
  int z = blockIdx.z;
  const unsigned short* W = qa.W[z];
  const float* bias = qa.bias[z];
  bool twoPass = (z < 2);
  int bm = blockIdx.x * 128, bn = blockIdx.y * 64;
  int tid = threadIdx.x;
  int wv = tid >> 6, lane = tid & 63;
  int wm = wv >> 1, wn = wv & 1;
  int l15 = lane & 15, quad = lane >> 4;
  int lrow = lane >> 2, lseg = lane & 3;
  f32x4 acc[4][2];
#pragma unroll
  for (int i = 0; i < 4; ++i)
#pragma unroll
    for (int j = 0; j < 2; ++j) acc[i][j] = (f32x4){0.f, 0.f, 0.f, 0.f};
  for (int k0 = 0; k0 < 256; k0 += 32) {
    __syncthreads();
#pragma unroll
    for (int s = 0; s < 2; ++s) {
      int brow = (wv + s * 4) * 16;
      size_t goff = (size_t)(bm + brow + lrow) * 256 + k0 + lseg * 8;
      GLDS16(Ahi + goff, &AsH[brow][0]);
      if (twoPass) GLDS16(Alo + goff, &AsL[brow][0]);
    }
    {
      int brow = wv * 16;
      GLDS16(W + (size_t)(bn + brow + lrow) * 256 + k0 + lseg * 8, &Bs[brow][0]);
    }
    __syncthreads();
    short8 ah[4], bfr[2];
#pragma unroll
    for (int mt = 0; mt < 4; ++mt)
      ah[mt] = *(const short8*)(&AsH[wm * 64 + mt * 16 + l15][quad * 8]);
#pragma unroll
    for (int nt = 0; nt < 2; ++nt)
      bfr[nt] = *(const short8*)(&Bs[wn * 32 + nt * 16 + l15][quad * 8]);
#pragma unroll
    for (int mt = 0; mt < 4; ++mt)
#pragma unroll
      for (int nt = 0; nt < 2; ++nt)
        acc[mt][nt] = __builtin_amdgcn_mfma_f32_16x16x32_bf16(ah[mt], bfr[nt],
                                                              acc[mt][nt], 0, 0, 0);
    if (twoPass) {
      short8 al[4];
#pragma unroll
      for (int mt = 0; mt < 4; ++mt)
        al[mt] = *(const short8*)(&AsL[wm * 64 + mt * 16 + l15][quad * 8]);
#pragma unroll
      for (int mt = 0; mt < 4; ++mt)
#pragma unroll
        for (int nt = 0; nt < 2; ++nt)
          acc[mt][nt] = __builtin_amdgcn_mfma_f32_16x16x32_bf16(al[mt], bfr[nt],
                                                                acc[mt][nt], 0, 0, 0);
    }
  }
  float* C = (z == 0) ? qa.Cq : qa.Ck;
#pragma unroll
  for (int nt = 0; nt < 2; ++nt) {
    int n = bn + wn * 32 + nt * 16 + l15;
    float bv = bias[n];
    float csum = 0.f;
#pragma unroll
    for (int mt = 0; mt < 4; ++mt)
#pragma unroll
      for (int r = 0; r < 4; ++r) {
        int m = bm + wm * 64 + mt * 16 + quad * 4 + r;
        float val = acc[mt][nt][r] + bv;
        if (z < 2) {
          C[(size_t)m * 256 + n] = val;
        } else {
          qa.Cv[(size_t)m * 256 + n] = f2b(val);
          csum += val;
        }
      }
    if (z == 2) {
      csum += __shfl_xor(csum, 16);
      csum += __shfl_xor(csum, 32);
      if (quad == 0) {
        int b = bm >> 11;
        atomicAdd(&qa.vmp[b * DMM + n], csum);
      }
    }
  }
}

// ---------------- FUSED O-proj GEMM (32x256, 512 thr) + tail, ctx-merge hoisted (R12) -----
__global__ __launch_bounds__(512) void oproj_tail(const float* __restrict__ vmp,
                                                  const unsigned char* __restrict__ mapb,
                                                  const float* __restrict__ pm,
                                                  const float* __restrict__ pl,
                                                  const float* __restrict__ po,
                                                  const unsigned short* __restrict__ W,
                                                  const float* __restrict__ bias,
                                                  const float* __restrict__ X,
                                                  const float* __restrict__ g1,
                                                  const float* __restrict__ b1ln,
                                                  const float* __restrict__ w1,
                                                  const float* __restrict__ b1,
                                                  const float* __restrict__ w2,
                                                  const float* __restrict__ b2,
                                                  const float* __restrict__ g2,
                                                  const float* __restrict__ b2ln,
                                                  float* __restrict__ Out,
                                                  unsigned short* __restrict__ OutB,
                                                  unsigned short* __restrict__ OutL,
                                                  const float* __restrict__ fing,
                                                  const float* __restrict__ finb,
                                                  void* __restrict__ finOut,
                                                  const int* __restrict__ flag,
                                                  float* __restrict__ stpZ,
                                                  float* __restrict__ stp2Z) {
  __shared__ __attribute__((aligned(16))) unsigned short As[OTR][DMM];  // full ctx panel
  __shared__ __attribute__((aligned(16))) unsigned short Bs[256][32];
  __shared__ float Cs[OTR][DMM];
  __shared__ float xs[8][DMM];
  int tid = threadIdx.x;
  if (blockIdx.x == 0 && tid < DMM) {
    stpZ[tid] = 0.f;
    stp2Z[tid] = 0.f;
  }
  int bm = blockIdx.x * OTR;
  int wv = tid >> 6, lane = tid & 63;
  int l15 = lane & 15, quad = lane >> 4;
  int b = bm >> 11, l0 = bm & 2047;
  const float invL = 1.0f / (float)LL;

  // ---- phase 1: ctx A-panel for all 8 heads, once, full-block parallel ----
#pragma unroll
  for (int uu = 0; uu < 2; ++uu) {
    int u = tid * 2 + uu;            // 0..1023
    int arow = u >> 5;               // 32 rows
    int sub = u & 31;
    int h = sub >> 2, adg = sub & 3; // 8 heads x 4 col-groups
    int bh = b * HH + h;
    int l = l0 + arow;
    int q = (int)mapb[bh * 2048 + l];
    unsigned short outv[8];
    if (q) {
      size_t base = ((size_t)bh * UU + (q - 1)) * KC;
      float Mx = -1e30f;
#pragma unroll
      for (int kc = 0; kc < KC; ++kc) Mx = fmaxf(Mx, pm[base + kc]);
      float Ls = 0.f;
      float sc[KC];
#pragma unroll
      for (int kc = 0; kc < KC; ++kc) {
        sc[kc] = expf(pm[base + kc] - Mx);
        Ls += pl[base + kc] * sc[kc];
      }
      float inv = 1.0f / Ls;
#pragma unroll
      for (int j = 0; j < 8; ++j) {
        int dl = adg * 8 + j;
        float o = 0.f;
#pragma unroll
        for (int kc = 0; kc < KC; ++kc) o += po[(base + kc) * 32 + dl] * sc[kc];
        outv[j] = f2b(o * inv);
      }
    } else {
      const float* vp = vmp + b * DMM + h * EE + adg * 8;
#pragma unroll
      for (int j = 0; j < 8; ++j) outv[j] = f2b(vp[j] * invL);
    }
    *(uint4*)(&As[arow][h * EE + adg * 8]) = *(const uint4*)outv;
  }
  __syncthreads();

  // ---- phase 2: GEMM loop (pure stage+MFMA) ----
  f32x4 acc[2][2];
#pragma unroll
  for (int i = 0; i < 2; ++i)
#pragma unroll
    for (int j = 0; j < 2; ++j) acc[i][j] = (f32x4){0.f, 0.f, 0.f, 0.f};
  for (int k0 = 0; k0 < 256; k0 += 32) {
    if (k0) __syncthreads();
    {  // stage all 256 B-rows once per block (8 waves x 2 rounds x 16 rows)
      int lrw = lane >> 2, lsg = lane & 3;
#pragma unroll
      for (int s = 0; s < 2; ++s) {
        int brow = s * 128 + wv * 16;
        GLDS16(W + (size_t)(brow + lrw) * 256 + k0 + lsg * 8, &Bs[brow][0]);
      }
    }
    __syncthreads();
    short8 af[2], bfr[2];
#pragma unroll
    for (int mt = 0; mt < 2; ++mt)
      af[mt] = *(const short8*)(&As[mt * 16 + l15][k0 + quad * 8]);
#pragma unroll
    for (int nt = 0; nt < 2; ++nt)
      bfr[nt] = *(const short8*)(&Bs[wv * 32 + nt * 16 + l15][quad * 8]);
#pragma unroll
    for (int mt = 0; mt < 2; ++mt)
#pragma unroll
      for (int nt = 0; nt < 2; ++nt)
        acc[mt][nt] = __builtin_amdgcn_mfma_f32_16x16x32_bf16(af[mt], bfr[nt],
                                                              acc[mt][nt], 0, 0, 0);
  }
  // epilogue -> LDS (replaces tmp)
#pragma unroll
  for (int nt = 0; nt < 2; ++nt) {
    int n = wv * 32 + nt * 16 + l15;
    float bv = bias[n];
#pragma unroll
    for (int mt = 0; mt < 2; ++mt)
#pragma unroll
      for (int r = 0; r < 4; ++r)
        Cs[mt * 16 + quad * 4 + r][n] = acc[mt][nt][r] + bv;
  }
  __syncthreads();
  // ---- enc_tail body, verbatim, 4 rows per wave ----
  for (int rr = 0; rr < 4; ++rr) {
    int lr = wv * 4 + rr;
    size_t row = (size_t)bm + lr;
    const float* xr = X + row * DMM;
    const float* tr = Cs[lr];
    float v[4];
#pragma unroll
    for (int i = 0; i < 4; ++i) v[i] = xr[lane + 64 * i] + tr[lane + 64 * i];
    float s = wave_sum(v[0] + v[1] + v[2] + v[3]);
    float m = s * (1.0f / (float)DMM);
    float sq = 0.f;
#pragma unroll
    for (int i = 0; i < 4; ++i) { float d = v[i] - m; sq += d * d; }
    sq = wave_sum(sq);
    float rstd = rsqrtf(sq * (1.0f / (float)DMM) + 1e-5f);
    float xv[4];
#pragma unroll
    for (int i = 0; i < 4; ++i) {
      int d = lane + 64 * i;
      xv[i] = (v[i] - m) * rstd * g1[d] + b1ln[d];
      xs[wv][d] = xv[i];
    }
    __syncthreads();
    int f = lane & 15, qtr = lane >> 4;
    const float* w1p = w1 + f * DMM + qtr * 64;
    const float* xq = &xs[wv][qtr * 64];
    float pacc = 0.f;
#pragma unroll 8
    for (int d = 0; d < 64; ++d) pacc += xq[d] * w1p[d];
    pacc += __shfl_xor(pacc, 16);
    pacc += __shfl_xor(pacc, 32);
    float y1 = fmaxf(pacc + b1[f], 0.0f);
    float y1v[16];
#pragma unroll
    for (int ff = 0; ff < 16; ++ff) y1v[ff] = __shfl(y1, ff);
#pragma unroll
    for (int i = 0; i < 4; ++i) {
      int d = lane + 64 * i;
      const float* w2p = w2 + d * ITR;
      float a = b2[d];
#pragma unroll
      for (int ff = 0; ff < 16; ++ff) a += y1v[ff] * w2p[ff];
      v[i] = xv[i] + a;
    }
    s = wave_sum(v[0] + v[1] + v[2] + v[3]);
    m = s * (1.0f / (float)DMM);
    sq = 0.f;
#pragma unroll
    for (int i = 0; i < 4; ++i) { float d = v[i] - m; sq += d * d; }
    sq = wave_sum(sq);
    rstd = rsqrtf(sq * (1.0f / (float)DMM) + 1e-5f);
    float vv[4];
#pragma unroll
    for (int i = 0; i < 4; ++i) {
      int d = lane + 64 * i;
      float val = (v[i] - m) * rstd * g2[d] + b2ln[d];
      vv[i] = val;
      Out[row * DMM + d] = val;
      unsigned short hi = f2b(val);
      OutB[row * DMM + d] = hi;
      OutL[row * DMM + d] = f2b(val - bfbits(hi));
    }
    if (finOut) {
      s = wave_sum(vv[0] + vv[1] + vv[2] + vv[3]);
      m = s * (1.0f / (float)DMM);
      sq = 0.f;
#pragma unroll
      for (int i = 0; i < 4; ++i) { float d = vv[i] - m; sq += d * d; }
      sq = wave_sum(sq);
      rstd = rsqrtf(sq * (1.0f / (float)DMM) + 1e-5f);
      int isf32 = *flag;
#pragma unroll
      for (int i = 0; i < 4; ++i) {
        int d = lane + 64 * i;
        float val = (vv[i] - m) * rstd * fing[d] + finb[d];
        if (isf32) ((float*)finOut)[row * DMM + d] = val;
        else       ((unsigned short*)finOut)[row * DMM + d] = f2b(val);
      }
    }
  }
}

// ---------------- conv GEMM: A window staged once per k0, 3 taps from LDS ----------------
__global__ __launch_bounds__(256) void gemm_conv(const unsigned short* __restrict__ A,
                                                 const unsigned short* __restrict__ W,
                                                 const float* __restrict__ bias,
                                                 float* __restrict__ C,
                                                 float* __restrict__ stp,
                                                 float* __restrict__ stp2) {
  __shared__ __attribute__((aligned(16))) unsigned short As[80][32];
  __shared__ __attribute__((aligned(16))) unsigned short Bs[192][32];
  int bm = blockIdx.x * 64, bn = blockIdx.y * 64;
  int tid = threadIdx.x;
  int wv = tid >> 6, lane = tid & 63;
  int wm = wv >> 1, wn = wv & 1;
  int l15 = lane & 15, quad = lane >> 4;
  int lrow = lane >> 2, lseg = lane & 3;
  int bbase = bm & ~2047, l0 = bm & 2047;
  f32x4 acc[2][2];
#pragma unroll
  for (int i = 0; i < 2; ++i)
#pragma unroll
    for (int j = 0; j < 2; ++j) acc[i][j] = (f32x4){0.f, 0.f, 0.f, 0.f};
  for (int k0 = 0; k0 < 256; k0 += 32) {
    __syncthreads();
    for (int c = wv; c < 5; c += 4) {
      int i0 = c * 16;
      int l = (l0 - 1 + i0 + lrow + 2048) & 2047;
      GLDS16(A + (size_t)(bbase | l) * 256 + k0 + lseg * 8, &As[i0][0]);
    }
    for (int c = wv; c < 12; c += 4) {
      int i0 = c * 16;
      int tap = c >> 2, brow = (c & 3) * 16;
      GLDS16(W + (size_t)tap * 65536 + (size_t)(bn + brow + lrow) * 256 + k0 + lseg * 8,
             &Bs[i0][0]);
    }
    __syncthreads();
#pragma unroll
    for (int tap = 0; tap < 3; ++tap) {
      short8 af[2], bfr[2];
#pragma unroll
      for (int mt = 0; mt < 2; ++mt)
        af[mt] = *(const short8*)(&As[wm * 32 + mt * 16 + l15 + tap][quad * 8]);
#pragma unroll
      for (int nt = 0; nt < 2; ++nt)
        bfr[nt] = *(const short8*)(&Bs[tap * 64 + wn * 32 + nt * 16 + l15][quad * 8]);
#pragma unroll
      for (int mt = 0; mt < 2; ++mt)
#pragma unroll
        for (int nt = 0; nt < 2; ++nt)
          acc[mt][nt] = __builtin_amdgcn_mfma_f32_16x16x32_bf16(af[mt], bfr[nt],
                                                                acc[mt][nt], 0, 0, 0);
    }
  }
#pragma unroll
  for (int nt = 0; nt < 2; ++nt) {
    int n = bn + wn * 32 + nt * 16 + l15;
    float bv = bias[n];
    float s = 0.f, s2 = 0.f;
#pragma unroll
    for (int mt = 0; mt < 2; ++mt)
#pragma unroll
      for (int r = 0; r < 4; ++r) {
        int m = bm + wm * 32 + mt * 16 + quad * 4 + r;
        float val = acc[mt][nt][r] + bv;
        C[(size_t)m * 256 + n] = val;
        s += val;
        s2 += val * val;
      }
    s  += __shfl_xor(s, 16);   s  += __shfl_xor(s, 32);
    s2 += __shfl_xor(s2, 16);  s2 += __shfl_xor(s2, 32);
    if (quad == 0) {
      atomicAdd(&stp[n], s);
      atomicAdd(&stp2[n], s2);
    }
  }
}

// ---------------- M scores: wave per (b,l), inline threefry, XCD-affinity swizzle ----------
__global__ __launch_bounds__(256) void m_kernel3(const float* __restrict__ Q,
                                                 const float* __restrict__ K,
                                                 uint32_t k20, uint32_t k21,
                                                 float* __restrict__ M) {
  int bid = blockIdx.x;
  int blk = (bid & 7) * 256 + (bid >> 3);   // XCD-affinity remap (pure perf, no semantics)
  int b = blk >> 9, lc = blk & 511;
  int wave = threadIdx.x >> 6, lane = threadIdx.x & 63;
  int l = lc * 4 + wave;
  int myidx = 0;
  if (lane < UU) {
    int j = l * UU + lane;
    uint32_t o0, o1;
    const int half = (LL * UU) / 2;  // 40960
    if (j < half) {
      threefry2x32(k20, k21, (uint32_t)j, (uint32_t)(j + half), &o0, &o1);
      myidx = (int)(o0 & (LL - 1));
    } else {
      threefry2x32(k20, k21, (uint32_t)(j - half), (uint32_t)j, &o0, &o1);
      myidx = (int)(o1 & (LL - 1));
    }
  }
  float4 q4 = *(const float4*)(Q + ((size_t)(b * LL + l)) * DMM + lane * 4);
  const float* Kb = K + (size_t)b * LL * DMM;
  float mx = -1e30f, sm = 0.f;
#pragma unroll 8
  for (int u = 0; u < UU; ++u) {
    int kidx = __shfl(myidx, u);
    float4 k4 = *(const float4*)(Kb + (size_t)kidx * DMM + lane * 4);
    float s = q4.x * k4.x + q4.y * k4.y + q4.z * k4.z + q4.w * k4.w;
    s += __shfl_xor(s, 1);
    s += __shfl_xor(s, 2);
    s += __shfl_xor(s, 4);
    mx = fmaxf(mx, s);
    sm += s;
  }
  if ((lane & 7) == 0) {
    int h = lane >> 3;
    M[((size_t)(b * HH + h)) * LL + l] = mx - sm * (1.0f / (float)LL);
  }
}

// ---------------- fused topk + split-K flash attention ------------------------------------
// R8-proven structure; radix slimmed: (1) packed 43-bit key (kv<<11 | 2047-l) has the same
// (kv, idx) lexicographic order as the proven (kv<<32 | idx) -> identical selection set &
// ranks, but needs only 6 byte-rounds (the two all-zero byte rounds are dropped); (2) the
// per-round suffix scan and final rank prefix scan use in-wave shuffles + 4-entry cross-wave
// totals (integer-exact) instead of 8-barrier ping-pong. ~115 barriers -> ~32. Bitwise-same.
__global__ __launch_bounds__(256) void attn_part(const float* __restrict__ Q,
                                                 const float* __restrict__ K,
                                                 const unsigned short* __restrict__ Vbf,
                                                 const float* __restrict__ M,
                                                 unsigned char* __restrict__ mapb,
                                                 float* __restrict__ pm,
                                                 float* __restrict__ pl,
                                                 float* __restrict__ po) {
  __shared__ float Qs[40][32];
  __shared__ unsigned short ps[40][KCH];
  __shared__ unsigned short Vs[KCH][40];
  __shared__ int qrows[40];
  __shared__ unsigned int hist[256];
  __shared__ unsigned int sA[256];
  __shared__ unsigned int wtot[4];
  __shared__ unsigned int tbv;
  int kc = blockIdx.x, bh = blockIdx.y;
  int h = bh & 7, b = bh >> 3;
  int tid = threadIdx.x;
  int wv = tid >> 6, lane = tid & 63;

  // ---- independent loads issued first (overlap with radix latency) ----
  {
    int row = tid >> 1, half = tid & 1;
    const unsigned short* vsrc =
        Vbf + (size_t)(b * LL + kc * KCH + row) * DMM + h * EE + half * 16;
    *(uint4*)(&Vs[row][half * 16]) = *(const uint4*)vsrc;
    *(uint4*)(&Vs[row][half * 16 + 8]) = *(const uint4*)(vsrc + 8);
  }
  int kk = tid & (KCH - 1), qh = tid >> 7;  // 2 threads/key, 20 queries each
  float4 kr[8];
  {
    const float4* kp =
        (const float4*)(K + ((size_t)(b * LL + kc * KCH + kk)) * DMM + h * EE);
#pragma unroll
    for (int j = 0; j < 8; ++j) kr[j] = kp[j];
  }

  // ---- exact top-40 radix select on M[bh]: packed 43-bit keys, 6 rounds ----
  u64 kreg[8];
#pragma unroll
  for (int r = 0; r < 8; ++r) {
    int l = tid + 256 * r;
    float v = M[(size_t)bh * LL + l];
    uint32_t bits = __float_as_uint(v);
    uint32_t kv = (bits & 0x80000000u) ? ~bits : (bits | 0x80000000u);
    kreg[r] = ((u64)kv << 11) | (uint32_t)(2047 - l);
  }
  u64 prefix = 0;
  int rank = UU;
  for (int round = 0; round < 6; ++round) {
    int shift = 40 - 8 * round;
    u64 maskTop = (round == 0) ? 0ull : (~0ull << (48 - 8 * round));
    hist[tid] = 0;
    __syncthreads();
#pragma unroll
    for (int r = 0; r < 8; ++r) {
      u64 k = kreg[r];
      if ((k & maskTop) == prefix)
        atomicAdd(&hist[(unsigned int)((k >> shift) & 0xFFu)], 1u);
    }
    __syncthreads();
    // suffix sums: in-wave shuffle suffix scan + cross-wave totals (integer-exact)
    unsigned int s = hist[tid];
#pragma unroll
    for (int off = 1; off < 64; off <<= 1) {
      unsigned int t = __shfl_down(s, off);
      if (lane + off < 64) s += t;
    }
    if (lane == 0) wtot[wv] = s;
    __syncthreads();
    unsigned int add = 0;
#pragma unroll
    for (int w = 0; w < 4; ++w)
      if (w > wv) add += wtot[w];
    sA[tid] = s + add;
    __syncthreads();
    unsigned int Sb = sA[tid];
    unsigned int Snext = (tid < 255) ? sA[tid + 1] : 0u;
    if (Sb >= (unsigned int)rank && Snext < (unsigned int)rank) tbv = (unsigned int)tid;
    __syncthreads();
    unsigned int tb = tbv;
    unsigned int above = (tb < 255u) ? sA[tb + 1] : 0u;
    rank -= (int)above;
    prefix |= ((u64)tb) << shift;
  }
  u64 T = prefix;   // exact 40th-largest packed key
  // ---- deterministic rank: in-wave prefix + cross-wave totals (exclusive over tid) ----
  int myCnt = 0;
#pragma unroll
  for (int r = 0; r < 8; ++r) myCnt += (kreg[r] >= T) ? 1 : 0;
  {
    unsigned int p = (unsigned int)myCnt;
#pragma unroll
    for (int off = 1; off < 64; off <<= 1) {
      unsigned int t = __shfl_up(p, off);
      if (lane >= off) p += t;
    }
    if (lane == 63) wtot[wv] = p;
    __syncthreads();
    unsigned int addp = 0;
#pragma unroll
    for (int w = 0; w < 4; ++w)
      if (w < wv) addp += wtot[w];
    int pos = (int)(p + addp) - myCnt;   // exclusive prefix (same values as R8)
    bool wmap = (kc == 0);
#pragma unroll
    for (int r = 0; r < 8; ++r) {
      u64 k = kreg[r];
      int l = 2047 - (int)(uint32_t)(k & 0x7FFu);
      unsigned char mv = 0;
      if (k >= T) {
        qrows[pos] = l;
        mv = (unsigned char)(pos + 1);
        pos++;
      }
      if (wmap) mapb[bh * 2048 + l] = mv;
    }
  }
  __syncthreads();

  // ---- Q staging for the 40 selected rows ----
  for (int t = tid; t < 40 * 32; t += 256) {
    int q = t >> 5, d = t & 31;
    Qs[q][d] = Q[((size_t)(b * LL + qrows[q])) * DMM + h * EE + d];
  }
  __syncthreads();
  // ---- scores ----
  {
    const float scale = 0.17677669529663687f;
    for (int q = qh * 20; q < qh * 20 + 20; ++q) {
      const float4* qp = (const float4*)Qs[q];
      float s = 0.f;
#pragma unroll
      for (int j = 0; j < 8; ++j) {
        float4 qv = qp[j];
        s += qv.x * kr[j].x + qv.y * kr[j].y + qv.z * kr[j].z + qv.w * kr[j].w;
      }
      ps[q][kk] = f2b(s * scale);
    }
  }
  __syncthreads();
  int kg = lane >> 5, d = lane & 31;
  for (int qq = 0; qq < 10; ++qq) {
    int q = wv * 10 + qq;
    float mx = fmaxf(bfbits(ps[q][lane]), bfbits(ps[q][lane + 64]));
#pragma unroll
    for (int off = 32; off > 0; off >>= 1) mx = fmaxf(mx, __shfl_xor(mx, off));
    float e0 = expf(bfbits(ps[q][lane]) - mx);
    float e1 = expf(bfbits(ps[q][lane + 64]) - mx);
    ps[q][lane] = f2b(e0);
    ps[q][lane + 64] = f2b(e1);
    float sum = wave_sum(e0 + e1);
    float o = 0.f;
#pragma unroll 8
    for (int j = 0; j < KCH / 2; ++j) {
      int r = 2 * j + kg;
      o += bfbits(ps[q][r]) * bfbits(Vs[r][d]);
    }
    o += __shfl_xor(o, 32);
    size_t base = ((size_t)bh * UU + q) * KC + kc;
    if (lane == 0) { pm[base] = mx; pl[base] = sum; }
    if (lane < 32) po[base * 32 + d] = o;
  }
}

// ---------------- bn+elu from atomic stats (+vmp zero for next layer) ----------------
__global__ __launch_bounds__(256) void bn_elu(const float* __restrict__ Y,
                                              const float* __restrict__ stp,
                                              const float* __restrict__ stp2,
                                              const float* __restrict__ g,
                                              const float* __restrict__ bb,
                                              float* __restrict__ X,
                                              unsigned short* __restrict__ XB,
                                              unsigned short* __restrict__ XL,
                                              float* __restrict__ vmpZ) {
  int gid = blockIdx.x * 256 + threadIdx.x;
  if (gid < BB * DMM) vmpZ[gid] = 0.f;
  int d = gid & 255;
  float mean = stp[d] * (1.0f / (float)ROWS);
  float var = stp2[d] * (1.0f / (float)ROWS) - mean * mean;
  float rstd = rsqrtf(var + 1e-5f);
  float v = (Y[gid] - mean) * rstd * g[d] + bb[d];
  float r = v > 0.f ? v : expm1f(v);
  X[gid] = r;
  unsigned short hi = f2b(r);
  XB[gid] = hi;
  XL[gid] = f2b(r - bfbits(hi));
}

extern "C" void kernel_launch(void* const* d_in, const int* in_sizes, int n_in,
                              void* d_out, int out_size, void* d_ws, size_t ws_size,
                              hipStream_t stream) {
  (void)in_sizes; (void)n_in; (void)out_size; (void)ws_size;

  // ---- workspace layout ----
  float* xbuf = (float*)d_ws;
  float* kb   = xbuf + NELEM;
  float* qb   = kb + NELEM;   // aliases tmp (Q dead after attn_part)
  float* tmp  = qb;
  float* Mbuf = qb + NELEM;
  float* vmp  = Mbuf + BB * HH * LL;
  float* stp  = vmp + BB * DMM;
  float* stp2 = stp + DMM;
  float* wp   = stp2 + DMM;
  const int wsz[23] = {
      NELEM,
      NLL * DMM * DMM, NLL * DMM,
      NLL * DMM * DMM, NLL * DMM,
      NLL * DMM * DMM, NLL * DMM,
      NLL * DMM * DMM, NLL * DMM,
      NLL * ITR * DMM, NLL * ITR,
      NLL * DMM * ITR, NLL * DMM,
      NLL * DMM, NLL * DMM,
      NLL * DMM, NLL * DMM,
      (NLL - 1) * DMM * DMM * 3, (NLL - 1) * DMM,
      (NLL - 1) * DMM, (NLL - 1) * DMM,
      DMM, DMM
  };
  float* fptr[23];
  fptr[0] = xbuf;
  for (int i = 1; i < 23; ++i) { fptr[i] = wp; wp += wsz[i]; }
  float* pm = wp;
  float* pl = pm + 32 * UU * KC;
  float* po = pl + 32 * UU * KC;
  unsigned short* xbf   = (unsigned short*)(po + 32 * UU * KC * 32);
  unsigned short* xlo   = xbf + NELEM;
  unsigned short* vbf   = xlo + NELEM;
  unsigned short* wqbf  = vbf + NELEM;
  unsigned short* wkbf  = wqbf + NLL * DMM * DMM;
  unsigned short* wvbf  = wkbf + NLL * DMM * DMM;
  unsigned short* wobf  = wvbf + NLL * DMM * DMM;
  unsigned short* dcwT  = wobf + NLL * DMM * DMM;
  u64* cand = (u64*)(dcwT + (NLL - 1) * 3 * DMM * DMM);  // layout kept (unused now)
  int* topb = (int*)(cand + 256 * 40);                    // layout kept (unused now)
  int* flag = topb + BB * HH * UU;
  unsigned char* mapb = (unsigned char*)(flag + 1);  // 32*2048

  // ---- convert (+cheap inline dtype probe, +dcw repack, +vmp zero, +flag publish) ----
  CvtArgs ca;
  int totalBlk = 0;
  for (int i = 0; i < 23; ++i) {
    ca.src[i] = d_in[i];
    ca.dstF[i] = fptr[i];
    ca.dstB[i] = nullptr;
    ca.dstL[i] = nullptr;
    ca.n[i] = wsz[i];
    ca.blkStart[i] = totalBlk;
    totalBlk += (wsz[i] + 255) / 256;
  }
  ca.blkStart[23] = totalBlk;
  ca.dstB[0] = xbf;  ca.dstL[0] = xlo;
  ca.dstB[1] = wqbf;
  ca.dstB[3] = wkbf;
  ca.dstB[5] = wvbf;
  ca.dstB[7] = wobf;
  ca.dcwT = dcwT;
  ca.vmpZ = vmp;
  ca.flagOut = flag;
  mega_cvt<<<totalBlk + 1, 256, 0, stream>>>(ca);

  dim3 gqkv(ROWS / 128, DMM / 64, 3);
  dim3 g64(ROWS / 64, DMM / 64);

  for (int i = 0; i < NLL; ++i) {
    QKVArgs qa;
    qa.W[0] = wqbf + (size_t)i * DMM * DMM;
    qa.W[1] = wkbf + (size_t)i * DMM * DMM;
    qa.W[2] = wvbf + (size_t)i * DMM * DMM;
    qa.bias[0] = fptr[2] + i * DMM;
    qa.bias[1] = fptr[4] + i * DMM;
    qa.bias[2] = fptr[6] + i * DMM;
    qa.Cq = qb; qa.Ck = kb; qa.Cv = vbf;
    qa.vmp = vmp;
    gemm_qkv<<<gqkv, 256, 0, stream>>>(xbf, xlo, qa);

    uint32_t ki0, ki1, a0, a1, b0, b1;
    threefry2x32(0u, 42u, 0u, (uint32_t)i, &ki0, &ki1);
    threefry2x32(ki0, ki1, 0u, 2u, &a0, &a1);
    threefry2x32(ki0, ki1, 1u, 3u, &b0, &b1);
    (void)a0; (void)b0;

    m_kernel3<<<BB * 512, 256, 0, stream>>>(qb, kb, a1, b1, Mbuf);
    attn_part<<<dim3(KC, BB * HH), 256, 0, stream>>>(qb, kb, vbf, Mbuf, mapb,
                                                     pm, pl, po);

    bool last = (i == NLL - 1);
    oproj_tail<<<ROWS / OTR, 512, 0, stream>>>(
        vmp, mapb, pm, pl, po,
        wobf + (size_t)i * DMM * DMM, fptr[8] + i * DMM,
        xbuf,
        fptr[13] + i * DMM, fptr[14] + i * DMM,
        fptr[9] + (size_t)i * ITR * DMM, fptr[10] + i * ITR,
        fptr[11] + (size_t)i * DMM * ITR, fptr[12] + i * DMM,
        fptr[15] + i * DMM, fptr[16] + i * DMM,
        xbuf, xbf, xlo,
        fptr[21], fptr[22], last ? d_out : nullptr, flag, stp, stp2);

    if (!last) {
      gemm_conv<<<g64, 256, 0, stream>>>(xbf, dcwT + (size_t)i * 3 * DMM * DMM,
                                         fptr[18] + i * DMM, tmp, stp, stp2);
      bn_elu<<<NELEM / 256, 256, 0, stream>>>(tmp, stp, stp2, fptr[19] + i * DMM,
                                              fptr[20] + i * DMM, xbuf, xbf, xlo, vmp);
    }
  }
}

// Round 15
// 447.019 us; speedup vs baseline: 1.2390x; 1.0687x over previous
//
#include <hip/hip_runtime.h>
#include <stdint.h>

#define BB 4
#define LL 2048
#define DMM 256
#define HH 8
#define EE 32
#define NLL 3
#define ITR 16
#define UU 40
#define KC 16                 // split-K chunks
#define KCH 128               // keys per chunk
#define ROWS (BB*LL)          // 8192
#define NELEM (ROWS*DMM)      // 2097152
#define OTR 32                // oproj_tail rows per block (32 -> 256 blocks, 512 thr each)

typedef __attribute__((ext_vector_type(8))) short short8;
typedef __attribute__((ext_vector_type(4))) float f32x4;
typedef unsigned long long u64;

#define GLDS16(g, l)                                                        \
  __builtin_amdgcn_global_load_lds(                                         \
      (const __attribute__((address_space(1))) uint32_t*)(g),               \
      (__attribute__((address_space(3))) uint32_t*)(l), 16, 0, 0)

// ---------------- bf16 bit helpers (RNE) ----------------
__device__ __forceinline__ float bfbits(unsigned short u) {
  return __uint_as_float(((uint32_t)u) << 16);
}
__device__ __forceinline__ unsigned short f2b(float f) {
  uint32_t u = __float_as_uint(f);
  uint32_t r = (u + 0x7FFFu + ((u >> 16) & 1u)) >> 16;
  return (unsigned short)r;
}

// ---------------- threefry2x32 (exact JAX semantics) ----------------
__host__ __device__ inline void threefry2x32(uint32_t k0, uint32_t k1,
                                             uint32_t x0, uint32_t x1,
                                             uint32_t* o0, uint32_t* o1) {
  uint32_t ks2 = k0 ^ k1 ^ 0x1BD11BDAu;
  x0 += k0; x1 += k1;
#define TFR(r) { x0 += x1; x1 = (x1 << (r)) | (x1 >> (32 - (r))); x1 ^= x0; }
  TFR(13) TFR(15) TFR(26) TFR(6)
  x0 += k1;  x1 += ks2 + 1u;
  TFR(17) TFR(29) TFR(16) TFR(24)
  x0 += ks2; x1 += k0 + 2u;
  TFR(13) TFR(15) TFR(26) TFR(6)
  x0 += k0;  x1 += k1 + 3u;
  TFR(17) TFR(29) TFR(16) TFR(24)
  x0 += k1;  x1 += ks2 + 4u;
  TFR(13) TFR(15) TFR(26) TFR(6)
  x0 += ks2; x1 += k0 + 5u;
#undef TFR
  *o0 = x0; *o1 = x1;
}

__device__ __forceinline__ float wave_sum(float v) {
#pragma unroll
  for (int off = 32; off > 0; off >>= 1) v += __shfl_xor(v, off);
  return v;
}

// ---------------- mega convert (+hi/lo splits, +dcw repack, +vmp zero, +cheap inline probe) -
struct CvtArgs {
  const void* src[23];
  float* dstF[23];
  unsigned short* dstB[23];
  unsigned short* dstL[23];
  int n[23];
  int blkStart[24];
  unsigned short* dcwT;
  float* vmpZ;     // zero BB*DMM floats
  int* flagOut;    // published dtype flag
};
__global__ __launch_bounds__(256) void mega_cvt(CvtArgs a) {
  // ---- inline dtype probe: 512 shorts (2/thread). bf16 data -> cnt~0; f32 data -> cnt~228.
  __shared__ int cnt;
  if (threadIdx.x == 0) cnt = 0;
  __syncthreads();
  {
    const unsigned short* u = (const unsigned short*)a.src[0];
    int bad = 0;
#pragma unroll
    for (int rep = 0; rep < 2; ++rep) {
      float v = bfbits(u[threadIdx.x + 256 * rep]);
      float av = fabsf(v);
      bool ok = (v == 0.0f) || (av > 1e-4f && av < 100.0f);
      if (!ok) bad++;
    }
    if (bad) atomicAdd(&cnt, bad);
  }
  __syncthreads();
  int isf32 = (cnt > 25) ? 1 : 0;

  int bid = blockIdx.x;
  if (bid == a.blkStart[23]) {
    for (int t = threadIdx.x; t < BB * DMM; t += 256) a.vmpZ[t] = 0.f;
    if (threadIdx.x == 0) *a.flagOut = isf32;
    return;
  }
  int i = 0;
  while (i < 22 && bid >= a.blkStart[i + 1]) ++i;
  int e = (bid - a.blkStart[i]) * 256 + (int)threadIdx.x;
  if (e >= a.n[i]) return;
  float v; unsigned short rw;
  if (isf32) { v = ((const float*)a.src[i])[e]; rw = f2b(v); }
  else       { rw = ((const unsigned short*)a.src[i])[e]; v = bfbits(rw); }
  a.dstF[i][e] = v;
  if (a.dstB[i]) a.dstB[i][e] = rw;
  if (a.dstL[i]) a.dstL[i][e] = f2b(v - bfbits(rw));
  if (i == 17) {  // dcw: [ly][n][k][t] -> [ly][t][n][k] bf16
    int ly = e / 196608;
    int r = e - ly * 196608;
    int n = r / 768;
    int rem = r - n * 768;
    int k = rem / 3, t = rem - k * 3;
    a.dcwT[ly * 196608 + t * 65536 + n * 256 + k] = rw;
  }
}

// ---------------- QKV MFMA GEMM: z=0:Q 1:K (hi/lo 2-pass, f32 out) 2:V (bf16 out + vmean) --
// (round-0 proven version: BK=32, [128][32]/[64][32] LDS)
struct QKVArgs {
  const unsigned short* W[3];
  const float* bias[3];
  float* Cq;
  float* Ck;
  unsigned short* Cv;
  float* vmp;
};
__global__ __launch_bounds__(256) void gemm_qkv(const unsigned short* __restrict__ Ahi,
                                                const unsigned short* __restrict__ Alo,
                                                QKVArgs qa) {
  __shared__ __attribute__((aligned(16))) unsigned short AsH[128][32];
  __shared__ __attribute__((aligned(16))) unsigned short AsL[128][32];
  __shared__ __attribute__((aligned(16))) unsigned short Bs[64][32];
  int z = blockIdx.z;
  const unsigned short* W = qa.W[z];
  const float* bias = qa.bias[z];
  bool twoPass = (z < 2);
  int bm = blockIdx.x * 128, bn = blockIdx.y * 64;
  int tid = threadIdx.x;
  int wv = tid >> 6, lane = tid & 63;
  int wm = wv >> 1, wn = wv & 1;
  int l15 = lane & 15, quad = lane >> 4;
  int lrow = lane >> 2, lseg = lane & 3;
  f32x4 acc[4][2];
#pragma unroll
  for (int i = 0; i < 4; ++i)
#pragma unroll
    for (int j = 0; j < 2; ++j) acc[i][j] = (f32x4){0.f, 0.f, 0.f, 0.f};
  for (int k0 = 0; k0 < 256; k0 += 32) {
    __syncthreads();
#pragma unroll
    for (int s = 0; s < 2; ++s) {
      int brow = (wv + s * 4) * 16;
      size_t goff = (size_t)(bm + brow + lrow) * 256 + k0 + lseg * 8;
      GLDS16(Ahi + goff, &AsH[brow][0]);
      if (twoPass) GLDS16(Alo + goff, &AsL[brow][0]);
    }
    {
      int brow = wv * 16;
      GLDS16(W + (size_t)(bn + brow + lrow) * 256 + k0 + lseg * 8, &Bs[brow][0]);
    }
    __syncthreads();
    short8 ah[4], bfr[2];
#pragma unroll
    for (int mt = 0; mt < 4; ++mt)
      ah[mt] = *(const short8*)(&AsH[wm * 64 + mt * 16 + l15][quad * 8]);
#pragma unroll
    for (int nt = 0; nt < 2; ++nt)
      bfr[nt] = *(const short8*)(&Bs[wn * 32 + nt * 16 + l15][quad * 8]);
#pragma unroll
    for (int mt = 0; mt < 4; ++mt)
#pragma unroll
      for (int nt = 0; nt < 2; ++nt)
        acc[mt][nt] = __builtin_amdgcn_mfma_f32_16x16x32_bf16(ah[mt], bfr[nt],
                                                              acc[mt][nt], 0, 0, 0);
    if (twoPass) {
      short8 al[4];
#pragma unroll
      for (int mt = 0; mt < 4; ++mt)
        al[mt] = *(const short8*)(&AsL[wm * 64 + mt * 16 + l15][quad * 8]);
#pragma unroll
      for (int mt = 0; mt < 4; ++mt)
#pragma unroll
        for (int nt = 0; nt < 2; ++nt)
          acc[mt][nt] = __builtin_amdgcn_mfma_f32_16x16x32_bf16(al[mt], bfr[nt],
                                                                acc[mt][nt], 0, 0, 0);
    }
  }
  float* C = (z == 0) ? qa.Cq : qa.Ck;
#pragma unroll
  for (int nt = 0; nt < 2; ++nt) {
    int n = bn + wn * 32 + nt * 16 + l15;
    float bv = bias[n];
    float csum = 0.f;
#pragma unroll
    for (int mt = 0; mt < 4; ++mt)
#pragma unroll
      for (int r = 0; r < 4; ++r) {
        int m = bm + wm * 64 + mt * 16 + quad * 4 + r;
        float val = acc[mt][nt][r] + bv;
        if (z < 2) {
          C[(size_t)m * 256 + n] = val;
        } else {
          qa.Cv[(size_t)m * 256 + n] = f2b(val);
          csum += val;
        }
      }
    if (z == 2) {
      csum += __shfl_xor(csum, 16);
      csum += __shfl_xor(csum, 32);
      if (quad == 0) {
        int b = bm >> 11;
        atomicAdd(&qa.vmp[b * DMM + n], csum);
      }
    }
  }
}

// ---------------- FUSED O-proj GEMM (32x256, 512 thr) + tail, ctx-merge hoisted (R12) -----
__global__ __launch_bounds__(512) void oproj_tail(const float* __restrict__ vmp,
                                                  const unsigned char* __restrict__ mapb,
                                                  const float* __restrict__ pm,
                                                  const float* __restrict__ pl,
                                                  const float* __restrict__ po,
                                                  const unsigned short* __restrict__ W,
                                                  const float* __restrict__ bias,
                                                  const float* __restrict__ X,
                                                  const float* __restrict__ g1,
                                                  const float* __restrict__ b1ln,
                                                  const float* __restrict__ w1,
                                                  const float* __restrict__ b1,
                                                  const float* __restrict__ w2,
                                                  const float* __restrict__ b2,
                                                  const float* __restrict__ g2,
                                                  const float* __restrict__ b2ln,
                                                  float* __restrict__ Out,
                                                  unsigned short* __restrict__ OutB,
                                                  unsigned short* __restrict__ OutL,
                                                  const float* __restrict__ fing,
                                                  const float* __restrict__ finb,
                                                  void* __restrict__ finOut,
                                                  const int* __restrict__ flag,
                                                  float* __restrict__ stpZ,
                                                  float* __restrict__ stp2Z) {
  __shared__ __attribute__((aligned(16))) unsigned short As[OTR][DMM];  // full ctx panel
  __shared__ __attribute__((aligned(16))) unsigned short Bs[256][32];
  __shared__ float Cs[OTR][DMM];
  __shared__ float xs[8][DMM];
  int tid = threadIdx.x;
  if (blockIdx.x == 0 && tid < DMM) {
    stpZ[tid] = 0.f;
    stp2Z[tid] = 0.f;
  }
  int bm = blockIdx.x * OTR;
  int wv = tid >> 6, lane = tid & 63;
  int l15 = lane & 15, quad = lane >> 4;
  int b = bm >> 11, l0 = bm & 2047;
  const float invL = 1.0f / (float)LL;

  // ---- phase 1: ctx A-panel for all 8 heads, once, full-block parallel ----
#pragma unroll
  for (int uu = 0; uu < 2; ++uu) {
    int u = tid * 2 + uu;            // 0..1023
    int arow = u >> 5;               // 32 rows
    int sub = u & 31;
    int h = sub >> 2, adg = sub & 3; // 8 heads x 4 col-groups
    int bh = b * HH + h;
    int l = l0 + arow;
    int q = (int)mapb[bh * 2048 + l];
    unsigned short outv[8];
    if (q) {
      size_t base = ((size_t)bh * UU + (q - 1)) * KC;
      float Mx = -1e30f;
#pragma unroll
      for (int kc = 0; kc < KC; ++kc) Mx = fmaxf(Mx, pm[base + kc]);
      float Ls = 0.f;
      float sc[KC];
#pragma unroll
      for (int kc = 0; kc < KC; ++kc) {
        sc[kc] = expf(pm[base + kc] - Mx);
        Ls += pl[base + kc] * sc[kc];
      }
      float inv = 1.0f / Ls;
#pragma unroll
      for (int j = 0; j < 8; ++j) {
        int dl = adg * 8 + j;
        float o = 0.f;
#pragma unroll
        for (int kc = 0; kc < KC; ++kc) o += po[(base + kc) * 32 + dl] * sc[kc];
        outv[j] = f2b(o * inv);
      }
    } else {
      const float* vp = vmp + b * DMM + h * EE + adg * 8;
#pragma unroll
      for (int j = 0; j < 8; ++j) outv[j] = f2b(vp[j] * invL);
    }
    *(uint4*)(&As[arow][h * EE + adg * 8]) = *(const uint4*)outv;
  }
  __syncthreads();

  // ---- phase 2: GEMM loop (pure stage+MFMA) ----
  f32x4 acc[2][2];
#pragma unroll
  for (int i = 0; i < 2; ++i)
#pragma unroll
    for (int j = 0; j < 2; ++j) acc[i][j] = (f32x4){0.f, 0.f, 0.f, 0.f};
  for (int k0 = 0; k0 < 256; k0 += 32) {
    if (k0) __syncthreads();
    {  // stage all 256 B-rows once per block (8 waves x 2 rounds x 16 rows)
      int lrw = lane >> 2, lsg = lane & 3;
#pragma unroll
      for (int s = 0; s < 2; ++s) {
        int brow = s * 128 + wv * 16;
        GLDS16(W + (size_t)(brow + lrw) * 256 + k0 + lsg * 8, &Bs[brow][0]);
      }
    }
    __syncthreads();
    short8 af[2], bfr[2];
#pragma unroll
    for (int mt = 0; mt < 2; ++mt)
      af[mt] = *(const short8*)(&As[mt * 16 + l15][k0 + quad * 8]);
#pragma unroll
    for (int nt = 0; nt < 2; ++nt)
      bfr[nt] = *(const short8*)(&Bs[wv * 32 + nt * 16 + l15][quad * 8]);
#pragma unroll
    for (int mt = 0; mt < 2; ++mt)
#pragma unroll
      for (int nt = 0; nt < 2; ++nt)
        acc[mt][nt] = __builtin_amdgcn_mfma_f32_16x16x32_bf16(af[mt], bfr[nt],
                                                              acc[mt][nt], 0, 0, 0);
  }
  // epilogue -> LDS (replaces tmp)
#pragma unroll
  for (int nt = 0; nt < 2; ++nt) {
    int n = wv * 32 + nt * 16 + l15;
    float bv = bias[n];
#pragma unroll
    for (int mt = 0; mt < 2; ++mt)
#pragma unroll
      for (int r = 0; r < 4; ++r)
        Cs[mt * 16 + quad * 4 + r][n] = acc[mt][nt][r] + bv;
  }
  __syncthreads();
  // ---- enc_tail body, verbatim, 4 rows per wave ----
  for (int rr = 0; rr < 4; ++rr) {
    int lr = wv * 4 + rr;
    size_t row = (size_t)bm + lr;
    const float* xr = X + row * DMM;
    const float* tr = Cs[lr];
    float v[4];
#pragma unroll
    for (int i = 0; i < 4; ++i) v[i] = xr[lane + 64 * i] + tr[lane + 64 * i];
    float s = wave_sum(v[0] + v[1] + v[2] + v[3]);
    float m = s * (1.0f / (float)DMM);
    float sq = 0.f;
#pragma unroll
    for (int i = 0; i < 4; ++i) { float d = v[i] - m; sq += d * d; }
    sq = wave_sum(sq);
    float rstd = rsqrtf(sq * (1.0f / (float)DMM) + 1e-5f);
    float xv[4];
#pragma unroll
    for (int i = 0; i < 4; ++i) {
      int d = lane + 64 * i;
      xv[i] = (v[i] - m) * rstd * g1[d] + b1ln[d];
      xs[wv][d] = xv[i];
    }
    __syncthreads();
    int f = lane & 15, qtr = lane >> 4;
    const float* w1p = w1 + f * DMM + qtr * 64;
    const float* xq = &xs[wv][qtr * 64];
    float pacc = 0.f;
#pragma unroll 8
    for (int d = 0; d < 64; ++d) pacc += xq[d] * w1p[d];
    pacc += __shfl_xor(pacc, 16);
    pacc += __shfl_xor(pacc, 32);
    float y1 = fmaxf(pacc + b1[f], 0.0f);
    float y1v[16];
#pragma unroll
    for (int ff = 0; ff < 16; ++ff) y1v[ff] = __shfl(y1, ff);
#pragma unroll
    for (int i = 0; i < 4; ++i) {
      int d = lane + 64 * i;
      const float* w2p = w2 + d * ITR;
      float a = b2[d];
#pragma unroll
      for (int ff = 0; ff < 16; ++ff) a += y1v[ff] * w2p[ff];
      v[i] = xv[i] + a;
    }
    s = wave_sum(v[0] + v[1] + v[2] + v[3]);
    m = s * (1.0f / (float)DMM);
    sq = 0.f;
#pragma unroll
    for (int i = 0; i < 4; ++i) { float d = v[i] - m; sq += d * d; }
    sq = wave_sum(sq);
    rstd = rsqrtf(sq * (1.0f / (float)DMM) + 1e-5f);
    float vv[4];
#pragma unroll
    for (int i = 0; i < 4; ++i) {
      int d = lane + 64 * i;
      float val = (v[i] - m) * rstd * g2[d] + b2ln[d];
      vv[i] = val;
      Out[row * DMM + d] = val;
      unsigned short hi = f2b(val);
      OutB[row * DMM + d] = hi;
      OutL[row * DMM + d] = f2b(val - bfbits(hi));
    }
    if (finOut) {
      s = wave_sum(vv[0] + vv[1] + vv[2] + vv[3]);
      m = s * (1.0f / (float)DMM);
      sq = 0.f;
#pragma unroll
      for (int i = 0; i < 4; ++i) { float d = vv[i] - m; sq += d * d; }
      sq = wave_sum(sq);
      rstd = rsqrtf(sq * (1.0f / (float)DMM) + 1e-5f);
      int isf32 = *flag;
#pragma unroll
      for (int i = 0; i < 4; ++i) {
        int d = lane + 64 * i;
        float val = (vv[i] - m) * rstd * fing[d] + finb[d];
        if (isf32) ((float*)finOut)[row * DMM + d] = val;
        else       ((unsigned short*)finOut)[row * DMM + d] = f2b(val);
      }
    }
  }
}

// ---------------- conv GEMM: A window staged once per k0, 3 taps from LDS ----------------
__global__ __launch_bounds__(256) void gemm_conv(const unsigned short* __restrict__ A,
                                                 const unsigned short* __restrict__ W,
                                                 const float* __restrict__ bias,
                                                 float* __restrict__ C,
                                                 float* __restrict__ stp,
                                                 float* __restrict__ stp2) {
  __shared__ __attribute__((aligned(16))) unsigned short As[80][32];
  __shared__ __attribute__((aligned(16))) unsigned short Bs[192][32];
  int bm = blockIdx.x * 64, bn = blockIdx.y * 64;
  int tid = threadIdx.x;
  int wv = tid >> 6, lane = tid & 63;
  int wm = wv >> 1, wn = wv & 1;
  int l15 = lane & 15, quad = lane >> 4;
  int lrow = lane >> 2, lseg = lane & 3;
  int bbase = bm & ~2047, l0 = bm & 2047;
  f32x4 acc[2][2];
#pragma unroll
  for (int i = 0; i < 2; ++i)
#pragma unroll
    for (int j = 0; j < 2; ++j) acc[i][j] = (f32x4){0.f, 0.f, 0.f, 0.f};
  for (int k0 = 0; k0 < 256; k0 += 32) {
    __syncthreads();
    for (int c = wv; c < 5; c += 4) {
      int i0 = c * 16;
      int l = (l0 - 1 + i0 + lrow + 2048) & 2047;
      GLDS16(A + (size_t)(bbase | l) * 256 + k0 + lseg * 8, &As[i0][0]);
    }
    for (int c = wv; c < 12; c += 4) {
      int i0 = c * 16;
      int tap = c >> 2, brow = (c & 3) * 16;
      GLDS16(W + (size_t)tap * 65536 + (size_t)(bn + brow + lrow) * 256 + k0 + lseg * 8,
             &Bs[i0][0]);
    }
    __syncthreads();
#pragma unroll
    for (int tap = 0; tap < 3; ++tap) {
      short8 af[2], bfr[2];
#pragma unroll
      for (int mt = 0; mt < 2; ++mt)
        af[mt] = *(const short8*)(&As[wm * 32 + mt * 16 + l15 + tap][quad * 8]);
#pragma unroll
      for (int nt = 0; nt < 2; ++nt)
        bfr[nt] = *(const short8*)(&Bs[tap * 64 + wn * 32 + nt * 16 + l15][quad * 8]);
#pragma unroll
      for (int mt = 0; mt < 2; ++mt)
#pragma unroll
        for (int nt = 0; nt < 2; ++nt)
          acc[mt][nt] = __builtin_amdgcn_mfma_f32_16x16x32_bf16(af[mt], bfr[nt],
                                                                acc[mt][nt], 0, 0, 0);
    }
  }
#pragma unroll
  for (int nt = 0; nt < 2; ++nt) {
    int n = bn + wn * 32 + nt * 16 + l15;
    float bv = bias[n];
    float s = 0.f, s2 = 0.f;
#pragma unroll
    for (int mt = 0; mt < 2; ++mt)
#pragma unroll
      for (int r = 0; r < 4; ++r) {
        int m = bm + wm * 32 + mt * 16 + quad * 4 + r;
        float val = acc[mt][nt][r] + bv;
        C[(size_t)m * 256 + n] = val;
        s += val;
        s2 += val * val;
      }
    s  += __shfl_xor(s, 16);   s  += __shfl_xor(s, 32);
    s2 += __shfl_xor(s2, 16);  s2 += __shfl_xor(s2, 32);
    if (quad == 0) {
      atomicAdd(&stp[n], s);
      atomicAdd(&stp2[n], s2);
    }
  }
}

// ---------------- M scores: wave per (b,l), inline threefry, XCD-affinity swizzle ----------
__global__ __launch_bounds__(256) void m_kernel3(const float* __restrict__ Q,
                                                 const float* __restrict__ K,
                                                 uint32_t k20, uint32_t k21,
                                                 float* __restrict__ M) {
  int bid = blockIdx.x;
  int blk = (bid & 7) * 256 + (bid >> 3);   // XCD-affinity remap (pure perf, no semantics)
  int b = blk >> 9, lc = blk & 511;
  int wave = threadIdx.x >> 6, lane = threadIdx.x & 63;
  int l = lc * 4 + wave;
  int myidx = 0;
  if (lane < UU) {
    int j = l * UU + lane;
    uint32_t o0, o1;
    const int half = (LL * UU) / 2;  // 40960
    if (j < half) {
      threefry2x32(k20, k21, (uint32_t)j, (uint32_t)(j + half), &o0, &o1);
      myidx = (int)(o0 & (LL - 1));
    } else {
      threefry2x32(k20, k21, (uint32_t)(j - half), (uint32_t)j, &o0, &o1);
      myidx = (int)(o1 & (LL - 1));
    }
  }
  float4 q4 = *(const float4*)(Q + ((size_t)(b * LL + l)) * DMM + lane * 4);
  const float* Kb = K + (size_t)b * LL * DMM;
  float mx = -1e30f, sm = 0.f;
#pragma unroll 8
  for (int u = 0; u < UU; ++u) {
    int kidx = __shfl(myidx, u);
    float4 k4 = *(const float4*)(Kb + (size_t)kidx * DMM + lane * 4);
    float s = q4.x * k4.x + q4.y * k4.y + q4.z * k4.z + q4.w * k4.w;
    s += __shfl_xor(s, 1);
    s += __shfl_xor(s, 2);
    s += __shfl_xor(s, 4);
    mx = fmaxf(mx, s);
    sm += s;
  }
  if ((lane & 7) == 0) {
    int h = lane >> 3;
    M[((size_t)(b * HH + h)) * LL + l] = mx - sm * (1.0f / (float)LL);
  }
}

// ---------------- fused topk + split-K flash attention ------------------------------------
// R14 structure (slim 6-round radix, shuffle scans) with the PV phase converted to MFMA:
// P[40x128] x V[128x32] via mfma_f32_16x16x32_bf16. V staged TRANSPOSED (VsT[d][k], the
// B-operand [n][k] layout every proven GEMM here reads); ps padded to 48 rows (40..47
// zeroed) so the partial 3rd q-tile reads defined data. Fragment mapping = the proven
// pattern (A: [tile*16+l15][kch*32+quad*8]; C: row=quad*4+r, col=l15). Softmax math,
// pm/pl, radix, scores all byte-identical to R14.
__global__ __launch_bounds__(256) void attn_part(const float* __restrict__ Q,
                                                 const float* __restrict__ K,
                                                 const unsigned short* __restrict__ Vbf,
                                                 const float* __restrict__ M,
                                                 unsigned char* __restrict__ mapb,
                                                 float* __restrict__ pm,
                                                 float* __restrict__ pl,
                                                 float* __restrict__ po) {
  __shared__ float Qs[40][32];
  __shared__ __attribute__((aligned(16))) unsigned short ps[48][KCH];
  __shared__ __attribute__((aligned(16))) unsigned short VsT[EE][KCH];
  __shared__ int qrows[40];
  __shared__ unsigned int hist[256];
  __shared__ unsigned int sA[256];
  __shared__ unsigned int wtot[4];
  __shared__ unsigned int tbv;
  int kc = blockIdx.x, bh = blockIdx.y;
  int h = bh & 7, b = bh >> 3;
  int tid = threadIdx.x;
  int wv = tid >> 6, lane = tid & 63;
  int l15 = lane & 15, quad = lane >> 4;

  // ---- independent loads issued first (overlap with radix latency) ----
  {
    int row = tid >> 1, half = tid & 1;
    const unsigned short* vsrc =
        Vbf + (size_t)(b * LL + kc * KCH + row) * DMM + h * EE + half * 16;
    unsigned short tv[16];
    *(uint4*)(&tv[0]) = *(const uint4*)vsrc;
    *(uint4*)(&tv[8]) = *(const uint4*)(vsrc + 8);
#pragma unroll
    for (int j = 0; j < 16; ++j) VsT[half * 16 + j][row] = tv[j];
  }
  int kk = tid & (KCH - 1), qh = tid >> 7;  // 2 threads/key, 20 queries each
  float4 kr[8];
  {
    const float4* kp =
        (const float4*)(K + ((size_t)(b * LL + kc * KCH + kk)) * DMM + h * EE);
#pragma unroll
    for (int j = 0; j < 8; ++j) kr[j] = kp[j];
  }
  // zero ps rows 40..47 (pad tile for MFMA A-reads)
  for (int t = tid; t < 512; t += 256)
    ((uint32_t*)&ps[40][0])[t] = 0u;

  // ---- exact top-40 radix select on M[bh]: packed 43-bit keys, 6 rounds (R14-proven) ----
  u64 kreg[8];
#pragma unroll
  for (int r = 0; r < 8; ++r) {
    int l = tid + 256 * r;
    float v = M[(size_t)bh * LL + l];
    uint32_t bits = __float_as_uint(v);
    uint32_t kv = (bits & 0x80000000u) ? ~bits : (bits | 0x80000000u);
    kreg[r] = ((u64)kv << 11) | (uint32_t)(2047 - l);
  }
  u64 prefix = 0;
  int rank = UU;
  for (int round = 0; round < 6; ++round) {
    int shift = 40 - 8 * round;
    u64 maskTop = (round == 0) ? 0ull : (~0ull << (48 - 8 * round));
    hist[tid] = 0;
    __syncthreads();
#pragma unroll
    for (int r = 0; r < 8; ++r) {
      u64 k = kreg[r];
      if ((k & maskTop) == prefix)
        atomicAdd(&hist[(unsigned int)((k >> shift) & 0xFFu)], 1u);
    }
    __syncthreads();
    unsigned int s = hist[tid];
#pragma unroll
    for (int off = 1; off < 64; off <<= 1) {
      unsigned int t = __shfl_down(s, off);
      if (lane + off < 64) s += t;
    }
    if (lane == 0) wtot[wv] = s;
    __syncthreads();
    unsigned int add = 0;
#pragma unroll
    for (int w = 0; w < 4; ++w)
      if (w > wv) add += wtot[w];
    sA[tid] = s + add;
    __syncthreads();
    unsigned int Sb = sA[tid];
    unsigned int Snext = (tid < 255) ? sA[tid + 1] : 0u;
    if (Sb >= (unsigned int)rank && Snext < (unsigned int)rank) tbv = (unsigned int)tid;
    __syncthreads();
    unsigned int tb = tbv;
    unsigned int above = (tb < 255u) ? sA[tb + 1] : 0u;
    rank -= (int)above;
    prefix |= ((u64)tb) << shift;
  }
  u64 T = prefix;   // exact 40th-largest packed key
  // ---- deterministic rank: in-wave prefix + cross-wave totals (exclusive over tid) ----
  int myCnt = 0;
#pragma unroll
  for (int r = 0; r < 8; ++r) myCnt += (kreg[r] >= T) ? 1 : 0;
  {
    unsigned int p = (unsigned int)myCnt;
#pragma unroll
    for (int off = 1; off < 64; off <<= 1) {
      unsigned int t = __shfl_up(p, off);
      if (lane >= off) p += t;
    }
    if (lane == 63) wtot[wv] = p;
    __syncthreads();
    unsigned int addp = 0;
#pragma unroll
    for (int w = 0; w < 4; ++w)
      if (w < wv) addp += wtot[w];
    int pos = (int)(p + addp) - myCnt;   // exclusive prefix
    bool wmap = (kc == 0);
#pragma unroll
    for (int r = 0; r < 8; ++r) {
      u64 k = kreg[r];
      int l = 2047 - (int)(uint32_t)(k & 0x7FFu);
      unsigned char mv = 0;
      if (k >= T) {
        qrows[pos] = l;
        mv = (unsigned char)(pos + 1);
        pos++;
      }
      if (wmap) mapb[bh * 2048 + l] = mv;
    }
  }
  __syncthreads();

  // ---- Q staging for the 40 selected rows ----
  for (int t = tid; t < 40 * 32; t += 256) {
    int q = t >> 5, d = t & 31;
    Qs[q][d] = Q[((size_t)(b * LL + qrows[q])) * DMM + h * EE + d];
  }
  __syncthreads();
  // ---- scores ----
  {
    const float scale = 0.17677669529663687f;
    for (int q = qh * 20; q < qh * 20 + 20; ++q) {
      const float4* qp = (const float4*)Qs[q];
      float s = 0.f;
#pragma unroll
      for (int j = 0; j < 8; ++j) {
        float4 qv = qp[j];
        s += qv.x * kr[j].x + qv.y * kr[j].y + qv.z * kr[j].z + qv.w * kr[j].w;
      }
      ps[q][kk] = f2b(s * scale);
    }
  }
  __syncthreads();
  // ---- softmax (max + exp + sum per row; writes exp back to ps; pm/pl) ----
  for (int qq = 0; qq < 10; ++qq) {
    int q = wv * 10 + qq;
    float mx = fmaxf(bfbits(ps[q][lane]), bfbits(ps[q][lane + 64]));
#pragma unroll
    for (int off = 32; off > 0; off >>= 1) mx = fmaxf(mx, __shfl_xor(mx, off));
    float e0 = expf(bfbits(ps[q][lane]) - mx);
    float e1 = expf(bfbits(ps[q][lane + 64]) - mx);
    ps[q][lane] = f2b(e0);
    ps[q][lane + 64] = f2b(e1);
    float sum = wave_sum(e0 + e1);
    size_t base = ((size_t)bh * UU + q) * KC + kc;
    if (lane == 0) { pm[base] = mx; pl[base] = sum; }
  }
  __syncthreads();
  // ---- PV via MFMA: waves 0..2 each compute one 16-row q-tile x 32 cols ----
  if (wv < 3) {
    f32x4 pacc[2];
#pragma unroll
    for (int nt = 0; nt < 2; ++nt) pacc[nt] = (f32x4){0.f, 0.f, 0.f, 0.f};
#pragma unroll
    for (int kch = 0; kch < 4; ++kch) {
      short8 af = *(const short8*)(&ps[wv * 16 + l15][kch * 32 + quad * 8]);
#pragma unroll
      for (int nt = 0; nt < 2; ++nt) {
        short8 bfr = *(const short8*)(&VsT[nt * 16 + l15][kch * 32 + quad * 8]);
        pacc[nt] = __builtin_amdgcn_mfma_f32_16x16x32_bf16(af, bfr, pacc[nt], 0, 0, 0);
      }
    }
#pragma unroll
    for (int nt = 0; nt < 2; ++nt) {
      int d = nt * 16 + l15;
#pragma unroll
      for (int r = 0; r < 4; ++r) {
        int q = wv * 16 + quad * 4 + r;
        if (q < UU) {
          size_t base = ((size_t)bh * UU + q) * KC + kc;
          po[base * 32 + d] = pacc[nt][r];
        }
      }
    }
  }
}

// ---------------- bn+elu from atomic stats (+vmp zero for next layer) ----------------
__global__ __launch_bounds__(256) void bn_elu(const float* __restrict__ Y,
                                              const float* __restrict__ stp,
                                              const float* __restrict__ stp2,
                                              const float* __restrict__ g,
                                              const float* __restrict__ bb,
                                              float* __restrict__ X,
                                              unsigned short* __restrict__ XB,
                                              unsigned short* __restrict__ XL,
                                              float* __restrict__ vmpZ) {
  int gid = blockIdx.x * 256 + threadIdx.x;
  if (gid < BB * DMM) vmpZ[gid] = 0.f;
  int d = gid & 255;
  float mean = stp[d] * (1.0f / (float)ROWS);
  float var = stp2[d] * (1.0f / (float)ROWS) - mean * mean;
  float rstd = rsqrtf(var + 1e-5f);
  float v = (Y[gid] - mean) * rstd * g[d] + bb[d];
  float r = v > 0.f ? v : expm1f(v);
  X[gid] = r;
  unsigned short hi = f2b(r);
  XB[gid] = hi;
  XL[gid] = f2b(r - bfbits(hi));
}

extern "C" void kernel_launch(void* const* d_in, const int* in_sizes, int n_in,
                              void* d_out, int out_size, void* d_ws, size_t ws_size,
                              hipStream_t stream) {
  (void)in_sizes; (void)n_in; (void)out_size; (void)ws_size;

  // ---- workspace layout ----
  float* xbuf = (float*)d_ws;
  float* kb   = xbuf + NELEM;
  float* qb   = kb + NELEM;   // aliases tmp (Q dead after attn_part)
  float* tmp  = qb;
  float* Mbuf = qb + NELEM;
  float* vmp  = Mbuf + BB * HH * LL;
  float* stp  = vmp + BB * DMM;
  float* stp2 = stp + DMM;
  float* wp   = stp2 + DMM;
  const int wsz[23] = {
      NELEM,
      NLL * DMM * DMM, NLL * DMM,
      NLL * DMM * DMM, NLL * DMM,
      NLL * DMM * DMM, NLL * DMM,
      NLL * DMM * DMM, NLL * DMM,
      NLL * ITR * DMM, NLL * ITR,
      NLL * DMM * ITR, NLL * DMM,
      NLL * DMM, NLL * DMM,
      NLL * DMM, NLL * DMM,
      (NLL - 1) * DMM * DMM * 3, (NLL - 1) * DMM,
      (NLL - 1) * DMM, (NLL - 1) * DMM,
      DMM, DMM
  };
  float* fptr[23];
  fptr[0] = xbuf;
  for (int i = 1; i < 23; ++i) { fptr[i] = wp; wp += wsz[i]; }
  float* pm = wp;
  float* pl = pm + 32 * UU * KC;
  float* po = pl + 32 * UU * KC;
  unsigned short* xbf   = (unsigned short*)(po + 32 * UU * KC * 32);
  unsigned short* xlo   = xbf + NELEM;
  unsigned short* vbf   = xlo + NELEM;
  unsigned short* wqbf  = vbf + NELEM;
  unsigned short* wkbf  = wqbf + NLL * DMM * DMM;
  unsigned short* wvbf  = wkbf + NLL * DMM * DMM;
  unsigned short* wobf  = wvbf + NLL * DMM * DMM;
  unsigned short* dcwT  = wobf + NLL * DMM * DMM;
  u64* cand = (u64*)(dcwT + (NLL - 1) * 3 * DMM * DMM);  // layout kept (unused now)
  int* topb = (int*)(cand + 256 * 40);                    // layout kept (unused now)
  int* flag = topb + BB * HH * UU;
  unsigned char* mapb = (unsigned char*)(flag + 1);  // 32*2048

  // ---- convert (+cheap inline dtype probe, +dcw repack, +vmp zero, +flag publish) ----
  CvtArgs ca;
  int totalBlk = 0;
  for (int i = 0; i < 23; ++i) {
    ca.src[i] = d_in[i];
    ca.dstF[i] = fptr[i];
    ca.dstB[i] = nullptr;
    ca.dstL[i] = nullptr;
    ca.n[i] = wsz[i];
    ca.blkStart[i] = totalBlk;
    totalBlk += (wsz[i] + 255) / 256;
  }
  ca.blkStart[23] = totalBlk;
  ca.dstB[0] = xbf;  ca.dstL[0] = xlo;
  ca.dstB[1] = wqbf;
  ca.dstB[3] = wkbf;
  ca.dstB[5] = wvbf;
  ca.dstB[7] = wobf;
  ca.dcwT = dcwT;
  ca.vmpZ = vmp;
  ca.flagOut = flag;
  mega_cvt<<<totalBlk + 1, 256, 0, stream>>>(ca);

  dim3 gqkv(ROWS / 128, DMM / 64, 3);
  dim3 g64(ROWS / 64, DMM / 64);

  for (int i = 0; i < NLL; ++i) {
    QKVArgs qa;
    qa.W[0] = wqbf + (size_t)i * DMM * DMM;
    qa.W[1] = wkbf + (size_t)i * DMM * DMM;
    qa.W[2] = wvbf + (size_t)i * DMM * DMM;
    qa.bias[0] = fptr[2] + i * DMM;
    qa.bias[1] = fptr[4] + i * DMM;
    qa.bias[2] = fptr[6] + i * DMM;
    qa.Cq = qb; qa.Ck = kb; qa.Cv = vbf;
    qa.vmp = vmp;
    gemm_qkv<<<gqkv, 256, 0, stream>>>(xbf, xlo, qa);

    uint32_t ki0, ki1, a0, a1, b0, b1;
    threefry2x32(0u, 42u, 0u, (uint32_t)i, &ki0, &ki1);
    threefry2x32(ki0, ki1, 0u, 2u, &a0, &a1);
    threefry2x32(ki0, ki1, 1u, 3u, &b0, &b1);
    (void)a0; (void)b0;

    m_kernel3<<<BB * 512, 256, 0, stream>>>(qb, kb, a1, b1, Mbuf);
    attn_part<<<dim3(KC, BB * HH), 256, 0, stream>>>(qb, kb, vbf, Mbuf, mapb,
                                                     pm, pl, po);

    bool last = (i == NLL - 1);
    oproj_tail<<<ROWS / OTR, 512, 0, stream>>>(
        vmp, mapb, pm, pl, po,
        wobf + (size_t)i * DMM * DMM, fptr[8] + i * DMM,
        xbuf,
        fptr[13] + i * DMM, fptr[14] + i * DMM,
        fptr[9] + (size_t)i * ITR * DMM, fptr[10] + i * ITR,
        fptr[11] + (size_t)i * DMM * ITR, fptr[12] + i * DMM,
        fptr[15] + i * DMM, fptr[16] + i * DMM,
        xbuf, xbf, xlo,
        fptr[21], fptr[22], last ? d_out : nullptr, flag, stp, stp2);

    if (!last) {
      gemm_conv<<<g64, 256, 0, stream>>>(xbf, dcwT + (size_t)i * 3 * DMM * DMM,
                                         fptr[18] + i * DMM, tmp, stp, stp2);
      bn_elu<<<NELEM / 256, 256, 0, stream>>>(tmp, stp, stp2, fptr[19] + i * DMM,
                                              fptr[20] + i * DMM, xbuf, xbf, xlo, vmp);
    }
  }
}

// Round 16
// 441.252 us; speedup vs baseline: 1.2552x; 1.0131x over previous
//
#include <hip/hip_runtime.h>
#include <stdint.h>

#define BB 4
#define LL 2048
#define DMM 256
#define HH 8
#define EE 32
#define NLL 3
#define ITR 16
#define UU 40
#define KC 16                 // split-K chunks
#define KCH 128               // keys per chunk
#define ROWS (BB*LL)          // 8192
#define NELEM (ROWS*DMM)      // 2097152
#define OTR 32                // oproj_tail rows per block (32 -> 256 blocks, 512 thr each)

typedef __attribute__((ext_vector_type(8))) short short8;
typedef __attribute__((ext_vector_type(4))) float f32x4;
typedef unsigned long long u64;

#define GLDS16(g, l)                                                        \
  __builtin_amdgcn_global_load_lds(                                         \
      (const __attribute__((address_space(1))) uint32_t*)(g),               \
      (__attribute__((address_space(3))) uint32_t*)(l), 16, 0, 0)

// ---------------- bf16 bit helpers (RNE) ----------------
__device__ __forceinline__ float bfbits(unsigned short u) {
  return __uint_as_float(((uint32_t)u) << 16);
}
__device__ __forceinline__ unsigned short f2b(float f) {
  uint32_t u = __float_as_uint(f);
  uint32_t r = (u + 0x7FFFu + ((u >> 16) & 1u)) >> 16;
  return (unsigned short)r;
}

// ---------------- threefry2x32 (exact JAX semantics) ----------------
__host__ __device__ inline void threefry2x32(uint32_t k0, uint32_t k1,
                                             uint32_t x0, uint32_t x1,
                                             uint32_t* o0, uint32_t* o1) {
  uint32_t ks2 = k0 ^ k1 ^ 0x1BD11BDAu;
  x0 += k0; x1 += k1;
#define TFR(r) { x0 += x1; x1 = (x1 << (r)) | (x1 >> (32 - (r))); x1 ^= x0; }
  TFR(13) TFR(15) TFR(26) TFR(6)
  x0 += k1;  x1 += ks2 + 1u;
  TFR(17) TFR(29) TFR(16) TFR(24)
  x0 += ks2; x1 += k0 + 2u;
  TFR(13) TFR(15) TFR(26) TFR(6)
  x0 += k0;  x1 += k1 + 3u;
  TFR(17) TFR(29) TFR(16) TFR(24)
  x0 += k1;  x1 += ks2 + 4u;
  TFR(13) TFR(15) TFR(26) TFR(6)
  x0 += ks2; x1 += k0 + 5u;
#undef TFR
  *o0 = x0; *o1 = x1;
}

__device__ __forceinline__ float wave_sum(float v) {
#pragma unroll
  for (int off = 32; off > 0; off >>= 1) v += __shfl_xor(v, off);
  return v;
}

// ---------------- mega convert (+hi/lo splits, +dcw repack, +vmp zero, +cheap inline probe) -
struct CvtArgs {
  const void* src[23];
  float* dstF[23];
  unsigned short* dstB[23];
  unsigned short* dstL[23];
  int n[23];
  int blkStart[24];
  unsigned short* dcwT;
  float* vmpZ;     // zero BB*DMM floats
  int* flagOut;    // published dtype flag
};
__global__ __launch_bounds__(256) void mega_cvt(CvtArgs a) {
  // ---- inline dtype probe: 512 shorts (2/thread). bf16 data -> cnt~0; f32 data -> cnt~228.
  __shared__ int cnt;
  if (threadIdx.x == 0) cnt = 0;
  __syncthreads();
  {
    const unsigned short* u = (const unsigned short*)a.src[0];
    int bad = 0;
#pragma unroll
    for (int rep = 0; rep < 2; ++rep) {
      float v = bfbits(u[threadIdx.x + 256 * rep]);
      float av = fabsf(v);
      bool ok = (v == 0.0f) || (av > 1e-4f && av < 100.0f);
      if (!ok) bad++;
    }
    if (bad) atomicAdd(&cnt, bad);
  }
  __syncthreads();
  int isf32 = (cnt > 25) ? 1 : 0;

  int bid = blockIdx.x;
  if (bid == a.blkStart[23]) {
    for (int t = threadIdx.x; t < BB * DMM; t += 256) a.vmpZ[t] = 0.f;
    if (threadIdx.x == 0) *a.flagOut = isf32;
    return;
  }
  int i = 0;
  while (i < 22 && bid >= a.blkStart[i + 1]) ++i;
  int e = (bid - a.blkStart[i]) * 256 + (int)threadIdx.x;
  if (e >= a.n[i]) return;
  float v; unsigned short rw;
  if (isf32) { v = ((const float*)a.src[i])[e]; rw = f2b(v); }
  else       { rw = ((const unsigned short*)a.src[i])[e]; v = bfbits(rw); }
  a.dstF[i][e] = v;
  if (a.dstB[i]) a.dstB[i][e] = rw;
  if (a.dstL[i]) a.dstL[i][e] = f2b(v - bfbits(rw));
  if (i == 17) {  // dcw: [ly][n][k][t] -> [ly][t][n][k] bf16
    int ly = e / 196608;
    int r = e - ly * 196608;
    int n = r / 768;
    int rem = r - n * 768;
    int k = rem / 3, t = rem - k * 3;
    a.dcwT[ly * 196608 + t * 65536 + n * 256 + k] = rw;
  }
}

// ---------------- QKV MFMA GEMM: z=0:Q 1:K (hi/lo 2-pass, f32 out) 2:V (bf16 out + vmean) --
// (round-0 proven version: BK=32, [128][32]/[64][32] LDS)
struct QKVArgs {
  const unsigned short* W[3];
  const float* bias[3];
  float* Cq;
  float* Ck;
  unsigned short* Cv;
  float* vmp;
};
__global__ __launch_bounds__(256) void gemm_qkv(const unsigned short* __restrict__ Ahi,
                                                const unsigned short* __restrict__ Alo,
                                                QKVArgs qa) {
  __shared__ __attribute__((aligned(16))) unsigned short AsH[128][32];
  __shared__ __attribute__((aligned(16))) unsigned short AsL[128][32];
  __shared__ __attribute__((aligned(16))) unsigned short Bs[64][32];
  int z = blockIdx.z;
  const unsigned short* W = qa.W[z];
  const float* bias = qa.bias[z];
  bool twoPass = (z < 2);
  int bm = blockIdx.x * 128, bn = blockIdx.y * 64;
  int tid = threadIdx.x;
  int wv = tid >> 6, lane = tid & 63;
  int wm = wv >> 1, wn = wv & 1;
  int l15 = lane & 15, quad = lane >> 4;
  int lrow = lane >> 2, lseg = lane & 3;
  f32x4 acc[4][2];
#pragma unroll
  for (int i = 0; i < 4; ++i)
#pragma unroll
    for (int j = 0; j < 2; ++j) acc[i][j] = (f32x4){0.f, 0.f, 0.f, 0.f};
  for (int k0 = 0; k0 < 256; k0 += 32) {
    __syncthreads();
#pragma unroll
    for (int s = 0; s < 2; ++s) {
      int brow = (wv + s * 4) * 16;
      size_t goff = (size_t)(bm + brow + lrow) * 256 + k0 + lseg * 8;
      GLDS16(Ahi + goff, &AsH[brow][0]);
      if (twoPass) GLDS16(Alo + goff, &AsL[brow][0]);
    }
    {
      int brow = wv * 16;
      GLDS16(W + (size_t)(bn + brow + lrow) * 256 + k0 + lseg * 8, &Bs[brow][0]);
    }
    __syncthreads();
    short8 ah[4], bfr[2];
#pragma unroll
    for (int mt = 0; mt < 4; ++mt)
      ah[mt] = *(const short8*)(&AsH[wm * 64 + mt * 16 + l15][quad * 8]);
#pragma unroll
    for (int nt = 0; nt < 2; ++nt)
      bfr[nt] = *(const short8*)(&Bs[wn * 32 + nt * 16 + l15][quad * 8]);
#pragma unroll
    for (int mt = 0; mt < 4; ++mt)
#pragma unroll
      for (int nt = 0; nt < 2; ++nt)
        acc[mt][nt] = __builtin_amdgcn_mfma_f32_16x16x32_bf16(ah[mt], bfr[nt],
                                                              acc[mt][nt], 0, 0, 0);
    if (twoPass) {
      short8 al[4];
#pragma unroll
      for (int mt = 0; mt < 4; ++mt)
        al[mt] = *(const short8*)(&AsL[wm * 64 + mt * 16 + l15][quad * 8]);
#pragma unroll
      for (int mt = 0; mt < 4; ++mt)
#pragma unroll
        for (int nt = 0; nt < 2; ++nt)
          acc[mt][nt] = __builtin_amdgcn_mfma_f32_16x16x32_bf16(al[mt], bfr[nt],
                                                                acc[mt][nt], 0, 0, 0);
    }
  }
  float* C = (z == 0) ? qa.Cq : qa.Ck;
#pragma unroll
  for (int nt = 0; nt < 2; ++nt) {
    int n = bn + wn * 32 + nt * 16 + l15;
    float bv = bias[n];
    float csum = 0.f;
#pragma unroll
    for (int mt = 0; mt < 4; ++mt)
#pragma unroll
      for (int r = 0; r < 4; ++r) {
        int m = bm + wm * 64 + mt * 16 + quad * 4 + r;
        float val = acc[mt][nt][r] + bv;
        if (z < 2) {
          C[(size_t)m * 256 + n] = val;
        } else {
          qa.Cv[(size_t)m * 256 + n] = f2b(val);
          csum += val;
        }
      }
    if (z == 2) {
      csum += __shfl_xor(csum, 16);
      csum += __shfl_xor(csum, 32);
      if (quad == 0) {
        int b = bm >> 11;
        atomicAdd(&qa.vmp[b * DMM + n], csum);
      }
    }
  }
}

// ---------------- FUSED O-proj GEMM (32x256, 512 thr) + tail, ctx-merge hoisted (R12) -----
__global__ __launch_bounds__(512) void oproj_tail(const float* __restrict__ vmp,
                                                  const unsigned char* __restrict__ mapb,
                                                  const float* __restrict__ pm,
                                                  const float* __restrict__ pl,
                                                  const float* __restrict__ po,
                                                  const unsigned short* __restrict__ W,
                                                  const float* __restrict__ bias,
                                                  const float* __restrict__ X,
                                                  const float* __restrict__ g1,
                                                  const float* __restrict__ b1ln,
                                                  const float* __restrict__ w1,
                                                  const float* __restrict__ b1,
                                                  const float* __restrict__ w2,
                                                  const float* __restrict__ b2,
                                                  const float* __restrict__ g2,
                                                  const float* __restrict__ b2ln,
                                                  float* __restrict__ Out,
                                                  unsigned short* __restrict__ OutB,
                                                  unsigned short* __restrict__ OutL,
                                                  const float* __restrict__ fing,
                                                  const float* __restrict__ finb,
                                                  void* __restrict__ finOut,
                                                  const int* __restrict__ flag,
                                                  float* __restrict__ stpZ,
                                                  float* __restrict__ stp2Z) {
  __shared__ __attribute__((aligned(16))) unsigned short As[OTR][DMM];  // full ctx panel
  __shared__ __attribute__((aligned(16))) unsigned short Bs[256][32];
  __shared__ float Cs[OTR][DMM];
  __shared__ float xs[8][DMM];
  int tid = threadIdx.x;
  if (blockIdx.x == 0 && tid < DMM) {
    stpZ[tid] = 0.f;
    stp2Z[tid] = 0.f;
  }
  int bm = blockIdx.x * OTR;
  int wv = tid >> 6, lane = tid & 63;
  int l15 = lane & 15, quad = lane >> 4;
  int b = bm >> 11, l0 = bm & 2047;
  const float invL = 1.0f / (float)LL;

  // ---- phase 1: ctx A-panel for all 8 heads, once, full-block parallel ----
#pragma unroll
  for (int uu = 0; uu < 2; ++uu) {
    int u = tid * 2 + uu;            // 0..1023
    int arow = u >> 5;               // 32 rows
    int sub = u & 31;
    int h = sub >> 2, adg = sub & 3; // 8 heads x 4 col-groups
    int bh = b * HH + h;
    int l = l0 + arow;
    int q = (int)mapb[bh * 2048 + l];
    unsigned short outv[8];
    if (q) {
      size_t base = ((size_t)bh * UU + (q - 1)) * KC;
      float Mx = -1e30f;
#pragma unroll
      for (int kc = 0; kc < KC; ++kc) Mx = fmaxf(Mx, pm[base + kc]);
      float Ls = 0.f;
      float sc[KC];
#pragma unroll
      for (int kc = 0; kc < KC; ++kc) {
        sc[kc] = expf(pm[base + kc] - Mx);
        Ls += pl[base + kc] * sc[kc];
      }
      float inv = 1.0f / Ls;
#pragma unroll
      for (int j = 0; j < 8; ++j) {
        int dl = adg * 8 + j;
        float o = 0.f;
#pragma unroll
        for (int kc = 0; kc < KC; ++kc) o += po[(base + kc) * 32 + dl] * sc[kc];
        outv[j] = f2b(o * inv);
      }
    } else {
      const float* vp = vmp + b * DMM + h * EE + adg * 8;
#pragma unroll
      for (int j = 0; j < 8; ++j) outv[j] = f2b(vp[j] * invL);
    }
    *(uint4*)(&As[arow][h * EE + adg * 8]) = *(const uint4*)outv;
  }
  __syncthreads();

  // ---- phase 2: GEMM loop (pure stage+MFMA) ----
  f32x4 acc[2][2];
#pragma unroll
  for (int i = 0; i < 2; ++i)
#pragma unroll
    for (int j = 0; j < 2; ++j) acc[i][j] = (f32x4){0.f, 0.f, 0.f, 0.f};
  for (int k0 = 0; k0 < 256; k0 += 32) {
    if (k0) __syncthreads();
    {  // stage all 256 B-rows once per block (8 waves x 2 rounds x 16 rows)
      int lrw = lane >> 2, lsg = lane & 3;
#pragma unroll
      for (int s = 0; s < 2; ++s) {
        int brow = s * 128 + wv * 16;
        GLDS16(W + (size_t)(brow + lrw) * 256 + k0 + lsg * 8, &Bs[brow][0]);
      }
    }
    __syncthreads();
    short8 af[2], bfr[2];
#pragma unroll
    for (int mt = 0; mt < 2; ++mt)
      af[mt] = *(const short8*)(&As[mt * 16 + l15][k0 + quad * 8]);
#pragma unroll
    for (int nt = 0; nt < 2; ++nt)
      bfr[nt] = *(const short8*)(&Bs[wv * 32 + nt * 16 + l15][quad * 8]);
#pragma unroll
    for (int mt = 0; mt < 2; ++mt)
#pragma unroll
      for (int nt = 0; nt < 2; ++nt)
        acc[mt][nt] = __builtin_amdgcn_mfma_f32_16x16x32_bf16(af[mt], bfr[nt],
                                                              acc[mt][nt], 0, 0, 0);
  }
  // epilogue -> LDS (replaces tmp)
#pragma unroll
  for (int nt = 0; nt < 2; ++nt) {
    int n = wv * 32 + nt * 16 + l15;
    float bv = bias[n];
#pragma unroll
    for (int mt = 0; mt < 2; ++mt)
#pragma unroll
      for (int r = 0; r < 4; ++r)
        Cs[mt * 16 + quad * 4 + r][n] = acc[mt][nt][r] + bv;
  }
  __syncthreads();
  // ---- enc_tail body, verbatim, 4 rows per wave ----
  for (int rr = 0; rr < 4; ++rr) {
    int lr = wv * 4 + rr;
    size_t row = (size_t)bm + lr;
    const float* xr = X + row * DMM;
    const float* tr = Cs[lr];
    float v[4];
#pragma unroll
    for (int i = 0; i < 4; ++i) v[i] = xr[lane + 64 * i] + tr[lane + 64 * i];
    float s = wave_sum(v[0] + v[1] + v[2] + v[3]);
    float m = s * (1.0f / (float)DMM);
    float sq = 0.f;
#pragma unroll
    for (int i = 0; i < 4; ++i) { float d = v[i] - m; sq += d * d; }
    sq = wave_sum(sq);
    float rstd = rsqrtf(sq * (1.0f / (float)DMM) + 1e-5f);
    float xv[4];
#pragma unroll
    for (int i = 0; i < 4; ++i) {
      int d = lane + 64 * i;
      xv[i] = (v[i] - m) * rstd * g1[d] + b1ln[d];
      xs[wv][d] = xv[i];
    }
    __syncthreads();
    int f = lane & 15, qtr = lane >> 4;
    const float* w1p = w1 + f * DMM + qtr * 64;
    const float* xq = &xs[wv][qtr * 64];
    float pacc = 0.f;
#pragma unroll 8
    for (int d = 0; d < 64; ++d) pacc += xq[d] * w1p[d];
    pacc += __shfl_xor(pacc, 16);
    pacc += __shfl_xor(pacc, 32);
    float y1 = fmaxf(pacc + b1[f], 0.0f);
    float y1v[16];
#pragma unroll
    for (int ff = 0; ff < 16; ++ff) y1v[ff] = __shfl(y1, ff);
#pragma unroll
    for (int i = 0; i < 4; ++i) {
      int d = lane + 64 * i;
      const float* w2p = w2 + d * ITR;
      float a = b2[d];
#pragma unroll
      for (int ff = 0; ff < 16; ++ff) a += y1v[ff] * w2p[ff];
      v[i] = xv[i] + a;
    }
    s = wave_sum(v[0] + v[1] + v[2] + v[3]);
    m = s * (1.0f / (float)DMM);
    sq = 0.f;
#pragma unroll
    for (int i = 0; i < 4; ++i) { float d = v[i] - m; sq += d * d; }
    sq = wave_sum(sq);
    rstd = rsqrtf(sq * (1.0f / (float)DMM) + 1e-5f);
    float vv[4];
#pragma unroll
    for (int i = 0; i < 4; ++i) {
      int d = lane + 64 * i;
      float val = (v[i] - m) * rstd * g2[d] + b2ln[d];
      vv[i] = val;
      Out[row * DMM + d] = val;
      unsigned short hi = f2b(val);
      OutB[row * DMM + d] = hi;
      OutL[row * DMM + d] = f2b(val - bfbits(hi));
    }
    if (finOut) {
      s = wave_sum(vv[0] + vv[1] + vv[2] + vv[3]);
      m = s * (1.0f / (float)DMM);
      sq = 0.f;
#pragma unroll
      for (int i = 0; i < 4; ++i) { float d = vv[i] - m; sq += d * d; }
      sq = wave_sum(sq);
      rstd = rsqrtf(sq * (1.0f / (float)DMM) + 1e-5f);
      int isf32 = *flag;
#pragma unroll
      for (int i = 0; i < 4; ++i) {
        int d = lane + 64 * i;
        float val = (vv[i] - m) * rstd * fing[d] + finb[d];
        if (isf32) ((float*)finOut)[row * DMM + d] = val;
        else       ((unsigned short*)finOut)[row * DMM + d] = f2b(val);
      }
    }
  }
}

// ---------------- conv GEMM: A window staged once per k0, 3 taps from LDS ----------------
__global__ __launch_bounds__(256) void gemm_conv(const unsigned short* __restrict__ A,
                                                 const unsigned short* __restrict__ W,
                                                 const float* __restrict__ bias,
                                                 float* __restrict__ C,
                                                 float* __restrict__ stp,
                                                 float* __restrict__ stp2) {
  __shared__ __attribute__((aligned(16))) unsigned short As[80][32];
  __shared__ __attribute__((aligned(16))) unsigned short Bs[192][32];
  int bm = blockIdx.x * 64, bn = blockIdx.y * 64;
  int tid = threadIdx.x;
  int wv = tid >> 6, lane = tid & 63;
  int wm = wv >> 1, wn = wv & 1;
  int l15 = lane & 15, quad = lane >> 4;
  int lrow = lane >> 2, lseg = lane & 3;
  int bbase = bm & ~2047, l0 = bm & 2047;
  f32x4 acc[2][2];
#pragma unroll
  for (int i = 0; i < 2; ++i)
#pragma unroll
    for (int j = 0; j < 2; ++j) acc[i][j] = (f32x4){0.f, 0.f, 0.f, 0.f};
  for (int k0 = 0; k0 < 256; k0 += 32) {
    __syncthreads();
    for (int c = wv; c < 5; c += 4) {
      int i0 = c * 16;
      int l = (l0 - 1 + i0 + lrow + 2048) & 2047;
      GLDS16(A + (size_t)(bbase | l) * 256 + k0 + lseg * 8, &As[i0][0]);
    }
    for (int c = wv; c < 12; c += 4) {
      int i0 = c * 16;
      int tap = c >> 2, brow = (c & 3) * 16;
      GLDS16(W + (size_t)tap * 65536 + (size_t)(bn + brow + lrow) * 256 + k0 + lseg * 8,
             &Bs[i0][0]);
    }
    __syncthreads();
#pragma unroll
    for (int tap = 0; tap < 3; ++tap) {
      short8 af[2], bfr[2];
#pragma unroll
      for (int mt = 0; mt < 2; ++mt)
        af[mt] = *(const short8*)(&As[wm * 32 + mt * 16 + l15 + tap][quad * 8]);
#pragma unroll
      for (int nt = 0; nt < 2; ++nt)
        bfr[nt] = *(const short8*)(&Bs[tap * 64 + wn * 32 + nt * 16 + l15][quad * 8]);
#pragma unroll
      for (int mt = 0; mt < 2; ++mt)
#pragma unroll
        for (int nt = 0; nt < 2; ++nt)
          acc[mt][nt] = __builtin_amdgcn_mfma_f32_16x16x32_bf16(af[mt], bfr[nt],
                                                                acc[mt][nt], 0, 0, 0);
    }
  }
#pragma unroll
  for (int nt = 0; nt < 2; ++nt) {
    int n = bn + wn * 32 + nt * 16 + l15;
    float bv = bias[n];
    float s = 0.f, s2 = 0.f;
#pragma unroll
    for (int mt = 0; mt < 2; ++mt)
#pragma unroll
      for (int r = 0; r < 4; ++r) {
        int m = bm + wm * 32 + mt * 16 + quad * 4 + r;
        float val = acc[mt][nt][r] + bv;
        C[(size_t)m * 256 + n] = val;
        s += val;
        s2 += val * val;
      }
    s  += __shfl_xor(s, 16);   s  += __shfl_xor(s, 32);
    s2 += __shfl_xor(s2, 16);  s2 += __shfl_xor(s2, 32);
    if (quad == 0) {
      atomicAdd(&stp[n], s);
      atomicAdd(&stp2[n], s2);
    }
  }
}

// ---------------- M scores: wave per (b,l), inline threefry, XCD-affinity swizzle ----------
__global__ __launch_bounds__(256) void m_kernel3(const float* __restrict__ Q,
                                                 const float* __restrict__ K,
                                                 uint32_t k20, uint32_t k21,
                                                 float* __restrict__ M) {
  int bid = blockIdx.x;
  int blk = (bid & 7) * 256 + (bid >> 3);   // XCD-affinity remap (pure perf, no semantics)
  int b = blk >> 9, lc = blk & 511;
  int wave = threadIdx.x >> 6, lane = threadIdx.x & 63;
  int l = lc * 4 + wave;
  int myidx = 0;
  if (lane < UU) {
    int j = l * UU + lane;
    uint32_t o0, o1;
    const int half = (LL * UU) / 2;  // 40960
    if (j < half) {
      threefry2x32(k20, k21, (uint32_t)j, (uint32_t)(j + half), &o0, &o1);
      myidx = (int)(o0 & (LL - 1));
    } else {
      threefry2x32(k20, k21, (uint32_t)(j - half), (uint32_t)j, &o0, &o1);
      myidx = (int)(o1 & (LL - 1));
    }
  }
  float4 q4 = *(const float4*)(Q + ((size_t)(b * LL + l)) * DMM + lane * 4);
  const float* Kb = K + (size_t)b * LL * DMM;
  float mx = -1e30f, sm = 0.f;
#pragma unroll 8
  for (int u = 0; u < UU; ++u) {
    int kidx = __shfl(myidx, u);
    float4 k4 = *(const float4*)(Kb + (size_t)kidx * DMM + lane * 4);
    float s = q4.x * k4.x + q4.y * k4.y + q4.z * k4.z + q4.w * k4.w;
    s += __shfl_xor(s, 1);
    s += __shfl_xor(s, 2);
    s += __shfl_xor(s, 4);
    mx = fmaxf(mx, s);
    sm += s;
  }
  if ((lane & 7) == 0) {
    int h = lane >> 3;
    M[((size_t)(b * HH + h)) * LL + l] = mx - sm * (1.0f / (float)LL);
  }
}

// ---------------- fused topk + split-K flash attention ------------------------------------
// R15 structure with the SCORES phase also converted to MFMA: S = Q[48x32] x K^T[32x128]
// via one K-step of mfma_f32_16x16x32_bf16 (K-dim = 32 exactly). Q and K staged as bf16
// (QsB A-layout [m][k], rows 40-47 zero; KsB B-layout [n][k]). Zero Q pad rows -> pad
// scores = 0 -> ps pad rows auto-zero for the PV MFMA (explicit pad-zero dropped).
// Softmax / pm / pl / radix / PV byte-identical to R15. kr registers eliminated.
__global__ __launch_bounds__(256) void attn_part(const float* __restrict__ Q,
                                                 const float* __restrict__ K,
                                                 const unsigned short* __restrict__ Vbf,
                                                 const float* __restrict__ M,
                                                 unsigned char* __restrict__ mapb,
                                                 float* __restrict__ pm,
                                                 float* __restrict__ pl,
                                                 float* __restrict__ po) {
  __shared__ __attribute__((aligned(16))) unsigned short QsB[48][32];
  __shared__ __attribute__((aligned(16))) unsigned short KsB[KCH][32];
  __shared__ __attribute__((aligned(16))) unsigned short ps[48][KCH];
  __shared__ __attribute__((aligned(16))) unsigned short VsT[EE][KCH];
  __shared__ int qrows[40];
  __shared__ unsigned int hist[256];
  __shared__ unsigned int sA[256];
  __shared__ unsigned int wtot[4];
  __shared__ unsigned int tbv;
  int kc = blockIdx.x, bh = blockIdx.y;
  int h = bh & 7, b = bh >> 3;
  int tid = threadIdx.x;
  int wv = tid >> 6, lane = tid & 63;
  int l15 = lane & 15, quad = lane >> 4;

  // ---- independent V/K loads issued first (overlap with radix latency) ----
  {
    int row = tid >> 1, half = tid & 1;
    const unsigned short* vsrc =
        Vbf + (size_t)(b * LL + kc * KCH + row) * DMM + h * EE + half * 16;
    unsigned short tv[16];
    *(uint4*)(&tv[0]) = *(const uint4*)vsrc;
    *(uint4*)(&tv[8]) = *(const uint4*)(vsrc + 8);
#pragma unroll
    for (int j = 0; j < 16; ++j) VsT[half * 16 + j][row] = tv[j];
    // K: f32 -> bf16 into B-operand layout [key][dim]
    const float* ksrc = K + ((size_t)(b * LL + kc * KCH + row)) * DMM + h * EE + half * 16;
    unsigned short tk[16];
#pragma unroll
    for (int j = 0; j < 16; ++j) tk[j] = f2b(ksrc[j]);
    *(uint4*)(&KsB[row][half * 16]) = *(const uint4*)(&tk[0]);
    *(uint4*)(&KsB[row][half * 16 + 8]) = *(const uint4*)(&tk[8]);
  }

  // ---- exact top-40 radix select on M[bh]: packed 43-bit keys, 6 rounds (R14-proven) ----
  u64 kreg[8];
#pragma unroll
  for (int r = 0; r < 8; ++r) {
    int l = tid + 256 * r;
    float v = M[(size_t)bh * LL + l];
    uint32_t bits = __float_as_uint(v);
    uint32_t kv = (bits & 0x80000000u) ? ~bits : (bits | 0x80000000u);
    kreg[r] = ((u64)kv << 11) | (uint32_t)(2047 - l);
  }
  u64 prefix = 0;
  int rank = UU;
  for (int round = 0; round < 6; ++round) {
    int shift = 40 - 8 * round;
    u64 maskTop = (round == 0) ? 0ull : (~0ull << (48 - 8 * round));
    hist[tid] = 0;
    __syncthreads();
#pragma unroll
    for (int r = 0; r < 8; ++r) {
      u64 k = kreg[r];
      if ((k & maskTop) == prefix)
        atomicAdd(&hist[(unsigned int)((k >> shift) & 0xFFu)], 1u);
    }
    __syncthreads();
    unsigned int s = hist[tid];
#pragma unroll
    for (int off = 1; off < 64; off <<= 1) {
      unsigned int t = __shfl_down(s, off);
      if (lane + off < 64) s += t;
    }
    if (lane == 0) wtot[wv] = s;
    __syncthreads();
    unsigned int add = 0;
#pragma unroll
    for (int w = 0; w < 4; ++w)
      if (w > wv) add += wtot[w];
    sA[tid] = s + add;
    __syncthreads();
    unsigned int Sb = sA[tid];
    unsigned int Snext = (tid < 255) ? sA[tid + 1] : 0u;
    if (Sb >= (unsigned int)rank && Snext < (unsigned int)rank) tbv = (unsigned int)tid;
    __syncthreads();
    unsigned int tb = tbv;
    unsigned int above = (tb < 255u) ? sA[tb + 1] : 0u;
    rank -= (int)above;
    prefix |= ((u64)tb) << shift;
  }
  u64 T = prefix;   // exact 40th-largest packed key
  // ---- deterministic rank: in-wave prefix + cross-wave totals (exclusive over tid) ----
  int myCnt = 0;
#pragma unroll
  for (int r = 0; r < 8; ++r) myCnt += (kreg[r] >= T) ? 1 : 0;
  {
    unsigned int p = (unsigned int)myCnt;
#pragma unroll
    for (int off = 1; off < 64; off <<= 1) {
      unsigned int t = __shfl_up(p, off);
      if (lane >= off) p += t;
    }
    if (lane == 63) wtot[wv] = p;
    __syncthreads();
    unsigned int addp = 0;
#pragma unroll
    for (int w = 0; w < 4; ++w)
      if (w < wv) addp += wtot[w];
    int pos = (int)(p + addp) - myCnt;   // exclusive prefix
    bool wmap = (kc == 0);
#pragma unroll
    for (int r = 0; r < 8; ++r) {
      u64 k = kreg[r];
      int l = 2047 - (int)(uint32_t)(k & 0x7FFu);
      unsigned char mv = 0;
      if (k >= T) {
        qrows[pos] = l;
        mv = (unsigned char)(pos + 1);
        pos++;
      }
      if (wmap) mapb[bh * 2048 + l] = mv;
    }
  }
  __syncthreads();

  // ---- Q staging (bf16, A-operand layout) for the 40 selected rows; rows 40-47 zero ----
  for (int t = tid; t < 40 * 32; t += 256) {
    int q = t >> 5, d = t & 31;
    QsB[q][d] = f2b(Q[((size_t)(b * LL + qrows[q])) * DMM + h * EE + d]);
  }
  {
    int q = 40 + (tid >> 5), d = tid & 31;
    if (q < 48) QsB[q][d] = 0;   // tid 0..255 covers exactly rows 40..47
  }
  __syncthreads();
  // ---- scores via MFMA: waves 0..2, one 16-q tile x 128 keys each ----
  if (wv < 3) {
    const float scale = 0.17677669529663687f;
    short8 aq = *(const short8*)(&QsB[wv * 16 + l15][quad * 8]);
    f32x4 sacc[8];
#pragma unroll
    for (int nt = 0; nt < 8; ++nt) {
      short8 bk = *(const short8*)(&KsB[nt * 16 + l15][quad * 8]);
      sacc[nt] = __builtin_amdgcn_mfma_f32_16x16x32_bf16(
          aq, bk, (f32x4){0.f, 0.f, 0.f, 0.f}, 0, 0, 0);
    }
#pragma unroll
    for (int nt = 0; nt < 8; ++nt)
#pragma unroll
      for (int r = 0; r < 4; ++r)
        ps[wv * 16 + quad * 4 + r][nt * 16 + l15] = f2b(sacc[nt][r] * scale);
  }
  __syncthreads();
  // ---- softmax (max + exp + sum per row; writes exp back to ps; pm/pl) ----
  for (int qq = 0; qq < 10; ++qq) {
    int q = wv * 10 + qq;
    float mx = fmaxf(bfbits(ps[q][lane]), bfbits(ps[q][lane + 64]));
#pragma unroll
    for (int off = 32; off > 0; off >>= 1) mx = fmaxf(mx, __shfl_xor(mx, off));
    float e0 = expf(bfbits(ps[q][lane]) - mx);
    float e1 = expf(bfbits(ps[q][lane + 64]) - mx);
    ps[q][lane] = f2b(e0);
    ps[q][lane + 64] = f2b(e1);
    float sum = wave_sum(e0 + e1);
    size_t base = ((size_t)bh * UU + q) * KC + kc;
    if (lane == 0) { pm[base] = mx; pl[base] = sum; }
  }
  __syncthreads();
  // ---- PV via MFMA: waves 0..2 each compute one 16-row q-tile x 32 cols (R15-proven) ----
  if (wv < 3) {
    f32x4 pacc[2];
#pragma unroll
    for (int nt = 0; nt < 2; ++nt) pacc[nt] = (f32x4){0.f, 0.f, 0.f, 0.f};
#pragma unroll
    for (int kch = 0; kch < 4; ++kch) {
      short8 af = *(const short8*)(&ps[wv * 16 + l15][kch * 32 + quad * 8]);
#pragma unroll
      for (int nt = 0; nt < 2; ++nt) {
        short8 bfr = *(const short8*)(&VsT[nt * 16 + l15][kch * 32 + quad * 8]);
        pacc[nt] = __builtin_amdgcn_mfma_f32_16x16x32_bf16(af, bfr, pacc[nt], 0, 0, 0);
      }
    }
#pragma unroll
    for (int nt = 0; nt < 2; ++nt) {
      int d = nt * 16 + l15;
#pragma unroll
      for (int r = 0; r < 4; ++r) {
        int q = wv * 16 + quad * 4 + r;
        if (q < UU) {
          size_t base = ((size_t)bh * UU + q) * KC + kc;
          po[base * 32 + d] = pacc[nt][r];
        }
      }
    }
  }
}

// ---------------- bn+elu from atomic stats (+vmp zero for next layer) ----------------
__global__ __launch_bounds__(256) void bn_elu(const float* __restrict__ Y,
                                              const float* __restrict__ stp,
                                              const float* __restrict__ stp2,
                                              const float* __restrict__ g,
                                              const float* __restrict__ bb,
                                              float* __restrict__ X,
                                              unsigned short* __restrict__ XB,
                                              unsigned short* __restrict__ XL,
                                              float* __restrict__ vmpZ) {
  int gid = blockIdx.x * 256 + threadIdx.x;
  if (gid < BB * DMM) vmpZ[gid] = 0.f;
  int d = gid & 255;
  float mean = stp[d] * (1.0f / (float)ROWS);
  float var = stp2[d] * (1.0f / (float)ROWS) - mean * mean;
  float rstd = rsqrtf(var + 1e-5f);
  float v = (Y[gid] - mean) * rstd * g[d] + bb[d];
  float r = v > 0.f ? v : expm1f(v);
  X[gid] = r;
  unsigned short hi = f2b(r);
  XB[gid] = hi;
  XL[gid] = f2b(r - bfbits(hi));
}

extern "C" void kernel_launch(void* const* d_in, const int* in_sizes, int n_in,
                              void* d_out, int out_size, void* d_ws, size_t ws_size,
                              hipStream_t stream) {
  (void)in_sizes; (void)n_in; (void)out_size; (void)ws_size;

  // ---- workspace layout ----
  float* xbuf = (float*)d_ws;
  float* kb   = xbuf + NELEM;
  float* qb   = kb + NELEM;   // aliases tmp (Q dead after attn_part)
  float* tmp  = qb;
  float* Mbuf = qb + NELEM;
  float* vmp  = Mbuf + BB * HH * LL;
  float* stp  = vmp + BB * DMM;
  float* stp2 = stp + DMM;
  float* wp   = stp2 + DMM;
  const int wsz[23] = {
      NELEM,
      NLL * DMM * DMM, NLL * DMM,
      NLL * DMM * DMM, NLL * DMM,
      NLL * DMM * DMM, NLL * DMM,
      NLL * DMM * DMM, NLL * DMM,
      NLL * ITR * DMM, NLL * ITR,
      NLL * DMM * ITR, NLL * DMM,
      NLL * DMM, NLL * DMM,
      NLL * DMM, NLL * DMM,
      (NLL - 1) * DMM * DMM * 3, (NLL - 1) * DMM,
      (NLL - 1) * DMM, (NLL - 1) * DMM,
      DMM, DMM
  };
  float* fptr[23];
  fptr[0] = xbuf;
  for (int i = 1; i < 23; ++i) { fptr[i] = wp; wp += wsz[i]; }
  float* pm = wp;
  float* pl = pm + 32 * UU * KC;
  float* po = pl + 32 * UU * KC;
  unsigned short* xbf   = (unsigned short*)(po + 32 * UU * KC * 32);
  unsigned short* xlo   = xbf + NELEM;
  unsigned short* vbf   = xlo + NELEM;
  unsigned short* wqbf  = vbf + NELEM;
  unsigned short* wkbf  = wqbf + NLL * DMM * DMM;
  unsigned short* wvbf  = wkbf + NLL * DMM * DMM;
  unsigned short* wobf  = wvbf + NLL * DMM * DMM;
  unsigned short* dcwT  = wobf + NLL * DMM * DMM;
  u64* cand = (u64*)(dcwT + (NLL - 1) * 3 * DMM * DMM);  // layout kept (unused now)
  int* topb = (int*)(cand + 256 * 40);                    // layout kept (unused now)
  int* flag = topb + BB * HH * UU;
  unsigned char* mapb = (unsigned char*)(flag + 1);  // 32*2048

  // ---- convert (+cheap inline dtype probe, +dcw repack, +vmp zero, +flag publish) ----
  CvtArgs ca;
  int totalBlk = 0;
  for (int i = 0; i < 23; ++i) {
    ca.src[i] = d_in[i];
    ca.dstF[i] = fptr[i];
    ca.dstB[i] = nullptr;
    ca.dstL[i] = nullptr;
    ca.n[i] = wsz[i];
    ca.blkStart[i] = totalBlk;
    totalBlk += (wsz[i] + 255) / 256;
  }
  ca.blkStart[23] = totalBlk;
  ca.dstB[0] = xbf;  ca.dstL[0] = xlo;
  ca.dstB[1] = wqbf;
  ca.dstB[3] = wkbf;
  ca.dstB[5] = wvbf;
  ca.dstB[7] = wobf;
  ca.dcwT = dcwT;
  ca.vmpZ = vmp;
  ca.flagOut = flag;
  mega_cvt<<<totalBlk + 1, 256, 0, stream>>>(ca);

  dim3 gqkv(ROWS / 128, DMM / 64, 3);
  dim3 g64(ROWS / 64, DMM / 64);

  for (int i = 0; i < NLL; ++i) {
    QKVArgs qa;
    qa.W[0] = wqbf + (size_t)i * DMM * DMM;
    qa.W[1] = wkbf + (size_t)i * DMM * DMM;
    qa.W[2] = wvbf + (size_t)i * DMM * DMM;
    qa.bias[0] = fptr[2] + i * DMM;
    qa.bias[1] = fptr[4] + i * DMM;
    qa.bias[2] = fptr[6] + i * DMM;
    qa.Cq = qb; qa.Ck = kb; qa.Cv = vbf;
    qa.vmp = vmp;
    gemm_qkv<<<gqkv, 256, 0, stream>>>(xbf, xlo, qa);

    uint32_t ki0, ki1, a0, a1, b0, b1;
    threefry2x32(0u, 42u, 0u, (uint32_t)i, &ki0, &ki1);
    threefry2x32(ki0, ki1, 0u, 2u, &a0, &a1);
    threefry2x32(ki0, ki1, 1u, 3u, &b0, &b1);
    (void)a0; (void)b0;

    m_kernel3<<<BB * 512, 256, 0, stream>>>(qb, kb, a1, b1, Mbuf);
    attn_part<<<dim3(KC, BB * HH), 256, 0, stream>>>(qb, kb, vbf, Mbuf, mapb,
                                                     pm, pl, po);

    bool last = (i == NLL - 1);
    oproj_tail<<<ROWS / OTR, 512, 0, stream>>>(
        vmp, mapb, pm, pl, po,
        wobf + (size_t)i * DMM * DMM, fptr[8] + i * DMM,
        xbuf,
        fptr[13] + i * DMM, fptr[14] + i * DMM,
        fptr[9] + (size_t)i * ITR * DMM, fptr[10] + i * ITR,
        fptr[11] + (size_t)i * DMM * ITR, fptr[12] + i * DMM,
        fptr[15] + i * DMM, fptr[16] + i * DMM,
        xbuf, xbf, xlo,
        fptr[21], fptr[22], last ? d_out : nullptr, flag, stp, stp2);

    if (!last) {
      gemm_conv<<<g64, 256, 0, stream>>>(xbf, dcwT + (size_t)i * 3 * DMM * DMM,
                                         fptr[18] + i * DMM, tmp, stp, stp2);
      bn_elu<<<NELEM / 256, 256, 0, stream>>>(tmp, stp, stp2, fptr[19] + i * DMM,
                                              fptr[20] + i * DMM, xbuf, xbf, xlo, vmp);
    }
  }
}

// Round 17
// 438.082 us; speedup vs baseline: 1.2643x; 1.0072x over previous
//
#include <hip/hip_runtime.h>
#include <stdint.h>

#define BB 4
#define LL 2048
#define DMM 256
#define HH 8
#define EE 32
#define NLL 3
#define ITR 16
#define UU 40
#define KC 16                 // split-K chunks
#define KCH 128               // keys per chunk
#define ROWS (BB*LL)          // 8192
#define NELEM (ROWS*DMM)      // 2097152
#define OTR 32                // oproj_tail rows per block (32 -> 256 blocks, 512 thr each)
#define APAD 8                // As leading-dim pad (shorts): 264*2=528B = 132 dw = 4 mod 32
#define CPAD 4                // Cs leading-dim pad (floats): 260 dw = 4 mod 32

typedef __attribute__((ext_vector_type(8))) short short8;
typedef __attribute__((ext_vector_type(4))) float f32x4;
typedef unsigned long long u64;

#define GLDS16(g, l)                                                        \
  __builtin_amdgcn_global_load_lds(                                         \
      (const __attribute__((address_space(1))) uint32_t*)(g),               \
      (__attribute__((address_space(3))) uint32_t*)(l), 16, 0, 0)

// ---------------- bf16 bit helpers (RNE) ----------------
__device__ __forceinline__ float bfbits(unsigned short u) {
  return __uint_as_float(((uint32_t)u) << 16);
}
__device__ __forceinline__ unsigned short f2b(float f) {
  uint32_t u = __float_as_uint(f);
  uint32_t r = (u + 0x7FFFu + ((u >> 16) & 1u)) >> 16;
  return (unsigned short)r;
}

// ---------------- threefry2x32 (exact JAX semantics) ----------------
__host__ __device__ inline void threefry2x32(uint32_t k0, uint32_t k1,
                                             uint32_t x0, uint32_t x1,
                                             uint32_t* o0, uint32_t* o1) {
  uint32_t ks2 = k0 ^ k1 ^ 0x1BD11BDAu;
  x0 += k0; x1 += k1;
#define TFR(r) { x0 += x1; x1 = (x1 << (r)) | (x1 >> (32 - (r))); x1 ^= x0; }
  TFR(13) TFR(15) TFR(26) TFR(6)
  x0 += k1;  x1 += ks2 + 1u;
  TFR(17) TFR(29) TFR(16) TFR(24)
  x0 += ks2; x1 += k0 + 2u;
  TFR(13) TFR(15) TFR(26) TFR(6)
  x0 += k0;  x1 += k1 + 3u;
  TFR(17) TFR(29) TFR(16) TFR(24)
  x0 += k1;  x1 += ks2 + 4u;
  TFR(13) TFR(15) TFR(26) TFR(6)
  x0 += ks2; x1 += k0 + 5u;
#undef TFR
  *o0 = x0; *o1 = x1;
}

__device__ __forceinline__ float wave_sum(float v) {
#pragma unroll
  for (int off = 32; off > 0; off >>= 1) v += __shfl_xor(v, off);
  return v;
}

// ---------------- mega convert (+hi/lo splits, +dcw repack, +vmp zero, +cheap inline probe) -
struct CvtArgs {
  const void* src[23];
  float* dstF[23];
  unsigned short* dstB[23];
  unsigned short* dstL[23];
  int n[23];
  int blkStart[24];
  unsigned short* dcwT;
  float* vmpZ;     // zero BB*DMM floats
  int* flagOut;    // published dtype flag
};
__global__ __launch_bounds__(256) void mega_cvt(CvtArgs a) {
  // ---- inline dtype probe: 512 shorts (2/thread). bf16 data -> cnt~0; f32 data -> cnt~228.
  __shared__ int cnt;
  if (threadIdx.x == 0) cnt = 0;
  __syncthreads();
  {
    const unsigned short* u = (const unsigned short*)a.src[0];
    int bad = 0;
#pragma unroll
    for (int rep = 0; rep < 2; ++rep) {
      float v = bfbits(u[threadIdx.x + 256 * rep]);
      float av = fabsf(v);
      bool ok = (v == 0.0f) || (av > 1e-4f && av < 100.0f);
      if (!ok) bad++;
    }
    if (bad) atomicAdd(&cnt, bad);
  }
  __syncthreads();
  int isf32 = (cnt > 25) ? 1 : 0;

  int bid = blockIdx.x;
  if (bid == a.blkStart[23]) {
    for (int t = threadIdx.x; t < BB * DMM; t += 256) a.vmpZ[t] = 0.f;
    if (threadIdx.x == 0) *a.flagOut = isf32;
    return;
  }
  int i = 0;
  while (i < 22 && bid >= a.blkStart[i + 1]) ++i;
  int e = (bid - a.blkStart[i]) * 256 + (int)threadIdx.x;
  if (e >= a.n[i]) return;
  float v; unsigned short rw;
  if (isf32) { v = ((const float*)a.src[i])[e]; rw = f2b(v); }
  else       { rw = ((const unsigned short*)a.src[i])[e]; v = bfbits(rw); }
  a.dstF[i][e] = v;
  if (a.dstB[i]) a.dstB[i][e] = rw;
  if (a.dstL[i]) a.dstL[i][e] = f2b(v - bfbits(rw));
  if (i == 17) {  // dcw: [ly][n][k][t] -> [ly][t][n][k] bf16
    int ly = e / 196608;
    int r = e - ly * 196608;
    int n = r / 768;
    int rem = r - n * 768;
    int k = rem / 3, t = rem - k * 3;
    a.dcwT[ly * 196608 + t * 65536 + n * 256 + k] = rw;
  }
}

// ---------------- QKV MFMA GEMM: z=0:Q 1:K (hi/lo 2-pass, f32 out) 2:V (bf16 out + vmean) --
// (round-0 proven version: BK=32, [128][32]/[64][32] LDS)
struct QKVArgs {
  const unsigned short* W[3];
  const float* bias[3];
  float* Cq;
  float* Ck;
  unsigned short* Cv;
  float* vmp;
};
__global__ __launch_bounds__(256) void gemm_qkv(const unsigned short* __restrict__ Ahi,
                                                const unsigned short* __restrict__ Alo,
                                                QKVArgs qa) {
  __shared__ __attribute__((aligned(16))) unsigned short AsH[128][32];
  __shared__ __attribute__((aligned(16))) unsigned short AsL[128][32];
  __shared__ __attribute__((aligned(16))) unsigned short Bs[64][32];
  int z = blockIdx.z;
  const unsigned short* W = qa.W[z];
  const float* bias = qa.bias[z];
  bool twoPass = (z < 2);
  int bm = blockIdx.x * 128, bn = blockIdx.y * 64;
  int tid = threadIdx.x;
  int wv = tid >> 6, lane = tid & 63;
  int wm = wv >> 1, wn = wv & 1;
  int l15 = lane & 15, quad = lane >> 4;
  int lrow = lane >> 2, lseg = lane & 3;
  f32x4 acc[4][2];
#pragma unroll
  for (int i = 0; i < 4; ++i)
#pragma unroll
    for (int j = 0; j < 2; ++j) acc[i][j] = (f32x4){0.f, 0.f, 0.f, 0.f};
  for (int k0 = 0; k0 < 256; k0 += 32) {
    __syncthreads();
#pragma unroll
    for (int s = 0; s < 2; ++s) {
      int brow = (wv + s * 4) * 16;
      size_t goff = (size_t)(bm + brow + lrow) * 256 + k0 + lseg * 8;
      GLDS16(Ahi + goff, &AsH[brow][0]);
      if (twoPass) GLDS16(Alo + goff, &AsL[brow][0]);
    }
    {
      int brow = wv * 16;
      GLDS16(W + (size_t)(bn + brow + lrow) * 256 + k0 + lseg * 8, &Bs[brow][0]);
    }
    __syncthreads();
    short8 ah[4], bfr[2];
#pragma unroll
    for (int mt = 0; mt < 4; ++mt)
      ah[mt] = *(const short8*)(&AsH[wm * 64 + mt * 16 + l15][quad * 8]);
#pragma unroll
    for (int nt = 0; nt < 2; ++nt)
      bfr[nt] = *(const short8*)(&Bs[wn * 32 + nt * 16 + l15][quad * 8]);
#pragma unroll
    for (int mt = 0; mt < 4; ++mt)
#pragma unroll
      for (int nt = 0; nt < 2; ++nt)
        acc[mt][nt] = __builtin_amdgcn_mfma_f32_16x16x32_bf16(ah[mt], bfr[nt],
                                                              acc[mt][nt], 0, 0, 0);
    if (twoPass) {
      short8 al[4];
#pragma unroll
      for (int mt = 0; mt < 4; ++mt)
        al[mt] = *(const short8*)(&AsL[wm * 64 + mt * 16 + l15][quad * 8]);
#pragma unroll
      for (int mt = 0; mt < 4; ++mt)
#pragma unroll
        for (int nt = 0; nt < 2; ++nt)
          acc[mt][nt] = __builtin_amdgcn_mfma_f32_16x16x32_bf16(al[mt], bfr[nt],
                                                                acc[mt][nt], 0, 0, 0);
    }
  }
  float* C = (z == 0) ? qa.Cq : qa.Ck;
#pragma unroll
  for (int nt = 0; nt < 2; ++nt) {
    int n = bn + wn * 32 + nt * 16 + l15;
    float bv = bias[n];
    float csum = 0.f;
#pragma unroll
    for (int mt = 0; mt < 4; ++mt)
#pragma unroll
      for (int r = 0; r < 4; ++r) {
        int m = bm + wm * 64 + mt * 16 + quad * 4 + r;
        float val = acc[mt][nt][r] + bv;
        if (z < 2) {
          C[(size_t)m * 256 + n] = val;
        } else {
          qa.Cv[(size_t)m * 256 + n] = f2b(val);
          csum += val;
        }
      }
    if (z == 2) {
      csum += __shfl_xor(csum, 16);
      csum += __shfl_xor(csum, 32);
      if (quad == 0) {
        int b = bm >> 11;
        atomicAdd(&qa.vmp[b * DMM + n], csum);
      }
    }
  }
}

// ---------------- FUSED O-proj GEMM (32x256, 512 thr) + tail, ctx-merge hoisted -----------
// R16 + LDS bank-conflict fix (G4): As row stride 256 shorts = 128 dw = 0 mod 32 made the
// 16-lane A-fragment read a 16-way same-bank conflict (R16 PMC: 1.67M conflicts). Pad As
// +8 shorts (132 dw = 4 mod 32 -> 2-way, free) and Cs +4 floats (260 dw = 4 mod 32).
// Pure layout change; all indexing adapts; 16B alignment preserved -> bitwise-identical.
__global__ __launch_bounds__(512) void oproj_tail(const float* __restrict__ vmp,
                                                  const unsigned char* __restrict__ mapb,
                                                  const float* __restrict__ pm,
                                                  const float* __restrict__ pl,
                                                  const float* __restrict__ po,
                                                  const unsigned short* __restrict__ W,
                                                  const float* __restrict__ bias,
                                                  const float* __restrict__ X,
                                                  const float* __restrict__ g1,
                                                  const float* __restrict__ b1ln,
                                                  const float* __restrict__ w1,
                                                  const float* __restrict__ b1,
                                                  const float* __restrict__ w2,
                                                  const float* __restrict__ b2,
                                                  const float* __restrict__ g2,
                                                  const float* __restrict__ b2ln,
                                                  float* __restrict__ Out,
                                                  unsigned short* __restrict__ OutB,
                                                  unsigned short* __restrict__ OutL,
                                                  const float* __restrict__ fing,
                                                  const float* __restrict__ finb,
                                                  void* __restrict__ finOut,
                                                  const int* __restrict__ flag,
                                                  float* __restrict__ stpZ,
                                                  float* __restrict__ stp2Z) {
  __shared__ __attribute__((aligned(16))) unsigned short As[OTR][DMM + APAD];
  __shared__ __attribute__((aligned(16))) unsigned short Bs[256][32];
  __shared__ float Cs[OTR][DMM + CPAD];
  __shared__ float xs[8][DMM];
  int tid = threadIdx.x;
  if (blockIdx.x == 0 && tid < DMM) {
    stpZ[tid] = 0.f;
    stp2Z[tid] = 0.f;
  }
  int bm = blockIdx.x * OTR;
  int wv = tid >> 6, lane = tid & 63;
  int l15 = lane & 15, quad = lane >> 4;
  int b = bm >> 11, l0 = bm & 2047;
  const float invL = 1.0f / (float)LL;

  // ---- phase 1: ctx A-panel for all 8 heads, once, full-block parallel ----
#pragma unroll
  for (int uu = 0; uu < 2; ++uu) {
    int u = tid * 2 + uu;            // 0..1023
    int arow = u >> 5;               // 32 rows
    int sub = u & 31;
    int h = sub >> 2, adg = sub & 3; // 8 heads x 4 col-groups
    int bh = b * HH + h;
    int l = l0 + arow;
    int q = (int)mapb[bh * 2048 + l];
    unsigned short outv[8];
    if (q) {
      size_t base = ((size_t)bh * UU + (q - 1)) * KC;
      float Mx = -1e30f;
#pragma unroll
      for (int kc = 0; kc < KC; ++kc) Mx = fmaxf(Mx, pm[base + kc]);
      float Ls = 0.f;
      float sc[KC];
#pragma unroll
      for (int kc = 0; kc < KC; ++kc) {
        sc[kc] = expf(pm[base + kc] - Mx);
        Ls += pl[base + kc] * sc[kc];
      }
      float inv = 1.0f / Ls;
#pragma unroll
      for (int j = 0; j < 8; ++j) {
        int dl = adg * 8 + j;
        float o = 0.f;
#pragma unroll
        for (int kc = 0; kc < KC; ++kc) o += po[(base + kc) * 32 + dl] * sc[kc];
        outv[j] = f2b(o * inv);
      }
    } else {
      const float* vp = vmp + b * DMM + h * EE + adg * 8;
#pragma unroll
      for (int j = 0; j < 8; ++j) outv[j] = f2b(vp[j] * invL);
    }
    *(uint4*)(&As[arow][h * EE + adg * 8]) = *(const uint4*)outv;
  }
  __syncthreads();

  // ---- phase 2: GEMM loop (pure stage+MFMA) ----
  f32x4 acc[2][2];
#pragma unroll
  for (int i = 0; i < 2; ++i)
#pragma unroll
    for (int j = 0; j < 2; ++j) acc[i][j] = (f32x4){0.f, 0.f, 0.f, 0.f};
  for (int k0 = 0; k0 < 256; k0 += 32) {
    if (k0) __syncthreads();
    {  // stage all 256 B-rows once per block (8 waves x 2 rounds x 16 rows)
      int lrw = lane >> 2, lsg = lane & 3;
#pragma unroll
      for (int s = 0; s < 2; ++s) {
        int brow = s * 128 + wv * 16;
        GLDS16(W + (size_t)(brow + lrw) * 256 + k0 + lsg * 8, &Bs[brow][0]);
      }
    }
    __syncthreads();
    short8 af[2], bfr[2];
#pragma unroll
    for (int mt = 0; mt < 2; ++mt)
      af[mt] = *(const short8*)(&As[mt * 16 + l15][k0 + quad * 8]);
#pragma unroll
    for (int nt = 0; nt < 2; ++nt)
      bfr[nt] = *(const short8*)(&Bs[wv * 32 + nt * 16 + l15][quad * 8]);
#pragma unroll
    for (int mt = 0; mt < 2; ++mt)
#pragma unroll
      for (int nt = 0; nt < 2; ++nt)
        acc[mt][nt] = __builtin_amdgcn_mfma_f32_16x16x32_bf16(af[mt], bfr[nt],
                                                              acc[mt][nt], 0, 0, 0);
  }
  // epilogue -> LDS (replaces tmp)
#pragma unroll
  for (int nt = 0; nt < 2; ++nt) {
    int n = wv * 32 + nt * 16 + l15;
    float bv = bias[n];
#pragma unroll
    for (int mt = 0; mt < 2; ++mt)
#pragma unroll
      for (int r = 0; r < 4; ++r)
        Cs[mt * 16 + quad * 4 + r][n] = acc[mt][nt][r] + bv;
  }
  __syncthreads();
  // ---- enc_tail body, verbatim, 4 rows per wave ----
  for (int rr = 0; rr < 4; ++rr) {
    int lr = wv * 4 + rr;
    size_t row = (size_t)bm + lr;
    const float* xr = X + row * DMM;
    const float* tr = Cs[lr];
    float v[4];
#pragma unroll
    for (int i = 0; i < 4; ++i) v[i] = xr[lane + 64 * i] + tr[lane + 64 * i];
    float s = wave_sum(v[0] + v[1] + v[2] + v[3]);
    float m = s * (1.0f / (float)DMM);
    float sq = 0.f;
#pragma unroll
    for (int i = 0; i < 4; ++i) { float d = v[i] - m; sq += d * d; }
    sq = wave_sum(sq);
    float rstd = rsqrtf(sq * (1.0f / (float)DMM) + 1e-5f);
    float xv[4];
#pragma unroll
    for (int i = 0; i < 4; ++i) {
      int d = lane + 64 * i;
      xv[i] = (v[i] - m) * rstd * g1[d] + b1ln[d];
      xs[wv][d] = xv[i];
    }
    __syncthreads();
    int f = lane & 15, qtr = lane >> 4;
    const float* w1p = w1 + f * DMM + qtr * 64;
    const float* xq = &xs[wv][qtr * 64];
    float pacc = 0.f;
#pragma unroll 8
    for (int d = 0; d < 64; ++d) pacc += xq[d] * w1p[d];
    pacc += __shfl_xor(pacc, 16);
    pacc += __shfl_xor(pacc, 32);
    float y1 = fmaxf(pacc + b1[f], 0.0f);
    float y1v[16];
#pragma unroll
    for (int ff = 0; ff < 16; ++ff) y1v[ff] = __shfl(y1, ff);
#pragma unroll
    for (int i = 0; i < 4; ++i) {
      int d = lane + 64 * i;
      const float* w2p = w2 + d * ITR;
      float a = b2[d];
#pragma unroll
      for (int ff = 0; ff < 16; ++ff) a += y1v[ff] * w2p[ff];
      v[i] = xv[i] + a;
    }
    s = wave_sum(v[0] + v[1] + v[2] + v[3]);
    m = s * (1.0f / (float)DMM);
    sq = 0.f;
#pragma unroll
    for (int i = 0; i < 4; ++i) { float d = v[i] - m; sq += d * d; }
    sq = wave_sum(sq);
    rstd = rsqrtf(sq * (1.0f / (float)DMM) + 1e-5f);
    float vv[4];
#pragma unroll
    for (int i = 0; i < 4; ++i) {
      int d = lane + 64 * i;
      float val = (v[i] - m) * rstd * g2[d] + b2ln[d];
      vv[i] = val;
      Out[row * DMM + d] = val;
      unsigned short hi = f2b(val);
      OutB[row * DMM + d] = hi;
      OutL[row * DMM + d] = f2b(val - bfbits(hi));
    }
    if (finOut) {
      s = wave_sum(vv[0] + vv[1] + vv[2] + vv[3]);
      m = s * (1.0f / (float)DMM);
      sq = 0.f;
#pragma unroll
      for (int i = 0; i < 4; ++i) { float d = vv[i] - m; sq += d * d; }
      sq = wave_sum(sq);
      rstd = rsqrtf(sq * (1.0f / (float)DMM) + 1e-5f);
      int isf32 = *flag;
#pragma unroll
      for (int i = 0; i < 4; ++i) {
        int d = lane + 64 * i;
        float val = (vv[i] - m) * rstd * fing[d] + finb[d];
        if (isf32) ((float*)finOut)[row * DMM + d] = val;
        else       ((unsigned short*)finOut)[row * DMM + d] = f2b(val);
      }
    }
  }
}

// ---------------- conv GEMM: A window staged once per k0, 3 taps from LDS ----------------
__global__ __launch_bounds__(256) void gemm_conv(const unsigned short* __restrict__ A,
                                                 const unsigned short* __restrict__ W,
                                                 const float* __restrict__ bias,
                                                 float* __restrict__ C,
                                                 float* __restrict__ stp,
                                                 float* __restrict__ stp2) {
  __shared__ __attribute__((aligned(16))) unsigned short As[80][32];
  __shared__ __attribute__((aligned(16))) unsigned short Bs[192][32];
  int bm = blockIdx.x * 64, bn = blockIdx.y * 64;
  int tid = threadIdx.x;
  int wv = tid >> 6, lane = tid & 63;
  int wm = wv >> 1, wn = wv & 1;
  int l15 = lane & 15, quad = lane >> 4;
  int lrow = lane >> 2, lseg = lane & 3;
  int bbase = bm & ~2047, l0 = bm & 2047;
  f32x4 acc[2][2];
#pragma unroll
  for (int i = 0; i < 2; ++i)
#pragma unroll
    for (int j = 0; j < 2; ++j) acc[i][j] = (f32x4){0.f, 0.f, 0.f, 0.f};
  for (int k0 = 0; k0 < 256; k0 += 32) {
    __syncthreads();
    for (int c = wv; c < 5; c += 4) {
      int i0 = c * 16;
      int l = (l0 - 1 + i0 + lrow + 2048) & 2047;
      GLDS16(A + (size_t)(bbase | l) * 256 + k0 + lseg * 8, &As[i0][0]);
    }
    for (int c = wv; c < 12; c += 4) {
      int i0 = c * 16;
      int tap = c >> 2, brow = (c & 3) * 16;
      GLDS16(W + (size_t)tap * 65536 + (size_t)(bn + brow + lrow) * 256 + k0 + lseg * 8,
             &Bs[i0][0]);
    }
    __syncthreads();
#pragma unroll
    for (int tap = 0; tap < 3; ++tap) {
      short8 af[2], bfr[2];
#pragma unroll
      for (int mt = 0; mt < 2; ++mt)
        af[mt] = *(const short8*)(&As[wm * 32 + mt * 16 + l15 + tap][quad * 8]);
#pragma unroll
      for (int nt = 0; nt < 2; ++nt)
        bfr[nt] = *(const short8*)(&Bs[tap * 64 + wn * 32 + nt * 16 + l15][quad * 8]);
#pragma unroll
      for (int mt = 0; mt < 2; ++mt)
#pragma unroll
        for (int nt = 0; nt < 2; ++nt)
          acc[mt][nt] = __builtin_amdgcn_mfma_f32_16x16x32_bf16(af[mt], bfr[nt],
                                                                acc[mt][nt], 0, 0, 0);
    }
  }
#pragma unroll
  for (int nt = 0; nt < 2; ++nt) {
    int n = bn + wn * 32 + nt * 16 + l15;
    float bv = bias[n];
    float s = 0.f, s2 = 0.f;
#pragma unroll
    for (int mt = 0; mt < 2; ++mt)
#pragma unroll
      for (int r = 0; r < 4; ++r) {
        int m = bm + wm * 32 + mt * 16 + quad * 4 + r;
        float val = acc[mt][nt][r] + bv;
        C[(size_t)m * 256 + n] = val;
        s += val;
        s2 += val * val;
      }
    s  += __shfl_xor(s, 16);   s  += __shfl_xor(s, 32);
    s2 += __shfl_xor(s2, 16);  s2 += __shfl_xor(s2, 32);
    if (quad == 0) {
      atomicAdd(&stp[n], s);
      atomicAdd(&stp2[n], s2);
    }
  }
}

// ---------------- M scores: wave per (b,l), inline threefry, XCD-affinity swizzle ----------
__global__ __launch_bounds__(256) void m_kernel3(const float* __restrict__ Q,
                                                 const float* __restrict__ K,
                                                 uint32_t k20, uint32_t k21,
                                                 float* __restrict__ M) {
  int bid = blockIdx.x;
  int blk = (bid & 7) * 256 + (bid >> 3);   // XCD-affinity remap (pure perf, no semantics)
  int b = blk >> 9, lc = blk & 511;
  int wave = threadIdx.x >> 6, lane = threadIdx.x & 63;
  int l = lc * 4 + wave;
  int myidx = 0;
  if (lane < UU) {
    int j = l * UU + lane;
    uint32_t o0, o1;
    const int half = (LL * UU) / 2;  // 40960
    if (j < half) {
      threefry2x32(k20, k21, (uint32_t)j, (uint32_t)(j + half), &o0, &o1);
      myidx = (int)(o0 & (LL - 1));
    } else {
      threefry2x32(k20, k21, (uint32_t)(j - half), (uint32_t)j, &o0, &o1);
      myidx = (int)(o1 & (LL - 1));
    }
  }
  float4 q4 = *(const float4*)(Q + ((size_t)(b * LL + l)) * DMM + lane * 4);
  const float* Kb = K + (size_t)b * LL * DMM;
  float mx = -1e30f, sm = 0.f;
#pragma unroll 8
  for (int u = 0; u < UU; ++u) {
    int kidx = __shfl(myidx, u);
    float4 k4 = *(const float4*)(Kb + (size_t)kidx * DMM + lane * 4);
    float s = q4.x * k4.x + q4.y * k4.y + q4.z * k4.z + q4.w * k4.w;
    s += __shfl_xor(s, 1);
    s += __shfl_xor(s, 2);
    s += __shfl_xor(s, 4);
    mx = fmaxf(mx, s);
    sm += s;
  }
  if ((lane & 7) == 0) {
    int h = lane >> 3;
    M[((size_t)(b * HH + h)) * LL + l] = mx - sm * (1.0f / (float)LL);
  }
}

// ---------------- fused topk + split-K flash attention (R16-proven) -----------------------
__global__ __launch_bounds__(256) void attn_part(const float* __restrict__ Q,
                                                 const float* __restrict__ K,
                                                 const unsigned short* __restrict__ Vbf,
                                                 const float* __restrict__ M,
                                                 unsigned char* __restrict__ mapb,
                                                 float* __restrict__ pm,
                                                 float* __restrict__ pl,
                                                 float* __restrict__ po) {
  __shared__ __attribute__((aligned(16))) unsigned short QsB[48][32];
  __shared__ __attribute__((aligned(16))) unsigned short KsB[KCH][32];
  __shared__ __attribute__((aligned(16))) unsigned short ps[48][KCH];
  __shared__ __attribute__((aligned(16))) unsigned short VsT[EE][KCH];
  __shared__ int qrows[40];
  __shared__ unsigned int hist[256];
  __shared__ unsigned int sA[256];
  __shared__ unsigned int wtot[4];
  __shared__ unsigned int tbv;
  int kc = blockIdx.x, bh = blockIdx.y;
  int h = bh & 7, b = bh >> 3;
  int tid = threadIdx.x;
  int wv = tid >> 6, lane = tid & 63;
  int l15 = lane & 15, quad = lane >> 4;

  // ---- independent V/K loads issued first (overlap with radix latency) ----
  {
    int row = tid >> 1, half = tid & 1;
    const unsigned short* vsrc =
        Vbf + (size_t)(b * LL + kc * KCH + row) * DMM + h * EE + half * 16;
    unsigned short tv[16];
    *(uint4*)(&tv[0]) = *(const uint4*)vsrc;
    *(uint4*)(&tv[8]) = *(const uint4*)(vsrc + 8);
#pragma unroll
    for (int j = 0; j < 16; ++j) VsT[half * 16 + j][row] = tv[j];
    // K: f32 -> bf16 into B-operand layout [key][dim]
    const float* ksrc = K + ((size_t)(b * LL + kc * KCH + row)) * DMM + h * EE + half * 16;
    unsigned short tk[16];
#pragma unroll
    for (int j = 0; j < 16; ++j) tk[j] = f2b(ksrc[j]);
    *(uint4*)(&KsB[row][half * 16]) = *(const uint4*)(&tk[0]);
    *(uint4*)(&KsB[row][half * 16 + 8]) = *(const uint4*)(&tk[8]);
  }

  // ---- exact top-40 radix select on M[bh]: packed 43-bit keys, 6 rounds (R14-proven) ----
  u64 kreg[8];
#pragma unroll
  for (int r = 0; r < 8; ++r) {
    int l = tid + 256 * r;
    float v = M[(size_t)bh * LL + l];
    uint32_t bits = __float_as_uint(v);
    uint32_t kv = (bits & 0x80000000u) ? ~bits : (bits | 0x80000000u);
    kreg[r] = ((u64)kv << 11) | (uint32_t)(2047 - l);
  }
  u64 prefix = 0;
  int rank = UU;
  for (int round = 0; round < 6; ++round) {
    int shift = 40 - 8 * round;
    u64 maskTop = (round == 0) ? 0ull : (~0ull << (48 - 8 * round));
    hist[tid] = 0;
    __syncthreads();
#pragma unroll
    for (int r = 0; r < 8; ++r) {
      u64 k = kreg[r];
      if ((k & maskTop) == prefix)
        atomicAdd(&hist[(unsigned int)((k >> shift) & 0xFFu)], 1u);
    }
    __syncthreads();
    unsigned int s = hist[tid];
#pragma unroll
    for (int off = 1; off < 64; off <<= 1) {
      unsigned int t = __shfl_down(s, off);
      if (lane + off < 64) s += t;
    }
    if (lane == 0) wtot[wv] = s;
    __syncthreads();
    unsigned int add = 0;
#pragma unroll
    for (int w = 0; w < 4; ++w)
      if (w > wv) add += wtot[w];
    sA[tid] = s + add;
    __syncthreads();
    unsigned int Sb = sA[tid];
    unsigned int Snext = (tid < 255) ? sA[tid + 1] : 0u;
    if (Sb >= (unsigned int)rank && Snext < (unsigned int)rank) tbv = (unsigned int)tid;
    __syncthreads();
    unsigned int tb = tbv;
    unsigned int above = (tb < 255u) ? sA[tb + 1] : 0u;
    rank -= (int)above;
    prefix |= ((u64)tb) << shift;
  }
  u64 T = prefix;   // exact 40th-largest packed key
  // ---- deterministic rank: in-wave prefix + cross-wave totals (exclusive over tid) ----
  int myCnt = 0;
#pragma unroll
  for (int r = 0; r < 8; ++r) myCnt += (kreg[r] >= T) ? 1 : 0;
  {
    unsigned int p = (unsigned int)myCnt;
#pragma unroll
    for (int off = 1; off < 64; off <<= 1) {
      unsigned int t = __shfl_up(p, off);
      if (lane >= off) p += t;
    }
    if (lane == 63) wtot[wv] = p;
    __syncthreads();
    unsigned int addp = 0;
#pragma unroll
    for (int w = 0; w < 4; ++w)
      if (w < wv) addp += wtot[w];
    int pos = (int)(p + addp) - myCnt;   // exclusive prefix
    bool wmap = (kc == 0);
#pragma unroll
    for (int r = 0; r < 8; ++r) {
      u64 k = kreg[r];
      int l = 2047 - (int)(uint32_t)(k & 0x7FFu);
      unsigned char mv = 0;
      if (k >= T) {
        qrows[pos] = l;
        mv = (unsigned char)(pos + 1);
        pos++;
      }
      if (wmap) mapb[bh * 2048 + l] = mv;
    }
  }
  __syncthreads();

  // ---- Q staging (bf16, A-operand layout) for the 40 selected rows; rows 40-47 zero ----
  for (int t = tid; t < 40 * 32; t += 256) {
    int q = t >> 5, d = t & 31;
    QsB[q][d] = f2b(Q[((size_t)(b * LL + qrows[q])) * DMM + h * EE + d]);
  }
  {
    int q = 40 + (tid >> 5), d = tid & 31;
    if (q < 48) QsB[q][d] = 0;   // tid 0..255 covers exactly rows 40..47
  }
  __syncthreads();
  // ---- scores via MFMA: waves 0..2, one 16-q tile x 128 keys each ----
  if (wv < 3) {
    const float scale = 0.17677669529663687f;
    short8 aq = *(const short8*)(&QsB[wv * 16 + l15][quad * 8]);
    f32x4 sacc[8];
#pragma unroll
    for (int nt = 0; nt < 8; ++nt) {
      short8 bk = *(const short8*)(&KsB[nt * 16 + l15][quad * 8]);
      sacc[nt] = __builtin_amdgcn_mfma_f32_16x16x32_bf16(
          aq, bk, (f32x4){0.f, 0.f, 0.f, 0.f}, 0, 0, 0);
    }
#pragma unroll
    for (int nt = 0; nt < 8; ++nt)
#pragma unroll
      for (int r = 0; r < 4; ++r)
        ps[wv * 16 + quad * 4 + r][nt * 16 + l15] = f2b(sacc[nt][r] * scale);
  }
  __syncthreads();
  // ---- softmax (max + exp + sum per row; writes exp back to ps; pm/pl) ----
  for (int qq = 0; qq < 10; ++qq) {
    int q = wv * 10 + qq;
    float mx = fmaxf(bfbits(ps[q][lane]), bfbits(ps[q][lane + 64]));
#pragma unroll
    for (int off = 32; off > 0; off >>= 1) mx = fmaxf(mx, __shfl_xor(mx, off));
    float e0 = expf(bfbits(ps[q][lane]) - mx);
    float e1 = expf(bfbits(ps[q][lane + 64]) - mx);
    ps[q][lane] = f2b(e0);
    ps[q][lane + 64] = f2b(e1);
    float sum = wave_sum(e0 + e1);
    size_t base = ((size_t)bh * UU + q) * KC + kc;
    if (lane == 0) { pm[base] = mx; pl[base] = sum; }
  }
  __syncthreads();
  // ---- PV via MFMA: waves 0..2 each compute one 16-row q-tile x 32 cols (R15-proven) ----
  if (wv < 3) {
    f32x4 pacc[2];
#pragma unroll
    for (int nt = 0; nt < 2; ++nt) pacc[nt] = (f32x4){0.f, 0.f, 0.f, 0.f};
#pragma unroll
    for (int kch = 0; kch < 4; ++kch) {
      short8 af = *(const short8*)(&ps[wv * 16 + l15][kch * 32 + quad * 8]);
#pragma unroll
      for (int nt = 0; nt < 2; ++nt) {
        short8 bfr = *(const short8*)(&VsT[nt * 16 + l15][kch * 32 + quad * 8]);
        pacc[nt] = __builtin_amdgcn_mfma_f32_16x16x32_bf16(af, bfr, pacc[nt], 0, 0, 0);
      }
    }
#pragma unroll
    for (int nt = 0; nt < 2; ++nt) {
      int d = nt * 16 + l15;
#pragma unroll
      for (int r = 0; r < 4; ++r) {
        int q = wv * 16 + quad * 4 + r;
        if (q < UU) {
          size_t base = ((size_t)bh * UU + q) * KC + kc;
          po[base * 32 + d] = pacc[nt][r];
        }
      }
    }
  }
}

// ---------------- bn+elu from atomic stats (+vmp zero for next layer) ----------------
__global__ __launch_bounds__(256) void bn_elu(const float* __restrict__ Y,
                                              const float* __restrict__ stp,
                                              const float* __restrict__ stp2,
                                              const float* __restrict__ g,
                                              const float* __restrict__ bb,
                                              float* __restrict__ X,
                                              unsigned short* __restrict__ XB,
                                              unsigned short* __restrict__ XL,
                                              float* __restrict__ vmpZ) {
  int gid = blockIdx.x * 256 + threadIdx.x;
  if (gid < BB * DMM) vmpZ[gid] = 0.f;
  int d = gid & 255;
  float mean = stp[d] * (1.0f / (float)ROWS);
  float var = stp2[d] * (1.0f / (float)ROWS) - mean * mean;
  float rstd = rsqrtf(var + 1e-5f);
  float v = (Y[gid] - mean) * rstd * g[d] + bb[d];
  float r = v > 0.f ? v : expm1f(v);
  X[gid] = r;
  unsigned short hi = f2b(r);
  XB[gid] = hi;
  XL[gid] = f2b(r - bfbits(hi));
}

extern "C" void kernel_launch(void* const* d_in, const int* in_sizes, int n_in,
                              void* d_out, int out_size, void* d_ws, size_t ws_size,
                              hipStream_t stream) {
  (void)in_sizes; (void)n_in; (void)out_size; (void)ws_size;

  // ---- workspace layout ----
  float* xbuf = (float*)d_ws;
  float* kb   = xbuf + NELEM;
  float* qb   = kb + NELEM;   // aliases tmp (Q dead after attn_part)
  float* tmp  = qb;
  float* Mbuf = qb + NELEM;
  float* vmp  = Mbuf + BB * HH * LL;
  float* stp  = vmp + BB * DMM;
  float* stp2 = stp + DMM;
  float* wp   = stp2 + DMM;
  const int wsz[23] = {
      NELEM,
      NLL * DMM * DMM, NLL * DMM,
      NLL * DMM * DMM, NLL * DMM,
      NLL * DMM * DMM, NLL * DMM,
      NLL * DMM * DMM, NLL * DMM,
      NLL * ITR * DMM, NLL * ITR,
      NLL * DMM * ITR, NLL * DMM,
      NLL * DMM, NLL * DMM,
      NLL * DMM, NLL * DMM,
      (NLL - 1) * DMM * DMM * 3, (NLL - 1) * DMM,
      (NLL - 1) * DMM, (NLL - 1) * DMM,
      DMM, DMM
  };
  float* fptr[23];
  fptr[0] = xbuf;
  for (int i = 1; i < 23; ++i) { fptr[i] = wp; wp += wsz[i]; }
  float* pm = wp;
  float* pl = pm + 32 * UU * KC;
  float* po = pl + 32 * UU * KC;
  unsigned short* xbf   = (unsigned short*)(po + 32 * UU * KC * 32);
  unsigned short* xlo   = xbf + NELEM;
  unsigned short* vbf   = xlo + NELEM;
  unsigned short* wqbf  = vbf + NELEM;
  unsigned short* wkbf  = wqbf + NLL * DMM * DMM;
  unsigned short* wvbf  = wkbf + NLL * DMM * DMM;
  unsigned short* wobf  = wvbf + NLL * DMM * DMM;
  unsigned short* dcwT  = wobf + NLL * DMM * DMM;
  u64* cand = (u64*)(dcwT + (NLL - 1) * 3 * DMM * DMM);  // layout kept (unused now)
  int* topb = (int*)(cand + 256 * 40);                    // layout kept (unused now)
  int* flag = topb + BB * HH * UU;
  unsigned char* mapb = (unsigned char*)(flag + 1);  // 32*2048

  // ---- convert (+cheap inline dtype probe, +dcw repack, +vmp zero, +flag publish) ----
  CvtArgs ca;
  int totalBlk = 0;
  for (int i = 0; i < 23; ++i) {
    ca.src[i] = d_in[i];
    ca.dstF[i] = fptr[i];
    ca.dstB[i] = nullptr;
    ca.dstL[i] = nullptr;
    ca.n[i] = wsz[i];
    ca.blkStart[i] = totalBlk;
    totalBlk += (wsz[i] + 255) / 256;
  }
  ca.blkStart[23] = totalBlk;
  ca.dstB[0] = xbf;  ca.dstL[0] = xlo;
  ca.dstB[1] = wqbf;
  ca.dstB[3] = wkbf;
  ca.dstB[5] = wvbf;
  ca.dstB[7] = wobf;
  ca.dcwT = dcwT;
  ca.vmpZ = vmp;
  ca.flagOut = flag;
  mega_cvt<<<totalBlk + 1, 256, 0, stream>>>(ca);

  dim3 gqkv(ROWS / 128, DMM / 64, 3);
  dim3 g64(ROWS / 64, DMM / 64);

  for (int i = 0; i < NLL; ++i) {
    QKVArgs qa;
    qa.W[0] = wqbf + (size_t)i * DMM * DMM;
    qa.W[1] = wkbf + (size_t)i * DMM * DMM;
    qa.W[2] = wvbf + (size_t)i * DMM * DMM;
    qa.bias[0] = fptr[2] + i * DMM;
    qa.bias[1] = fptr[4] + i * DMM;
    qa.bias[2] = fptr[6] + i * DMM;
    qa.Cq = qb; qa.Ck = kb; qa.Cv = vbf;
    qa.vmp = vmp;
    gemm_qkv<<<gqkv, 256, 0, stream>>>(xbf, xlo, qa);

    uint32_t ki0, ki1, a0, a1, b0, b1;
    threefry2x32(0u, 42u, 0u, (uint32_t)i, &ki0, &ki1);
    threefry2x32(ki0, ki1, 0u, 2u, &a0, &a1);
    threefry2x32(ki0, ki1, 1u, 3u, &b0, &b1);
    (void)a0; (void)b0;

    m_kernel3<<<BB * 512, 256, 0, stream>>>(qb, kb, a1, b1, Mbuf);
    attn_part<<<dim3(KC, BB * HH), 256, 0, stream>>>(qb, kb, vbf, Mbuf, mapb,
                                                     pm, pl, po);

    bool last = (i == NLL - 1);
    oproj_tail<<<ROWS / OTR, 512, 0, stream>>>(
        vmp, mapb, pm, pl, po,
        wobf + (size_t)i * DMM * DMM, fptr[8] + i * DMM,
        xbuf,
        fptr[13] + i * DMM, fptr[14] + i * DMM,
        fptr[9] + (size_t)i * ITR * DMM, fptr[10] + i * ITR,
        fptr[11] + (size_t)i * DMM * ITR, fptr[12] + i * DMM,
        fptr[15] + i * DMM, fptr[16] + i * DMM,
        xbuf, xbf, xlo,
        fptr[21], fptr[22], last ? d_out : nullptr, flag, stp, stp2);

    if (!last) {
      gemm_conv<<<g64, 256, 0, stream>>>(xbf, dcwT + (size_t)i * 3 * DMM * DMM,
                                         fptr[18] + i * DMM, tmp, stp, stp2);
      bn_elu<<<NELEM / 256, 256, 0, stream>>>(tmp, stp, stp2, fptr[19] + i * DMM,
                                              fptr[20] + i * DMM, xbuf, xbf, xlo, vmp);
    }
  }
}

// Round 18
// 435.746 us; speedup vs baseline: 1.2711x; 1.0054x over previous
//
#include <hip/hip_runtime.h>
#include <stdint.h>

#define BB 4
#define LL 2048
#define DMM 256
#define HH 8
#define EE 32
#define NLL 3
#define ITR 16
#define UU 40
#define KC 16                 // split-K chunks
#define KCH 128               // keys per chunk
#define ROWS (BB*LL)          // 8192
#define NELEM (ROWS*DMM)      // 2097152
#define OTR 32                // oproj_tail rows per block (32 -> 256 blocks, 512 thr each)
#define APAD 8                // As leading-dim pad (shorts): 264*2=528B = 132 dw = 4 mod 32
#define CPAD 4                // Cs leading-dim pad (floats): 260 dw = 4 mod 32
#define PSP 8                 // ps/VsT pad (shorts): 136*2=272B = 68 dw = 4 mod 32 -> 2-way
#define KQP 8                 // KsB/QsB pad (shorts): 40*2=80B = 20 dw = 20 mod 32 -> 2-way

typedef __attribute__((ext_vector_type(8))) short short8;
typedef __attribute__((ext_vector_type(4))) float f32x4;
typedef unsigned long long u64;

#define GLDS16(g, l)                                                        \
  __builtin_amdgcn_global_load_lds(                                         \
      (const __attribute__((address_space(1))) uint32_t*)(g),               \
      (__attribute__((address_space(3))) uint32_t*)(l), 16, 0, 0)

// ---------------- bf16 bit helpers (RNE) ----------------
__device__ __forceinline__ float bfbits(unsigned short u) {
  return __uint_as_float(((uint32_t)u) << 16);
}
__device__ __forceinline__ unsigned short f2b(float f) {
  uint32_t u = __float_as_uint(f);
  uint32_t r = (u + 0x7FFFu + ((u >> 16) & 1u)) >> 16;
  return (unsigned short)r;
}

// ---------------- threefry2x32 (exact JAX semantics) ----------------
__host__ __device__ inline void threefry2x32(uint32_t k0, uint32_t k1,
                                             uint32_t x0, uint32_t x1,
                                             uint32_t* o0, uint32_t* o1) {
  uint32_t ks2 = k0 ^ k1 ^ 0x1BD11BDAu;
  x0 += k0; x1 += k1;
#define TFR(r) { x0 += x1; x1 = (x1 << (r)) | (x1 >> (32 - (r))); x1 ^= x0; }
  TFR(13) TFR(15) TFR(26) TFR(6)
  x0 += k1;  x1 += ks2 + 1u;
  TFR(17) TFR(29) TFR(16) TFR(24)
  x0 += ks2; x1 += k0 + 2u;
  TFR(13) TFR(15) TFR(26) TFR(6)
  x0 += k0;  x1 += k1 + 3u;
  TFR(17) TFR(29) TFR(16) TFR(24)
  x0 += k1;  x1 += ks2 + 4u;
  TFR(13) TFR(15) TFR(26) TFR(6)
  x0 += ks2; x1 += k0 + 5u;
#undef TFR
  *o0 = x0; *o1 = x1;
}

__device__ __forceinline__ float wave_sum(float v) {
#pragma unroll
  for (int off = 32; off > 0; off >>= 1) v += __shfl_xor(v, off);
  return v;
}

// ---------------- mega convert (+hi/lo splits, +dcw repack, +vmp zero, +cheap inline probe) -
struct CvtArgs {
  const void* src[23];
  float* dstF[23];
  unsigned short* dstB[23];
  unsigned short* dstL[23];
  int n[23];
  int blkStart[24];
  unsigned short* dcwT;
  float* vmpZ;     // zero BB*DMM floats
  int* flagOut;    // published dtype flag
};
__global__ __launch_bounds__(256) void mega_cvt(CvtArgs a) {
  // ---- inline dtype probe: 512 shorts (2/thread). bf16 data -> cnt~0; f32 data -> cnt~228.
  __shared__ int cnt;
  if (threadIdx.x == 0) cnt = 0;
  __syncthreads();
  {
    const unsigned short* u = (const unsigned short*)a.src[0];
    int bad = 0;
#pragma unroll
    for (int rep = 0; rep < 2; ++rep) {
      float v = bfbits(u[threadIdx.x + 256 * rep]);
      float av = fabsf(v);
      bool ok = (v == 0.0f) || (av > 1e-4f && av < 100.0f);
      if (!ok) bad++;
    }
    if (bad) atomicAdd(&cnt, bad);
  }
  __syncthreads();
  int isf32 = (cnt > 25) ? 1 : 0;

  int bid = blockIdx.x;
  if (bid == a.blkStart[23]) {
    for (int t = threadIdx.x; t < BB * DMM; t += 256) a.vmpZ[t] = 0.f;
    if (threadIdx.x == 0) *a.flagOut = isf32;
    return;
  }
  int i = 0;
  while (i < 22 && bid >= a.blkStart[i + 1]) ++i;
  int e = (bid - a.blkStart[i]) * 256 + (int)threadIdx.x;
  if (e >= a.n[i]) return;
  float v; unsigned short rw;
  if (isf32) { v = ((const float*)a.src[i])[e]; rw = f2b(v); }
  else       { rw = ((const unsigned short*)a.src[i])[e]; v = bfbits(rw); }
  a.dstF[i][e] = v;
  if (a.dstB[i]) a.dstB[i][e] = rw;
  if (a.dstL[i]) a.dstL[i][e] = f2b(v - bfbits(rw));
  if (i == 17) {  // dcw: [ly][n][k][t] -> [ly][t][n][k] bf16
    int ly = e / 196608;
    int r = e - ly * 196608;
    int n = r / 768;
    int rem = r - n * 768;
    int k = rem / 3, t = rem - k * 3;
    a.dcwT[ly * 196608 + t * 65536 + n * 256 + k] = rw;
  }
}

// ---------------- QKV MFMA GEMM: z=0:Q 1:K (hi/lo 2-pass, f32 out) 2:V (bf16 out + vmean) --
// (round-0 proven version: BK=32, [128][32]/[64][32] LDS)
struct QKVArgs {
  const unsigned short* W[3];
  const float* bias[3];
  float* Cq;
  float* Ck;
  unsigned short* Cv;
  float* vmp;
};
__global__ __launch_bounds__(256) void gemm_qkv(const unsigned short* __restrict__ Ahi,
                                                const unsigned short* __restrict__ Alo,
                                                QKVArgs qa) {
  __shared__ __attribute__((aligned(16))) unsigned short AsH[128][32];
  __shared__ __attribute__((aligned(16))) unsigned short AsL[128][32];
  __shared__ __attribute__((aligned(16))) unsigned short Bs[64][32];
  int z = blockIdx.z;
  const unsigned short* W = qa.W[z];
  const float* bias = qa.bias[z];
  bool twoPass = (z < 2);
  int bm = blockIdx.x * 128, bn = blockIdx.y * 64;
  int tid = threadIdx.x;
  int wv = tid >> 6, lane = tid & 63;
  int wm = wv >> 1, wn = wv & 1;
  int l15 = lane & 15, quad = lane >> 4;
  int lrow = lane >> 2, lseg = lane & 3;
  f32x4 acc[4][2];
#pragma unroll
  for (int i = 0; i < 4; ++i)
#pragma unroll
    for (int j = 0; j < 2; ++j) acc[i][j] = (f32x4){0.f, 0.f, 0.f, 0.f};
  for (int k0 = 0; k0 < 256; k0 += 32) {
    __syncthreads();
#pragma unroll
    for (int s = 0; s < 2; ++s) {
      int brow = (wv + s * 4) * 16;
      size_t goff = (size_t)(bm + brow + lrow) * 256 + k0 + lseg * 8;
      GLDS16(Ahi + goff, &AsH[brow][0]);
      if (twoPass) GLDS16(Alo + goff, &AsL[brow][0]);
    }
    {
      int brow = wv * 16;
      GLDS16(W + (size_t)(bn + brow + lrow) * 256 + k0 + lseg * 8, &Bs[brow][0]);
    }
    __syncthreads();
    short8 ah[4], bfr[2];
#pragma unroll
    for (int mt = 0; mt < 4; ++mt)
      ah[mt] = *(const short8*)(&AsH[wm * 64 + mt * 16 + l15][quad * 8]);
#pragma unroll
    for (int nt = 0; nt < 2; ++nt)
      bfr[nt] = *(const short8*)(&Bs[wn * 32 + nt * 16 + l15][quad * 8]);
#pragma unroll
    for (int mt = 0; mt < 4; ++mt)
#pragma unroll
      for (int nt = 0; nt < 2; ++nt)
        acc[mt][nt] = __builtin_amdgcn_mfma_f32_16x16x32_bf16(ah[mt], bfr[nt],
                                                              acc[mt][nt], 0, 0, 0);
    if (twoPass) {
      short8 al[4];
#pragma unroll
      for (int mt = 0; mt < 4; ++mt)
        al[mt] = *(const short8*)(&AsL[wm * 64 + mt * 16 + l15][quad * 8]);
#pragma unroll
      for (int mt = 0; mt < 4; ++mt)
#pragma unroll
        for (int nt = 0; nt < 2; ++nt)
          acc[mt][nt] = __builtin_amdgcn_mfma_f32_16x16x32_bf16(al[mt], bfr[nt],
                                                                acc[mt][nt], 0, 0, 0);
    }
  }
  float* C = (z == 0) ? qa.Cq : qa.Ck;
#pragma unroll
  for (int nt = 0; nt < 2; ++nt) {
    int n = bn + wn * 32 + nt * 16 + l15;
    float bv = bias[n];
    float csum = 0.f;
#pragma unroll
    for (int mt = 0; mt < 4; ++mt)
#pragma unroll
      for (int r = 0; r < 4; ++r) {
        int m = bm + wm * 64 + mt * 16 + quad * 4 + r;
        float val = acc[mt][nt][r] + bv;
        if (z < 2) {
          C[(size_t)m * 256 + n] = val;
        } else {
          qa.Cv[(size_t)m * 256 + n] = f2b(val);
          csum += val;
        }
      }
    if (z == 2) {
      csum += __shfl_xor(csum, 16);
      csum += __shfl_xor(csum, 32);
      if (quad == 0) {
        int b = bm >> 11;
        atomicAdd(&qa.vmp[b * DMM + n], csum);
      }
    }
  }
}

// ---------------- FUSED O-proj GEMM (32x256, 512 thr) + tail (R17: padded As/Cs) ----------
__global__ __launch_bounds__(512) void oproj_tail(const float* __restrict__ vmp,
                                                  const unsigned char* __restrict__ mapb,
                                                  const float* __restrict__ pm,
                                                  const float* __restrict__ pl,
                                                  const float* __restrict__ po,
                                                  const unsigned short* __restrict__ W,
                                                  const float* __restrict__ bias,
                                                  const float* __restrict__ X,
                                                  const float* __restrict__ g1,
                                                  const float* __restrict__ b1ln,
                                                  const float* __restrict__ w1,
                                                  const float* __restrict__ b1,
                                                  const float* __restrict__ w2,
                                                  const float* __restrict__ b2,
                                                  const float* __restrict__ g2,
                                                  const float* __restrict__ b2ln,
                                                  float* __restrict__ Out,
                                                  unsigned short* __restrict__ OutB,
                                                  unsigned short* __restrict__ OutL,
                                                  const float* __restrict__ fing,
                                                  const float* __restrict__ finb,
                                                  void* __restrict__ finOut,
                                                  const int* __restrict__ flag,
                                                  float* __restrict__ stpZ,
                                                  float* __restrict__ stp2Z) {
  __shared__ __attribute__((aligned(16))) unsigned short As[OTR][DMM + APAD];
  __shared__ __attribute__((aligned(16))) unsigned short Bs[256][32];
  __shared__ float Cs[OTR][DMM + CPAD];
  __shared__ float xs[8][DMM];
  int tid = threadIdx.x;
  if (blockIdx.x == 0 && tid < DMM) {
    stpZ[tid] = 0.f;
    stp2Z[tid] = 0.f;
  }
  int bm = blockIdx.x * OTR;
  int wv = tid >> 6, lane = tid & 63;
  int l15 = lane & 15, quad = lane >> 4;
  int b = bm >> 11, l0 = bm & 2047;
  const float invL = 1.0f / (float)LL;

  // ---- phase 1: ctx A-panel for all 8 heads, once, full-block parallel ----
#pragma unroll
  for (int uu = 0; uu < 2; ++uu) {
    int u = tid * 2 + uu;            // 0..1023
    int arow = u >> 5;               // 32 rows
    int sub = u & 31;
    int h = sub >> 2, adg = sub & 3; // 8 heads x 4 col-groups
    int bh = b * HH + h;
    int l = l0 + arow;
    int q = (int)mapb[bh * 2048 + l];
    unsigned short outv[8];
    if (q) {
      size_t base = ((size_t)bh * UU + (q - 1)) * KC;
      float Mx = -1e30f;
#pragma unroll
      for (int kc = 0; kc < KC; ++kc) Mx = fmaxf(Mx, pm[base + kc]);
      float Ls = 0.f;
      float sc[KC];
#pragma unroll
      for (int kc = 0; kc < KC; ++kc) {
        sc[kc] = expf(pm[base + kc] - Mx);
        Ls += pl[base + kc] * sc[kc];
      }
      float inv = 1.0f / Ls;
#pragma unroll
      for (int j = 0; j < 8; ++j) {
        int dl = adg * 8 + j;
        float o = 0.f;
#pragma unroll
        for (int kc = 0; kc < KC; ++kc) o += po[(base + kc) * 32 + dl] * sc[kc];
        outv[j] = f2b(o * inv);
      }
    } else {
      const float* vp = vmp + b * DMM + h * EE + adg * 8;
#pragma unroll
      for (int j = 0; j < 8; ++j) outv[j] = f2b(vp[j] * invL);
    }
    *(uint4*)(&As[arow][h * EE + adg * 8]) = *(const uint4*)outv;
  }
  __syncthreads();

  // ---- phase 2: GEMM loop (pure stage+MFMA) ----
  f32x4 acc[2][2];
#pragma unroll
  for (int i = 0; i < 2; ++i)
#pragma unroll
    for (int j = 0; j < 2; ++j) acc[i][j] = (f32x4){0.f, 0.f, 0.f, 0.f};
  for (int k0 = 0; k0 < 256; k0 += 32) {
    if (k0) __syncthreads();
    {  // stage all 256 B-rows once per block (8 waves x 2 rounds x 16 rows)
      int lrw = lane >> 2, lsg = lane & 3;
#pragma unroll
      for (int s = 0; s < 2; ++s) {
        int brow = s * 128 + wv * 16;
        GLDS16(W + (size_t)(brow + lrw) * 256 + k0 + lsg * 8, &Bs[brow][0]);
      }
    }
    __syncthreads();
    short8 af[2], bfr[2];
#pragma unroll
    for (int mt = 0; mt < 2; ++mt)
      af[mt] = *(const short8*)(&As[mt * 16 + l15][k0 + quad * 8]);
#pragma unroll
    for (int nt = 0; nt < 2; ++nt)
      bfr[nt] = *(const short8*)(&Bs[wv * 32 + nt * 16 + l15][quad * 8]);
#pragma unroll
    for (int mt = 0; mt < 2; ++mt)
#pragma unroll
      for (int nt = 0; nt < 2; ++nt)
        acc[mt][nt] = __builtin_amdgcn_mfma_f32_16x16x32_bf16(af[mt], bfr[nt],
                                                              acc[mt][nt], 0, 0, 0);
  }
  // epilogue -> LDS (replaces tmp)
#pragma unroll
  for (int nt = 0; nt < 2; ++nt) {
    int n = wv * 32 + nt * 16 + l15;
    float bv = bias[n];
#pragma unroll
    for (int mt = 0; mt < 2; ++mt)
#pragma unroll
      for (int r = 0; r < 4; ++r)
        Cs[mt * 16 + quad * 4 + r][n] = acc[mt][nt][r] + bv;
  }
  __syncthreads();
  // ---- enc_tail body, verbatim, 4 rows per wave ----
  for (int rr = 0; rr < 4; ++rr) {
    int lr = wv * 4 + rr;
    size_t row = (size_t)bm + lr;
    const float* xr = X + row * DMM;
    const float* tr = Cs[lr];
    float v[4];
#pragma unroll
    for (int i = 0; i < 4; ++i) v[i] = xr[lane + 64 * i] + tr[lane + 64 * i];
    float s = wave_sum(v[0] + v[1] + v[2] + v[3]);
    float m = s * (1.0f / (float)DMM);
    float sq = 0.f;
#pragma unroll
    for (int i = 0; i < 4; ++i) { float d = v[i] - m; sq += d * d; }
    sq = wave_sum(sq);
    float rstd = rsqrtf(sq * (1.0f / (float)DMM) + 1e-5f);
    float xv[4];
#pragma unroll
    for (int i = 0; i < 4; ++i) {
      int d = lane + 64 * i;
      xv[i] = (v[i] - m) * rstd * g1[d] + b1ln[d];
      xs[wv][d] = xv[i];
    }
    __syncthreads();
    int f = lane & 15, qtr = lane >> 4;
    const float* w1p = w1 + f * DMM + qtr * 64;
    const float* xq = &xs[wv][qtr * 64];
    float pacc = 0.f;
#pragma unroll 8
    for (int d = 0; d < 64; ++d) pacc += xq[d] * w1p[d];
    pacc += __shfl_xor(pacc, 16);
    pacc += __shfl_xor(pacc, 32);
    float y1 = fmaxf(pacc + b1[f], 0.0f);
    float y1v[16];
#pragma unroll
    for (int ff = 0; ff < 16; ++ff) y1v[ff] = __shfl(y1, ff);
#pragma unroll
    for (int i = 0; i < 4; ++i) {
      int d = lane + 64 * i;
      const float* w2p = w2 + d * ITR;
      float a = b2[d];
#pragma unroll
      for (int ff = 0; ff < 16; ++ff) a += y1v[ff] * w2p[ff];
      v[i] = xv[i] + a;
    }
    s = wave_sum(v[0] + v[1] + v[2] + v[3]);
    m = s * (1.0f / (float)DMM);
    sq = 0.f;
#pragma unroll
    for (int i = 0; i < 4; ++i) { float d = v[i] - m; sq += d * d; }
    sq = wave_sum(sq);
    rstd = rsqrtf(sq * (1.0f / (float)DMM) + 1e-5f);
    float vv[4];
#pragma unroll
    for (int i = 0; i < 4; ++i) {
      int d = lane + 64 * i;
      float val = (v[i] - m) * rstd * g2[d] + b2ln[d];
      vv[i] = val;
      Out[row * DMM + d] = val;
      unsigned short hi = f2b(val);
      OutB[row * DMM + d] = hi;
      OutL[row * DMM + d] = f2b(val - bfbits(hi));
    }
    if (finOut) {
      s = wave_sum(vv[0] + vv[1] + vv[2] + vv[3]);
      m = s * (1.0f / (float)DMM);
      sq = 0.f;
#pragma unroll
      for (int i = 0; i < 4; ++i) { float d = vv[i] - m; sq += d * d; }
      sq = wave_sum(sq);
      rstd = rsqrtf(sq * (1.0f / (float)DMM) + 1e-5f);
      int isf32 = *flag;
#pragma unroll
      for (int i = 0; i < 4; ++i) {
        int d = lane + 64 * i;
        float val = (vv[i] - m) * rstd * fing[d] + finb[d];
        if (isf32) ((float*)finOut)[row * DMM + d] = val;
        else       ((unsigned short*)finOut)[row * DMM + d] = f2b(val);
      }
    }
  }
}

// ---------------- conv GEMM: A window staged once per k0, 3 taps from LDS ----------------
__global__ __launch_bounds__(256) void gemm_conv(const unsigned short* __restrict__ A,
                                                 const unsigned short* __restrict__ W,
                                                 const float* __restrict__ bias,
                                                 float* __restrict__ C,
                                                 float* __restrict__ stp,
                                                 float* __restrict__ stp2) {
  __shared__ __attribute__((aligned(16))) unsigned short As[80][32];
  __shared__ __attribute__((aligned(16))) unsigned short Bs[192][32];
  int bm = blockIdx.x * 64, bn = blockIdx.y * 64;
  int tid = threadIdx.x;
  int wv = tid >> 6, lane = tid & 63;
  int wm = wv >> 1, wn = wv & 1;
  int l15 = lane & 15, quad = lane >> 4;
  int lrow = lane >> 2, lseg = lane & 3;
  int bbase = bm & ~2047, l0 = bm & 2047;
  f32x4 acc[2][2];
#pragma unroll
  for (int i = 0; i < 2; ++i)
#pragma unroll
    for (int j = 0; j < 2; ++j) acc[i][j] = (f32x4){0.f, 0.f, 0.f, 0.f};
  for (int k0 = 0; k0 < 256; k0 += 32) {
    __syncthreads();
    for (int c = wv; c < 5; c += 4) {
      int i0 = c * 16;
      int l = (l0 - 1 + i0 + lrow + 2048) & 2047;
      GLDS16(A + (size_t)(bbase | l) * 256 + k0 + lseg * 8, &As[i0][0]);
    }
    for (int c = wv; c < 12; c += 4) {
      int i0 = c * 16;
      int tap = c >> 2, brow = (c & 3) * 16;
      GLDS16(W + (size_t)tap * 65536 + (size_t)(bn + brow + lrow) * 256 + k0 + lseg * 8,
             &Bs[i0][0]);
    }
    __syncthreads();
#pragma unroll
    for (int tap = 0; tap < 3; ++tap) {
      short8 af[2], bfr[2];
#pragma unroll
      for (int mt = 0; mt < 2; ++mt)
        af[mt] = *(const short8*)(&As[wm * 32 + mt * 16 + l15 + tap][quad * 8]);
#pragma unroll
      for (int nt = 0; nt < 2; ++nt)
        bfr[nt] = *(const short8*)(&Bs[tap * 64 + wn * 32 + nt * 16 + l15][quad * 8]);
#pragma unroll
      for (int mt = 0; mt < 2; ++mt)
#pragma unroll
        for (int nt = 0; nt < 2; ++nt)
          acc[mt][nt] = __builtin_amdgcn_mfma_f32_16x16x32_bf16(af[mt], bfr[nt],
                                                                acc[mt][nt], 0, 0, 0);
    }
  }
#pragma unroll
  for (int nt = 0; nt < 2; ++nt) {
    int n = bn + wn * 32 + nt * 16 + l15;
    float bv = bias[n];
    float s = 0.f, s2 = 0.f;
#pragma unroll
    for (int mt = 0; mt < 2; ++mt)
#pragma unroll
      for (int r = 0; r < 4; ++r) {
        int m = bm + wm * 32 + mt * 16 + quad * 4 + r;
        float val = acc[mt][nt][r] + bv;
        C[(size_t)m * 256 + n] = val;
        s += val;
        s2 += val * val;
      }
    s  += __shfl_xor(s, 16);   s  += __shfl_xor(s, 32);
    s2 += __shfl_xor(s2, 16);  s2 += __shfl_xor(s2, 32);
    if (quad == 0) {
      atomicAdd(&stp[n], s);
      atomicAdd(&stp2[n], s2);
    }
  }
}

// ---------------- M scores: wave per (b,l), inline threefry, XCD-affinity swizzle ----------
__global__ __launch_bounds__(256) void m_kernel3(const float* __restrict__ Q,
                                                 const float* __restrict__ K,
                                                 uint32_t k20, uint32_t k21,
                                                 float* __restrict__ M) {
  int bid = blockIdx.x;
  int blk = (bid & 7) * 256 + (bid >> 3);   // XCD-affinity remap (pure perf, no semantics)
  int b = blk >> 9, lc = blk & 511;
  int wave = threadIdx.x >> 6, lane = threadIdx.x & 63;
  int l = lc * 4 + wave;
  int myidx = 0;
  if (lane < UU) {
    int j = l * UU + lane;
    uint32_t o0, o1;
    const int half = (LL * UU) / 2;  // 40960
    if (j < half) {
      threefry2x32(k20, k21, (uint32_t)j, (uint32_t)(j + half), &o0, &o1);
      myidx = (int)(o0 & (LL - 1));
    } else {
      threefry2x32(k20, k21, (uint32_t)(j - half), (uint32_t)j, &o0, &o1);
      myidx = (int)(o1 & (LL - 1));
    }
  }
  float4 q4 = *(const float4*)(Q + ((size_t)(b * LL + l)) * DMM + lane * 4);
  const float* Kb = K + (size_t)b * LL * DMM;
  float mx = -1e30f, sm = 0.f;
#pragma unroll 8
  for (int u = 0; u < UU; ++u) {
    int kidx = __shfl(myidx, u);
    float4 k4 = *(const float4*)(Kb + (size_t)kidx * DMM + lane * 4);
    float s = q4.x * k4.x + q4.y * k4.y + q4.z * k4.z + q4.w * k4.w;
    s += __shfl_xor(s, 1);
    s += __shfl_xor(s, 2);
    s += __shfl_xor(s, 4);
    mx = fmaxf(mx, s);
    sm += s;
  }
  if ((lane & 7) == 0) {
    int h = lane >> 3;
    M[((size_t)(b * HH + h)) * LL + l] = mx - sm * (1.0f / (float)LL);
  }
}

// ---------------- fused topk + split-K flash attention (R16 + G4 pads) --------------------
// Bank-conflict audit (same arithmetic as R17's oproj fix): ps/VsT row stride 256B = 64 dw
// = 0 mod 32 made the PV A/B fragment reads 16-way conflicts; KsB/QsB stride 64B = 16 dw
// made score fragment reads 8-way. Pads: +8 shorts each -> 272B (68 dw = 4 mod 32) and
// 80B (20 dw) -> 2-way (free). 16B alignment preserved. Pure layout; bitwise-identical.
__global__ __launch_bounds__(256) void attn_part(const float* __restrict__ Q,
                                                 const float* __restrict__ K,
                                                 const unsigned short* __restrict__ Vbf,
                                                 const float* __restrict__ M,
                                                 unsigned char* __restrict__ mapb,
                                                 float* __restrict__ pm,
                                                 float* __restrict__ pl,
                                                 float* __restrict__ po) {
  __shared__ __attribute__((aligned(16))) unsigned short QsB[48][32 + KQP];
  __shared__ __attribute__((aligned(16))) unsigned short KsB[KCH][32 + KQP];
  __shared__ __attribute__((aligned(16))) unsigned short ps[48][KCH + PSP];
  __shared__ __attribute__((aligned(16))) unsigned short VsT[EE][KCH + PSP];
  __shared__ int qrows[40];
  __shared__ unsigned int hist[256];
  __shared__ unsigned int sA[256];
  __shared__ unsigned int wtot[4];
  __shared__ unsigned int tbv;
  int kc = blockIdx.x, bh = blockIdx.y;
  int h = bh & 7, b = bh >> 3;
  int tid = threadIdx.x;
  int wv = tid >> 6, lane = tid & 63;
  int l15 = lane & 15, quad = lane >> 4;

  // ---- independent V/K loads issued first (overlap with radix latency) ----
  {
    int row = tid >> 1, half = tid & 1;
    const unsigned short* vsrc =
        Vbf + (size_t)(b * LL + kc * KCH + row) * DMM + h * EE + half * 16;
    unsigned short tv[16];
    *(uint4*)(&tv[0]) = *(const uint4*)vsrc;
    *(uint4*)(&tv[8]) = *(const uint4*)(vsrc + 8);
#pragma unroll
    for (int j = 0; j < 16; ++j) VsT[half * 16 + j][row] = tv[j];
    // K: f32 -> bf16 into B-operand layout [key][dim]
    const float* ksrc = K + ((size_t)(b * LL + kc * KCH + row)) * DMM + h * EE + half * 16;
    unsigned short tk[16];
#pragma unroll
    for (int j = 0; j < 16; ++j) tk[j] = f2b(ksrc[j]);
    *(uint4*)(&KsB[row][half * 16]) = *(const uint4*)(&tk[0]);
    *(uint4*)(&KsB[row][half * 16 + 8]) = *(const uint4*)(&tk[8]);
  }

  // ---- exact top-40 radix select on M[bh]: packed 43-bit keys, 6 rounds (R14-proven) ----
  u64 kreg[8];
#pragma unroll
  for (int r = 0; r < 8; ++r) {
    int l = tid + 256 * r;
    float v = M[(size_t)bh * LL + l];
    uint32_t bits = __float_as_uint(v);
    uint32_t kv = (bits & 0x80000000u) ? ~bits : (bits | 0x80000000u);
    kreg[r] = ((u64)kv << 11) | (uint32_t)(2047 - l);
  }
  u64 prefix = 0;
  int rank = UU;
  for (int round = 0; round < 6; ++round) {
    int shift = 40 - 8 * round;
    u64 maskTop = (round == 0) ? 0ull : (~0ull << (48 - 8 * round));
    hist[tid] = 0;
    __syncthreads();
#pragma unroll
    for (int r = 0; r < 8; ++r) {
      u64 k = kreg[r];
      if ((k & maskTop) == prefix)
        atomicAdd(&hist[(unsigned int)((k >> shift) & 0xFFu)], 1u);
    }
    __syncthreads();
    unsigned int s = hist[tid];
#pragma unroll
    for (int off = 1; off < 64; off <<= 1) {
      unsigned int t = __shfl_down(s, off);
      if (lane + off < 64) s += t;
    }
    if (lane == 0) wtot[wv] = s;
    __syncthreads();
    unsigned int add = 0;
#pragma unroll
    for (int w = 0; w < 4; ++w)
      if (w > wv) add += wtot[w];
    sA[tid] = s + add;
    __syncthreads();
    unsigned int Sb = sA[tid];
    unsigned int Snext = (tid < 255) ? sA[tid + 1] : 0u;
    if (Sb >= (unsigned int)rank && Snext < (unsigned int)rank) tbv = (unsigned int)tid;
    __syncthreads();
    unsigned int tb = tbv;
    unsigned int above = (tb < 255u) ? sA[tb + 1] : 0u;
    rank -= (int)above;
    prefix |= ((u64)tb) << shift;
  }
  u64 T = prefix;   // exact 40th-largest packed key
  // ---- deterministic rank: in-wave prefix + cross-wave totals (exclusive over tid) ----
  int myCnt = 0;
#pragma unroll
  for (int r = 0; r < 8; ++r) myCnt += (kreg[r] >= T) ? 1 : 0;
  {
    unsigned int p = (unsigned int)myCnt;
#pragma unroll
    for (int off = 1; off < 64; off <<= 1) {
      unsigned int t = __shfl_up(p, off);
      if (lane >= off) p += t;
    }
    if (lane == 63) wtot[wv] = p;
    __syncthreads();
    unsigned int addp = 0;
#pragma unroll
    for (int w = 0; w < 4; ++w)
      if (w < wv) addp += wtot[w];
    int pos = (int)(p + addp) - myCnt;   // exclusive prefix
    bool wmap = (kc == 0);
#pragma unroll
    for (int r = 0; r < 8; ++r) {
      u64 k = kreg[r];
      int l = 2047 - (int)(uint32_t)(k & 0x7FFu);
      unsigned char mv = 0;
      if (k >= T) {
        qrows[pos] = l;
        mv = (unsigned char)(pos + 1);
        pos++;
      }
      if (wmap) mapb[bh * 2048 + l] = mv;
    }
  }
  __syncthreads();

  // ---- Q staging (bf16, A-operand layout) for the 40 selected rows; rows 40-47 zero ----
  for (int t = tid; t < 40 * 32; t += 256) {
    int q = t >> 5, d = t & 31;
    QsB[q][d] = f2b(Q[((size_t)(b * LL + qrows[q])) * DMM + h * EE + d]);
  }
  {
    int q = 40 + (tid >> 5), d = tid & 31;
    if (q < 48) QsB[q][d] = 0;   // tid 0..255 covers exactly rows 40..47
  }
  __syncthreads();
  // ---- scores via MFMA: waves 0..2, one 16-q tile x 128 keys each ----
  if (wv < 3) {
    const float scale = 0.17677669529663687f;
    short8 aq = *(const short8*)(&QsB[wv * 16 + l15][quad * 8]);
    f32x4 sacc[8];
#pragma unroll
    for (int nt = 0; nt < 8; ++nt) {
      short8 bk = *(const short8*)(&KsB[nt * 16 + l15][quad * 8]);
      sacc[nt] = __builtin_amdgcn_mfma_f32_16x16x32_bf16(
          aq, bk, (f32x4){0.f, 0.f, 0.f, 0.f}, 0, 0, 0);
    }
#pragma unroll
    for (int nt = 0; nt < 8; ++nt)
#pragma unroll
      for (int r = 0; r < 4; ++r)
        ps[wv * 16 + quad * 4 + r][nt * 16 + l15] = f2b(sacc[nt][r] * scale);
  }
  __syncthreads();
  // ---- softmax (max + exp + sum per row; writes exp back to ps; pm/pl) ----
  for (int qq = 0; qq < 10; ++qq) {
    int q = wv * 10 + qq;
    float mx = fmaxf(bfbits(ps[q][lane]), bfbits(ps[q][lane + 64]));
#pragma unroll
    for (int off = 32; off > 0; off >>= 1) mx = fmaxf(mx, __shfl_xor(mx, off));
    float e0 = expf(bfbits(ps[q][lane]) - mx);
    float e1 = expf(bfbits(ps[q][lane + 64]) - mx);
    ps[q][lane] = f2b(e0);
    ps[q][lane + 64] = f2b(e1);
    float sum = wave_sum(e0 + e1);
    size_t base = ((size_t)bh * UU + q) * KC + kc;
    if (lane == 0) { pm[base] = mx; pl[base] = sum; }
  }
  __syncthreads();
  // ---- PV via MFMA: waves 0..2 each compute one 16-row q-tile x 32 cols (R15-proven) ----
  if (wv < 3) {
    f32x4 pacc[2];
#pragma unroll
    for (int nt = 0; nt < 2; ++nt) pacc[nt] = (f32x4){0.f, 0.f, 0.f, 0.f};
#pragma unroll
    for (int kch = 0; kch < 4; ++kch) {
      short8 af = *(const short8*)(&ps[wv * 16 + l15][kch * 32 + quad * 8]);
#pragma unroll
      for (int nt = 0; nt < 2; ++nt) {
        short8 bfr = *(const short8*)(&VsT[nt * 16 + l15][kch * 32 + quad * 8]);
        pacc[nt] = __builtin_amdgcn_mfma_f32_16x16x32_bf16(af, bfr, pacc[nt], 0, 0, 0);
      }
    }
#pragma unroll
    for (int nt = 0; nt < 2; ++nt) {
      int d = nt * 16 + l15;
#pragma unroll
      for (int r = 0; r < 4; ++r) {
        int q = wv * 16 + quad * 4 + r;
        if (q < UU) {
          size_t base = ((size_t)bh * UU + q) * KC + kc;
          po[base * 32 + d] = pacc[nt][r];
        }
      }
    }
  }
}

// ---------------- bn+elu from atomic stats (+vmp zero for next layer) ----------------
__global__ __launch_bounds__(256) void bn_elu(const float* __restrict__ Y,
                                              const float* __restrict__ stp,
                                              const float* __restrict__ stp2,
                                              const float* __restrict__ g,
                                              const float* __restrict__ bb,
                                              float* __restrict__ X,
                                              unsigned short* __restrict__ XB,
                                              unsigned short* __restrict__ XL,
                                              float* __restrict__ vmpZ) {
  int gid = blockIdx.x * 256 + threadIdx.x;
  if (gid < BB * DMM) vmpZ[gid] = 0.f;
  int d = gid & 255;
  float mean = stp[d] * (1.0f / (float)ROWS);
  float var = stp2[d] * (1.0f / (float)ROWS) - mean * mean;
  float rstd = rsqrtf(var + 1e-5f);
  float v = (Y[gid] - mean) * rstd * g[d] + bb[d];
  float r = v > 0.f ? v : expm1f(v);
  X[gid] = r;
  unsigned short hi = f2b(r);
  XB[gid] = hi;
  XL[gid] = f2b(r - bfbits(hi));
}

extern "C" void kernel_launch(void* const* d_in, const int* in_sizes, int n_in,
                              void* d_out, int out_size, void* d_ws, size_t ws_size,
                              hipStream_t stream) {
  (void)in_sizes; (void)n_in; (void)out_size; (void)ws_size;

  // ---- workspace layout ----
  float* xbuf = (float*)d_ws;
  float* kb   = xbuf + NELEM;
  float* qb   = kb + NELEM;   // aliases tmp (Q dead after attn_part)
  float* tmp  = qb;
  float* Mbuf = qb + NELEM;
  float* vmp  = Mbuf + BB * HH * LL;
  float* stp  = vmp + BB * DMM;
  float* stp2 = stp + DMM;
  float* wp   = stp2 + DMM;
  const int wsz[23] = {
      NELEM,
      NLL * DMM * DMM, NLL * DMM,
      NLL * DMM * DMM, NLL * DMM,
      NLL * DMM * DMM, NLL * DMM,
      NLL * DMM * DMM, NLL * DMM,
      NLL * ITR * DMM, NLL * ITR,
      NLL * DMM * ITR, NLL * DMM,
      NLL * DMM, NLL * DMM,
      NLL * DMM, NLL * DMM,
      (NLL - 1) * DMM * DMM * 3, (NLL - 1) * DMM,
      (NLL - 1) * DMM, (NLL - 1) * DMM,
      DMM, DMM
  };
  float* fptr[23];
  fptr[0] = xbuf;
  for (int i = 1; i < 23; ++i) { fptr[i] = wp; wp += wsz[i]; }
  float* pm = wp;
  float* pl = pm + 32 * UU * KC;
  float* po = pl + 32 * UU * KC;
  unsigned short* xbf   = (unsigned short*)(po + 32 * UU * KC * 32);
  unsigned short* xlo   = xbf + NELEM;
  unsigned short* vbf   = xlo + NELEM;
  unsigned short* wqbf  = vbf + NELEM;
  unsigned short* wkbf  = wqbf + NLL * DMM * DMM;
  unsigned short* wvbf  = wkbf + NLL * DMM * DMM;
  unsigned short* wobf  = wvbf + NLL * DMM * DMM;
  unsigned short* dcwT  = wobf + NLL * DMM * DMM;
  u64* cand = (u64*)(dcwT + (NLL - 1) * 3 * DMM * DMM);  // layout kept (unused now)
  int* topb = (int*)(cand + 256 * 40);                    // layout kept (unused now)
  int* flag = topb + BB * HH * UU;
  unsigned char* mapb = (unsigned char*)(flag + 1);  // 32*2048

  // ---- convert (+cheap inline dtype probe, +dcw repack, +vmp zero, +flag publish) ----
  CvtArgs ca;
  int totalBlk = 0;
  for (int i = 0; i < 23; ++i) {
    ca.src[i] = d_in[i];
    ca.dstF[i] = fptr[i];
    ca.dstB[i] = nullptr;
    ca.dstL[i] = nullptr;
    ca.n[i] = wsz[i];
    ca.blkStart[i] = totalBlk;
    totalBlk += (wsz[i] + 255) / 256;
  }
  ca.blkStart[23] = totalBlk;
  ca.dstB[0] = xbf;  ca.dstL[0] = xlo;
  ca.dstB[1] = wqbf;
  ca.dstB[3] = wkbf;
  ca.dstB[5] = wvbf;
  ca.dstB[7] = wobf;
  ca.dcwT = dcwT;
  ca.vmpZ = vmp;
  ca.flagOut = flag;
  mega_cvt<<<totalBlk + 1, 256, 0, stream>>>(ca);

  dim3 gqkv(ROWS / 128, DMM / 64, 3);
  dim3 g64(ROWS / 64, DMM / 64);

  for (int i = 0; i < NLL; ++i) {
    QKVArgs qa;
    qa.W[0] = wqbf + (size_t)i * DMM * DMM;
    qa.W[1] = wkbf + (size_t)i * DMM * DMM;
    qa.W[2] = wvbf + (size_t)i * DMM * DMM;
    qa.bias[0] = fptr[2] + i * DMM;
    qa.bias[1] = fptr[4] + i * DMM;
    qa.bias[2] = fptr[6] + i * DMM;
    qa.Cq = qb; qa.Ck = kb; qa.Cv = vbf;
    qa.vmp = vmp;
    gemm_qkv<<<gqkv, 256, 0, stream>>>(xbf, xlo, qa);

    uint32_t ki0, ki1, a0, a1, b0, b1;
    threefry2x32(0u, 42u, 0u, (uint32_t)i, &ki0, &ki1);
    threefry2x32(ki0, ki1, 0u, 2u, &a0, &a1);
    threefry2x32(ki0, ki1, 1u, 3u, &b0, &b1);
    (void)a0; (void)b0;

    m_kernel3<<<BB * 512, 256, 0, stream>>>(qb, kb, a1, b1, Mbuf);
    attn_part<<<dim3(KC, BB * HH), 256, 0, stream>>>(qb, kb, vbf, Mbuf, mapb,
                                                     pm, pl, po);

    bool last = (i == NLL - 1);
    oproj_tail<<<ROWS / OTR, 512, 0, stream>>>(
        vmp, mapb, pm, pl, po,
        wobf + (size_t)i * DMM * DMM, fptr[8] + i * DMM,
        xbuf,
        fptr[13] + i * DMM, fptr[14] + i * DMM,
        fptr[9] + (size_t)i * ITR * DMM, fptr[10] + i * ITR,
        fptr[11] + (size_t)i * DMM * ITR, fptr[12] + i * DMM,
        fptr[15] + i * DMM, fptr[16] + i * DMM,
        xbuf, xbf, xlo,
        fptr[21], fptr[22], last ? d_out : nullptr, flag, stp, stp2);

    if (!last) {
      gemm_conv<<<g64, 256, 0, stream>>>(xbf, dcwT + (size_t)i * 3 * DMM * DMM,
                                         fptr[18] + i * DMM, tmp, stp, stp2);
      bn_elu<<<NELEM / 256, 256, 0, stream>>>(tmp, stp, stp2, fptr[19] + i * DMM,
                                              fptr[20] + i * DMM, xbuf, xbf, xlo, vmp);
    }
  }
}

// Round 19
// 432.729 us; speedup vs baseline: 1.2799x; 1.0070x over previous
//
#include <hip/hip_runtime.h>
#include <stdint.h>

#define BB 4
#define LL 2048
#define DMM 256
#define HH 8
#define EE 32
#define NLL 3
#define ITR 16
#define UU 40
#define KC 16                 // split-K chunks
#define KCH 128               // keys per chunk
#define ROWS (BB*LL)          // 8192
#define NELEM (ROWS*DMM)      // 2097152
#define OTR 32                // oproj_tail rows per block (32 -> 256 blocks, 512 thr each)
#define APAD 8                // As leading-dim pad (shorts): 264*2=528B = 132 dw = 4 mod 32
#define CPAD 4                // Cs leading-dim pad (floats): 260 dw = 4 mod 32
#define PSP 8                 // ps/VsT pad (shorts): 136*2=272B = 68 dw = 4 mod 32 -> 2-way
#define KQP 8                 // KsB/QsB pad (shorts): 40*2=80B = 20 dw = 20 mod 32 -> 2-way

typedef __attribute__((ext_vector_type(8))) short short8;
typedef __attribute__((ext_vector_type(4))) float f32x4;
typedef unsigned long long u64;

#define GLDS16(g, l)                                                        \
  __builtin_amdgcn_global_load_lds(                                         \
      (const __attribute__((address_space(1))) uint32_t*)(g),               \
      (__attribute__((address_space(3))) uint32_t*)(l), 16, 0, 0)

// ---------------- bf16 bit helpers (RNE) ----------------
__device__ __forceinline__ float bfbits(unsigned short u) {
  return __uint_as_float(((uint32_t)u) << 16);
}
__device__ __forceinline__ unsigned short f2b(float f) {
  uint32_t u = __float_as_uint(f);
  uint32_t r = (u + 0x7FFFu + ((u >> 16) & 1u)) >> 16;
  return (unsigned short)r;
}

// ---------------- threefry2x32 (exact JAX semantics) ----------------
__host__ __device__ inline void threefry2x32(uint32_t k0, uint32_t k1,
                                             uint32_t x0, uint32_t x1,
                                             uint32_t* o0, uint32_t* o1) {
  uint32_t ks2 = k0 ^ k1 ^ 0x1BD11BDAu;
  x0 += k0; x1 += k1;
#define TFR(r) { x0 += x1; x1 = (x1 << (r)) | (x1 >> (32 - (r))); x1 ^= x0; }
  TFR(13) TFR(15) TFR(26) TFR(6)
  x0 += k1;  x1 += ks2 + 1u;
  TFR(17) TFR(29) TFR(16) TFR(24)
  x0 += ks2; x1 += k0 + 2u;
  TFR(13) TFR(15) TFR(26) TFR(6)
  x0 += k0;  x1 += k1 + 3u;
  TFR(17) TFR(29) TFR(16) TFR(24)
  x0 += k1;  x1 += ks2 + 4u;
  TFR(13) TFR(15) TFR(26) TFR(6)
  x0 += ks2; x1 += k0 + 5u;
#undef TFR
  *o0 = x0; *o1 = x1;
}

__device__ __forceinline__ float wave_sum(float v) {
#pragma unroll
  for (int off = 32; off > 0; off >>= 1) v += __shfl_xor(v, off);
  return v;
}

// ---------------- mega convert (+hi/lo splits, +dcw repack, +vmp zero, +cheap inline probe) -
struct CvtArgs {
  const void* src[23];
  float* dstF[23];
  unsigned short* dstB[23];
  unsigned short* dstL[23];
  int n[23];
  int blkStart[24];
  unsigned short* dcwT;
  float* vmpZ;     // zero BB*DMM floats
  int* flagOut;    // published dtype flag
};
__global__ __launch_bounds__(256) void mega_cvt(CvtArgs a) {
  // ---- inline dtype probe: 512 shorts (2/thread). bf16 data -> cnt~0; f32 data -> cnt~228.
  __shared__ int cnt;
  if (threadIdx.x == 0) cnt = 0;
  __syncthreads();
  {
    const unsigned short* u = (const unsigned short*)a.src[0];
    int bad = 0;
#pragma unroll
    for (int rep = 0; rep < 2; ++rep) {
      float v = bfbits(u[threadIdx.x + 256 * rep]);
      float av = fabsf(v);
      bool ok = (v == 0.0f) || (av > 1e-4f && av < 100.0f);
      if (!ok) bad++;
    }
    if (bad) atomicAdd(&cnt, bad);
  }
  __syncthreads();
  int isf32 = (cnt > 25) ? 1 : 0;

  int bid = blockIdx.x;
  if (bid == a.blkStart[23]) {
    for (int t = threadIdx.x; t < BB * DMM; t += 256) a.vmpZ[t] = 0.f;
    if (threadIdx.x == 0) *a.flagOut = isf32;
    return;
  }
  int i = 0;
  while (i < 22 && bid >= a.blkStart[i + 1]) ++i;
  int e = (bid - a.blkStart[i]) * 256 + (int)threadIdx.x;
  if (e >= a.n[i]) return;
  float v; unsigned short rw;
  if (isf32) { v = ((const float*)a.src[i])[e]; rw = f2b(v); }
  else       { rw = ((const unsigned short*)a.src[i])[e]; v = bfbits(rw); }
  a.dstF[i][e] = v;
  if (a.dstB[i]) a.dstB[i][e] = rw;
  if (a.dstL[i]) a.dstL[i][e] = f2b(v - bfbits(rw));
  if (i == 17) {  // dcw: [ly][n][k][t] -> [ly][t][n][k] bf16
    int ly = e / 196608;
    int r = e - ly * 196608;
    int n = r / 768;
    int rem = r - n * 768;
    int k = rem / 3, t = rem - k * 3;
    a.dcwT[ly * 196608 + t * 65536 + n * 256 + k] = rw;
  }
}

// ---------------- QKV MFMA GEMM: z=0:Q 1:K (hi/lo 2-pass, f32 out) 2:V (bf16 out + vmean) --
// (round-0 proven version: BK=32, [128][32]/[64][32] LDS)
struct QKVArgs {
  const unsigned short* W[3];
  const float* bias[3];
  float* Cq;
  float* Ck;
  unsigned short* Cv;
  float* vmp;
};
__global__ __launch_bounds__(256) void gemm_qkv(const unsigned short* __restrict__ Ahi,
                                                const unsigned short* __restrict__ Alo,
                                                QKVArgs qa) {
  __shared__ __attribute__((aligned(16))) unsigned short AsH[128][32];
  __shared__ __attribute__((aligned(16))) unsigned short AsL[128][32];
  __shared__ __attribute__((aligned(16))) unsigned short Bs[64][32];
  int z = blockIdx.z;
  const unsigned short* W = qa.W[z];
  const float* bias = qa.bias[z];
  bool twoPass = (z < 2);
  int bm = blockIdx.x * 128, bn = blockIdx.y * 64;
  int tid = threadIdx.x;
  int wv = tid >> 6, lane = tid & 63;
  int wm = wv >> 1, wn = wv & 1;
  int l15 = lane & 15, quad = lane >> 4;
  int lrow = lane >> 2, lseg = lane & 3;
  f32x4 acc[4][2];
#pragma unroll
  for (int i = 0; i < 4; ++i)
#pragma unroll
    for (int j = 0; j < 2; ++j) acc[i][j] = (f32x4){0.f, 0.f, 0.f, 0.f};
  for (int k0 = 0; k0 < 256; k0 += 32) {
    __syncthreads();
#pragma unroll
    for (int s = 0; s < 2; ++s) {
      int brow = (wv + s * 4) * 16;
      size_t goff = (size_t)(bm + brow + lrow) * 256 + k0 + lseg * 8;
      GLDS16(Ahi + goff, &AsH[brow][0]);
      if (twoPass) GLDS16(Alo + goff, &AsL[brow][0]);
    }
    {
      int brow = wv * 16;
      GLDS16(W + (size_t)(bn + brow + lrow) * 256 + k0 + lseg * 8, &Bs[brow][0]);
    }
    __syncthreads();
    short8 ah[4], bfr[2];
#pragma unroll
    for (int mt = 0; mt < 4; ++mt)
      ah[mt] = *(const short8*)(&AsH[wm * 64 + mt * 16 + l15][quad * 8]);
#pragma unroll
    for (int nt = 0; nt < 2; ++nt)
      bfr[nt] = *(const short8*)(&Bs[wn * 32 + nt * 16 + l15][quad * 8]);
#pragma unroll
    for (int mt = 0; mt < 4; ++mt)
#pragma unroll
      for (int nt = 0; nt < 2; ++nt)
        acc[mt][nt] = __builtin_amdgcn_mfma_f32_16x16x32_bf16(ah[mt], bfr[nt],
                                                              acc[mt][nt], 0, 0, 0);
    if (twoPass) {
      short8 al[4];
#pragma unroll
      for (int mt = 0; mt < 4; ++mt)
        al[mt] = *(const short8*)(&AsL[wm * 64 + mt * 16 + l15][quad * 8]);
#pragma unroll
      for (int mt = 0; mt < 4; ++mt)
#pragma unroll
        for (int nt = 0; nt < 2; ++nt)
          acc[mt][nt] = __builtin_amdgcn_mfma_f32_16x16x32_bf16(al[mt], bfr[nt],
                                                                acc[mt][nt], 0, 0, 0);
    }
  }
  float* C = (z == 0) ? qa.Cq : qa.Ck;
#pragma unroll
  for (int nt = 0; nt < 2; ++nt) {
    int n = bn + wn * 32 + nt * 16 + l15;
    float bv = bias[n];
    float csum = 0.f;
#pragma unroll
    for (int mt = 0; mt < 4; ++mt)
#pragma unroll
      for (int r = 0; r < 4; ++r) {
        int m = bm + wm * 64 + mt * 16 + quad * 4 + r;
        float val = acc[mt][nt][r] + bv;
        if (z < 2) {
          C[(size_t)m * 256 + n] = val;
        } else {
          qa.Cv[(size_t)m * 256 + n] = f2b(val);
          csum += val;
        }
      }
    if (z == 2) {
      csum += __shfl_xor(csum, 16);
      csum += __shfl_xor(csum, 32);
      if (quad == 0) {
        int b = bm >> 11;
        atomicAdd(&qa.vmp[b * DMM + n], csum);
      }
    }
  }
}

// ---------------- FUSED O-proj GEMM (32x256, 512 thr) + tail (R17 pads) -------------------
// R19: residual path switched to bf16 hi+lo reconstruction (XB+XL); all f32 residual
// writes dropped (-8MB/layer here, -8MB in bn_elu). Reconstruction error ~2^-17 relative
// (lo = f2b(val - bfbits(hi)) by construction). In-place safe: each thread reads its
// row's residual before writing that row's output; rows are block-private.
__global__ __launch_bounds__(512) void oproj_tail(const float* __restrict__ vmp,
                                                  const unsigned char* __restrict__ mapb,
                                                  const float* __restrict__ pm,
                                                  const float* __restrict__ pl,
                                                  const float* __restrict__ po,
                                                  const unsigned short* __restrict__ W,
                                                  const float* __restrict__ bias,
                                                  const unsigned short* __restrict__ XBin,
                                                  const unsigned short* __restrict__ XLin,
                                                  const float* __restrict__ g1,
                                                  const float* __restrict__ b1ln,
                                                  const float* __restrict__ w1,
                                                  const float* __restrict__ b1,
                                                  const float* __restrict__ w2,
                                                  const float* __restrict__ b2,
                                                  const float* __restrict__ g2,
                                                  const float* __restrict__ b2ln,
                                                  unsigned short* __restrict__ OutB,
                                                  unsigned short* __restrict__ OutL,
                                                  const float* __restrict__ fing,
                                                  const float* __restrict__ finb,
                                                  void* __restrict__ finOut,
                                                  const int* __restrict__ flag,
                                                  float* __restrict__ stpZ,
                                                  float* __restrict__ stp2Z) {
  __shared__ __attribute__((aligned(16))) unsigned short As[OTR][DMM + APAD];
  __shared__ __attribute__((aligned(16))) unsigned short Bs[256][32];
  __shared__ float Cs[OTR][DMM + CPAD];
  __shared__ float xs[8][DMM];
  int tid = threadIdx.x;
  if (blockIdx.x == 0 && tid < DMM) {
    stpZ[tid] = 0.f;
    stp2Z[tid] = 0.f;
  }
  int bm = blockIdx.x * OTR;
  int wv = tid >> 6, lane = tid & 63;
  int l15 = lane & 15, quad = lane >> 4;
  int b = bm >> 11, l0 = bm & 2047;
  const float invL = 1.0f / (float)LL;

  // ---- phase 1: ctx A-panel for all 8 heads, once, full-block parallel ----
#pragma unroll
  for (int uu = 0; uu < 2; ++uu) {
    int u = tid * 2 + uu;            // 0..1023
    int arow = u >> 5;               // 32 rows
    int sub = u & 31;
    int h = sub >> 2, adg = sub & 3; // 8 heads x 4 col-groups
    int bh = b * HH + h;
    int l = l0 + arow;
    int q = (int)mapb[bh * 2048 + l];
    unsigned short outv[8];
    if (q) {
      size_t base = ((size_t)bh * UU + (q - 1)) * KC;
      float Mx = -1e30f;
#pragma unroll
      for (int kc = 0; kc < KC; ++kc) Mx = fmaxf(Mx, pm[base + kc]);
      float Ls = 0.f;
      float sc[KC];
#pragma unroll
      for (int kc = 0; kc < KC; ++kc) {
        sc[kc] = expf(pm[base + kc] - Mx);
        Ls += pl[base + kc] * sc[kc];
      }
      float inv = 1.0f / Ls;
#pragma unroll
      for (int j = 0; j < 8; ++j) {
        int dl = adg * 8 + j;
        float o = 0.f;
#pragma unroll
        for (int kc = 0; kc < KC; ++kc) o += po[(base + kc) * 32 + dl] * sc[kc];
        outv[j] = f2b(o * inv);
      }
    } else {
      const float* vp = vmp + b * DMM + h * EE + adg * 8;
#pragma unroll
      for (int j = 0; j < 8; ++j) outv[j] = f2b(vp[j] * invL);
    }
    *(uint4*)(&As[arow][h * EE + adg * 8]) = *(const uint4*)outv;
  }
  __syncthreads();

  // ---- phase 2: GEMM loop (pure stage+MFMA) ----
  f32x4 acc[2][2];
#pragma unroll
  for (int i = 0; i < 2; ++i)
#pragma unroll
    for (int j = 0; j < 2; ++j) acc[i][j] = (f32x4){0.f, 0.f, 0.f, 0.f};
  for (int k0 = 0; k0 < 256; k0 += 32) {
    if (k0) __syncthreads();
    {  // stage all 256 B-rows once per block (8 waves x 2 rounds x 16 rows)
      int lrw = lane >> 2, lsg = lane & 3;
#pragma unroll
      for (int s = 0; s < 2; ++s) {
        int brow = s * 128 + wv * 16;
        GLDS16(W + (size_t)(brow + lrw) * 256 + k0 + lsg * 8, &Bs[brow][0]);
      }
    }
    __syncthreads();
    short8 af[2], bfr[2];
#pragma unroll
    for (int mt = 0; mt < 2; ++mt)
      af[mt] = *(const short8*)(&As[mt * 16 + l15][k0 + quad * 8]);
#pragma unroll
    for (int nt = 0; nt < 2; ++nt)
      bfr[nt] = *(const short8*)(&Bs[wv * 32 + nt * 16 + l15][quad * 8]);
#pragma unroll
    for (int mt = 0; mt < 2; ++mt)
#pragma unroll
      for (int nt = 0; nt < 2; ++nt)
        acc[mt][nt] = __builtin_amdgcn_mfma_f32_16x16x32_bf16(af[mt], bfr[nt],
                                                              acc[mt][nt], 0, 0, 0);
  }
  // epilogue -> LDS (replaces tmp)
#pragma unroll
  for (int nt = 0; nt < 2; ++nt) {
    int n = wv * 32 + nt * 16 + l15;
    float bv = bias[n];
#pragma unroll
    for (int mt = 0; mt < 2; ++mt)
#pragma unroll
      for (int r = 0; r < 4; ++r)
        Cs[mt * 16 + quad * 4 + r][n] = acc[mt][nt][r] + bv;
  }
  __syncthreads();
  // ---- enc_tail body, 4 rows per wave; residual from bf16 hi+lo ----
  for (int rr = 0; rr < 4; ++rr) {
    int lr = wv * 4 + rr;
    size_t row = (size_t)bm + lr;
    const unsigned short* xbr = XBin + row * DMM;
    const unsigned short* xlr = XLin + row * DMM;
    const float* tr = Cs[lr];
    float v[4];
#pragma unroll
    for (int i = 0; i < 4; ++i) {
      int d = lane + 64 * i;
      v[i] = bfbits(xbr[d]) + bfbits(xlr[d]) + tr[d];
    }
    float s = wave_sum(v[0] + v[1] + v[2] + v[3]);
    float m = s * (1.0f / (float)DMM);
    float sq = 0.f;
#pragma unroll
    for (int i = 0; i < 4; ++i) { float d = v[i] - m; sq += d * d; }
    sq = wave_sum(sq);
    float rstd = rsqrtf(sq * (1.0f / (float)DMM) + 1e-5f);
    float xv[4];
#pragma unroll
    for (int i = 0; i < 4; ++i) {
      int d = lane + 64 * i;
      xv[i] = (v[i] - m) * rstd * g1[d] + b1ln[d];
      xs[wv][d] = xv[i];
    }
    __syncthreads();
    int f = lane & 15, qtr = lane >> 4;
    const float* w1p = w1 + f * DMM + qtr * 64;
    const float* xq = &xs[wv][qtr * 64];
    float pacc = 0.f;
#pragma unroll 8
    for (int d = 0; d < 64; ++d) pacc += xq[d] * w1p[d];
    pacc += __shfl_xor(pacc, 16);
    pacc += __shfl_xor(pacc, 32);
    float y1 = fmaxf(pacc + b1[f], 0.0f);
    float y1v[16];
#pragma unroll
    for (int ff = 0; ff < 16; ++ff) y1v[ff] = __shfl(y1, ff);
#pragma unroll
    for (int i = 0; i < 4; ++i) {
      int d = lane + 64 * i;
      const float* w2p = w2 + d * ITR;
      float a = b2[d];
#pragma unroll
      for (int ff = 0; ff < 16; ++ff) a += y1v[ff] * w2p[ff];
      v[i] = xv[i] + a;
    }
    s = wave_sum(v[0] + v[1] + v[2] + v[3]);
    m = s * (1.0f / (float)DMM);
    sq = 0.f;
#pragma unroll
    for (int i = 0; i < 4; ++i) { float d = v[i] - m; sq += d * d; }
    sq = wave_sum(sq);
    rstd = rsqrtf(sq * (1.0f / (float)DMM) + 1e-5f);
    float vv[4];
#pragma unroll
    for (int i = 0; i < 4; ++i) {
      int d = lane + 64 * i;
      float val = (v[i] - m) * rstd * g2[d] + b2ln[d];
      vv[i] = val;
      unsigned short hi = f2b(val);
      OutB[row * DMM + d] = hi;
      OutL[row * DMM + d] = f2b(val - bfbits(hi));
    }
    if (finOut) {
      s = wave_sum(vv[0] + vv[1] + vv[2] + vv[3]);
      m = s * (1.0f / (float)DMM);
      sq = 0.f;
#pragma unroll
      for (int i = 0; i < 4; ++i) { float d = vv[i] - m; sq += d * d; }
      sq = wave_sum(sq);
      rstd = rsqrtf(sq * (1.0f / (float)DMM) + 1e-5f);
      int isf32 = *flag;
#pragma unroll
      for (int i = 0; i < 4; ++i) {
        int d = lane + 64 * i;
        float val = (vv[i] - m) * rstd * fing[d] + finb[d];
        if (isf32) ((float*)finOut)[row * DMM + d] = val;
        else       ((unsigned short*)finOut)[row * DMM + d] = f2b(val);
      }
    }
  }
}

// ---------------- conv GEMM: A window staged once per k0, 3 taps from LDS ----------------
__global__ __launch_bounds__(256) void gemm_conv(const unsigned short* __restrict__ A,
                                                 const unsigned short* __restrict__ W,
                                                 const float* __restrict__ bias,
                                                 float* __restrict__ C,
                                                 float* __restrict__ stp,
                                                 float* __restrict__ stp2) {
  __shared__ __attribute__((aligned(16))) unsigned short As[80][32];
  __shared__ __attribute__((aligned(16))) unsigned short Bs[192][32];
  int bm = blockIdx.x * 64, bn = blockIdx.y * 64;
  int tid = threadIdx.x;
  int wv = tid >> 6, lane = tid & 63;
  int wm = wv >> 1, wn = wv & 1;
  int l15 = lane & 15, quad = lane >> 4;
  int lrow = lane >> 2, lseg = lane & 3;
  int bbase = bm & ~2047, l0 = bm & 2047;
  f32x4 acc[2][2];
#pragma unroll
  for (int i = 0; i < 2; ++i)
#pragma unroll
    for (int j = 0; j < 2; ++j) acc[i][j] = (f32x4){0.f, 0.f, 0.f, 0.f};
  for (int k0 = 0; k0 < 256; k0 += 32) {
    __syncthreads();
    for (int c = wv; c < 5; c += 4) {
      int i0 = c * 16;
      int l = (l0 - 1 + i0 + lrow + 2048) & 2047;
      GLDS16(A + (size_t)(bbase | l) * 256 + k0 + lseg * 8, &As[i0][0]);
    }
    for (int c = wv; c < 12; c += 4) {
      int i0 = c * 16;
      int tap = c >> 2, brow = (c & 3) * 16;
      GLDS16(W + (size_t)tap * 65536 + (size_t)(bn + brow + lrow) * 256 + k0 + lseg * 8,
             &Bs[i0][0]);
    }
    __syncthreads();
#pragma unroll
    for (int tap = 0; tap < 3; ++tap) {
      short8 af[2], bfr[2];
#pragma unroll
      for (int mt = 0; mt < 2; ++mt)
        af[mt] = *(const short8*)(&As[wm * 32 + mt * 16 + l15 + tap][quad * 8]);
#pragma unroll
      for (int nt = 0; nt < 2; ++nt)
        bfr[nt] = *(const short8*)(&Bs[tap * 64 + wn * 32 + nt * 16 + l15][quad * 8]);
#pragma unroll
      for (int mt = 0; mt < 2; ++mt)
#pragma unroll
        for (int nt = 0; nt < 2; ++nt)
          acc[mt][nt] = __builtin_amdgcn_mfma_f32_16x16x32_bf16(af[mt], bfr[nt],
                                                                acc[mt][nt], 0, 0, 0);
    }
  }
#pragma unroll
  for (int nt = 0; nt < 2; ++nt) {
    int n = bn + wn * 32 + nt * 16 + l15;
    float bv = bias[n];
    float s = 0.f, s2 = 0.f;
#pragma unroll
    for (int mt = 0; mt < 2; ++mt)
#pragma unroll
      for (int r = 0; r < 4; ++r) {
        int m = bm + wm * 32 + mt * 16 + quad * 4 + r;
        float val = acc[mt][nt][r] + bv;
        C[(size_t)m * 256 + n] = val;
        s += val;
        s2 += val * val;
      }
    s  += __shfl_xor(s, 16);   s  += __shfl_xor(s, 32);
    s2 += __shfl_xor(s2, 16);  s2 += __shfl_xor(s2, 32);
    if (quad == 0) {
      atomicAdd(&stp[n], s);
      atomicAdd(&stp2[n], s2);
    }
  }
}

// ---------------- M scores: wave per (b,l), inline threefry, XCD-affinity swizzle ----------
__global__ __launch_bounds__(256) void m_kernel3(const float* __restrict__ Q,
                                                 const float* __restrict__ K,
                                                 uint32_t k20, uint32_t k21,
                                                 float* __restrict__ M) {
  int bid = blockIdx.x;
  int blk = (bid & 7) * 256 + (bid >> 3);   // XCD-affinity remap (pure perf, no semantics)
  int b = blk >> 9, lc = blk & 511;
  int wave = threadIdx.x >> 6, lane = threadIdx.x & 63;
  int l = lc * 4 + wave;
  int myidx = 0;
  if (lane < UU) {
    int j = l * UU + lane;
    uint32_t o0, o1;
    const int half = (LL * UU) / 2;  // 40960
    if (j < half) {
      threefry2x32(k20, k21, (uint32_t)j, (uint32_t)(j + half), &o0, &o1);
      myidx = (int)(o0 & (LL - 1));
    } else {
      threefry2x32(k20, k21, (uint32_t)(j - half), (uint32_t)j, &o0, &o1);
      myidx = (int)(o1 & (LL - 1));
    }
  }
  float4 q4 = *(const float4*)(Q + ((size_t)(b * LL + l)) * DMM + lane * 4);
  const float* Kb = K + (size_t)b * LL * DMM;
  float mx = -1e30f, sm = 0.f;
#pragma unroll 8
  for (int u = 0; u < UU; ++u) {
    int kidx = __shfl(myidx, u);
    float4 k4 = *(const float4*)(Kb + (size_t)kidx * DMM + lane * 4);
    float s = q4.x * k4.x + q4.y * k4.y + q4.z * k4.z + q4.w * k4.w;
    s += __shfl_xor(s, 1);
    s += __shfl_xor(s, 2);
    s += __shfl_xor(s, 4);
    mx = fmaxf(mx, s);
    sm += s;
  }
  if ((lane & 7) == 0) {
    int h = lane >> 3;
    M[((size_t)(b * HH + h)) * LL + l] = mx - sm * (1.0f / (float)LL);
  }
}

// ---------------- fused topk + split-K flash attention (R18-proven, padded) ---------------
__global__ __launch_bounds__(256) void attn_part(const float* __restrict__ Q,
                                                 const float* __restrict__ K,
                                                 const unsigned short* __restrict__ Vbf,
                                                 const float* __restrict__ M,
                                                 unsigned char* __restrict__ mapb,
                                                 float* __restrict__ pm,
                                                 float* __restrict__ pl,
                                                 float* __restrict__ po) {
  __shared__ __attribute__((aligned(16))) unsigned short QsB[48][32 + KQP];
  __shared__ __attribute__((aligned(16))) unsigned short KsB[KCH][32 + KQP];
  __shared__ __attribute__((aligned(16))) unsigned short ps[48][KCH + PSP];
  __shared__ __attribute__((aligned(16))) unsigned short VsT[EE][KCH + PSP];
  __shared__ int qrows[40];
  __shared__ unsigned int hist[256];
  __shared__ unsigned int sA[256];
  __shared__ unsigned int wtot[4];
  __shared__ unsigned int tbv;
  int kc = blockIdx.x, bh = blockIdx.y;
  int h = bh & 7, b = bh >> 3;
  int tid = threadIdx.x;
  int wv = tid >> 6, lane = tid & 63;
  int l15 = lane & 15, quad = lane >> 4;

  // ---- independent V/K loads issued first (overlap with radix latency) ----
  {
    int row = tid >> 1, half = tid & 1;
    const unsigned short* vsrc =
        Vbf + (size_t)(b * LL + kc * KCH + row) * DMM + h * EE + half * 16;
    unsigned short tv[16];
    *(uint4*)(&tv[0]) = *(const uint4*)vsrc;
    *(uint4*)(&tv[8]) = *(const uint4*)(vsrc + 8);
#pragma unroll
    for (int j = 0; j < 16; ++j) VsT[half * 16 + j][row] = tv[j];
    // K: f32 -> bf16 into B-operand layout [key][dim]
    const float* ksrc = K + ((size_t)(b * LL + kc * KCH + row)) * DMM + h * EE + half * 16;
    unsigned short tk[16];
#pragma unroll
    for (int j = 0; j < 16; ++j) tk[j] = f2b(ksrc[j]);
    *(uint4*)(&KsB[row][half * 16]) = *(const uint4*)(&tk[0]);
    *(uint4*)(&KsB[row][half * 16 + 8]) = *(const uint4*)(&tk[8]);
  }

  // ---- exact top-40 radix select on M[bh]: packed 43-bit keys, 6 rounds (R14-proven) ----
  u64 kreg[8];
#pragma unroll
  for (int r = 0; r < 8; ++r) {
    int l = tid + 256 * r;
    float v = M[(size_t)bh * LL + l];
    uint32_t bits = __float_as_uint(v);
    uint32_t kv = (bits & 0x80000000u) ? ~bits : (bits | 0x80000000u);
    kreg[r] = ((u64)kv << 11) | (uint32_t)(2047 - l);
  }
  u64 prefix = 0;
  int rank = UU;
  for (int round = 0; round < 6; ++round) {
    int shift = 40 - 8 * round;
    u64 maskTop = (round == 0) ? 0ull : (~0ull << (48 - 8 * round));
    hist[tid] = 0;
    __syncthreads();
#pragma unroll
    for (int r = 0; r < 8; ++r) {
      u64 k = kreg[r];
      if ((k & maskTop) == prefix)
        atomicAdd(&hist[(unsigned int)((k >> shift) & 0xFFu)], 1u);
    }
    __syncthreads();
    unsigned int s = hist[tid];
#pragma unroll
    for (int off = 1; off < 64; off <<= 1) {
      unsigned int t = __shfl_down(s, off);
      if (lane + off < 64) s += t;
    }
    if (lane == 0) wtot[wv] = s;
    __syncthreads();
    unsigned int add = 0;
#pragma unroll
    for (int w = 0; w < 4; ++w)
      if (w > wv) add += wtot[w];
    sA[tid] = s + add;
    __syncthreads();
    unsigned int Sb = sA[tid];
    unsigned int Snext = (tid < 255) ? sA[tid + 1] : 0u;
    if (Sb >= (unsigned int)rank && Snext < (unsigned int)rank) tbv = (unsigned int)tid;
    __syncthreads();
    unsigned int tb = tbv;
    unsigned int above = (tb < 255u) ? sA[tb + 1] : 0u;
    rank -= (int)above;
    prefix |= ((u64)tb) << shift;
  }
  u64 T = prefix;   // exact 40th-largest packed key
  // ---- deterministic rank: in-wave prefix + cross-wave totals (exclusive over tid) ----
  int myCnt = 0;
#pragma unroll
  for (int r = 0; r < 8; ++r) myCnt += (kreg[r] >= T) ? 1 : 0;
  {
    unsigned int p = (unsigned int)myCnt;
#pragma unroll
    for (int off = 1; off < 64; off <<= 1) {
      unsigned int t = __shfl_up(p, off);
      if (lane >= off) p += t;
    }
    if (lane == 63) wtot[wv] = p;
    __syncthreads();
    unsigned int addp = 0;
#pragma unroll
    for (int w = 0; w < 4; ++w)
      if (w < wv) addp += wtot[w];
    int pos = (int)(p + addp) - myCnt;   // exclusive prefix
    bool wmap = (kc == 0);
#pragma unroll
    for (int r = 0; r < 8; ++r) {
      u64 k = kreg[r];
      int l = 2047 - (int)(uint32_t)(k & 0x7FFu);
      unsigned char mv = 0;
      if (k >= T) {
        qrows[pos] = l;
        mv = (unsigned char)(pos + 1);
        pos++;
      }
      if (wmap) mapb[bh * 2048 + l] = mv;
    }
  }
  __syncthreads();

  // ---- Q staging (bf16, A-operand layout) for the 40 selected rows; rows 40-47 zero ----
  for (int t = tid; t < 40 * 32; t += 256) {
    int q = t >> 5, d = t & 31;
    QsB[q][d] = f2b(Q[((size_t)(b * LL + qrows[q])) * DMM + h * EE + d]);
  }
  {
    int q = 40 + (tid >> 5), d = tid & 31;
    if (q < 48) QsB[q][d] = 0;   // tid 0..255 covers exactly rows 40..47
  }
  __syncthreads();
  // ---- scores via MFMA: waves 0..2, one 16-q tile x 128 keys each ----
  if (wv < 3) {
    const float scale = 0.17677669529663687f;
    short8 aq = *(const short8*)(&QsB[wv * 16 + l15][quad * 8]);
    f32x4 sacc[8];
#pragma unroll
    for (int nt = 0; nt < 8; ++nt) {
      short8 bk = *(const short8*)(&KsB[nt * 16 + l15][quad * 8]);
      sacc[nt] = __builtin_amdgcn_mfma_f32_16x16x32_bf16(
          aq, bk, (f32x4){0.f, 0.f, 0.f, 0.f}, 0, 0, 0);
    }
#pragma unroll
    for (int nt = 0; nt < 8; ++nt)
#pragma unroll
      for (int r = 0; r < 4; ++r)
        ps[wv * 16 + quad * 4 + r][nt * 16 + l15] = f2b(sacc[nt][r] * scale);
  }
  __syncthreads();
  // ---- softmax (max + exp + sum per row; writes exp back to ps; pm/pl) ----
  for (int qq = 0; qq < 10; ++qq) {
    int q = wv * 10 + qq;
    float mx = fmaxf(bfbits(ps[q][lane]), bfbits(ps[q][lane + 64]));
#pragma unroll
    for (int off = 32; off > 0; off >>= 1) mx = fmaxf(mx, __shfl_xor(mx, off));
    float e0 = expf(bfbits(ps[q][lane]) - mx);
    float e1 = expf(bfbits(ps[q][lane + 64]) - mx);
    ps[q][lane] = f2b(e0);
    ps[q][lane + 64] = f2b(e1);
    float sum = wave_sum(e0 + e1);
    size_t base = ((size_t)bh * UU + q) * KC + kc;
    if (lane == 0) { pm[base] = mx; pl[base] = sum; }
  }
  __syncthreads();
  // ---- PV via MFMA: waves 0..2 each compute one 16-row q-tile x 32 cols (R15-proven) ----
  if (wv < 3) {
    f32x4 pacc[2];
#pragma unroll
    for (int nt = 0; nt < 2; ++nt) pacc[nt] = (f32x4){0.f, 0.f, 0.f, 0.f};
#pragma unroll
    for (int kch = 0; kch < 4; ++kch) {
      short8 af = *(const short8*)(&ps[wv * 16 + l15][kch * 32 + quad * 8]);
#pragma unroll
      for (int nt = 0; nt < 2; ++nt) {
        short8 bfr = *(const short8*)(&VsT[nt * 16 + l15][kch * 32 + quad * 8]);
        pacc[nt] = __builtin_amdgcn_mfma_f32_16x16x32_bf16(af, bfr, pacc[nt], 0, 0, 0);
      }
    }
#pragma unroll
    for (int nt = 0; nt < 2; ++nt) {
      int d = nt * 16 + l15;
#pragma unroll
      for (int r = 0; r < 4; ++r) {
        int q = wv * 16 + quad * 4 + r;
        if (q < UU) {
          size_t base = ((size_t)bh * UU + q) * KC + kc;
          po[base * 32 + d] = pacc[nt][r];
        }
      }
    }
  }
}

// ---------------- bn+elu from atomic stats (bf16 hi+lo out only; +vmp zero) ---------------
__global__ __launch_bounds__(256) void bn_elu(const float* __restrict__ Y,
                                              const float* __restrict__ stp,
                                              const float* __restrict__ stp2,
                                              const float* __restrict__ g,
                                              const float* __restrict__ bb,
                                              unsigned short* __restrict__ XB,
                                              unsigned short* __restrict__ XL,
                                              float* __restrict__ vmpZ) {
  int gid = blockIdx.x * 256 + threadIdx.x;
  if (gid < BB * DMM) vmpZ[gid] = 0.f;
  int d = gid & 255;
  float mean = stp[d] * (1.0f / (float)ROWS);
  float var = stp2[d] * (1.0f / (float)ROWS) - mean * mean;
  float rstd = rsqrtf(var + 1e-5f);
  float v = (Y[gid] - mean) * rstd * g[d] + bb[d];
  float r = v > 0.f ? v : expm1f(v);
  unsigned short hi = f2b(r);
  XB[gid] = hi;
  XL[gid] = f2b(r - bfbits(hi));
}

extern "C" void kernel_launch(void* const* d_in, const int* in_sizes, int n_in,
                              void* d_out, int out_size, void* d_ws, size_t ws_size,
                              hipStream_t stream) {
  (void)in_sizes; (void)n_in; (void)out_size; (void)ws_size;

  // ---- workspace layout ----
  float* xbuf = (float*)d_ws;
  float* kb   = xbuf + NELEM;
  float* qb   = kb + NELEM;   // aliases tmp (Q dead after attn_part)
  float* tmp  = qb;
  float* Mbuf = qb + NELEM;
  float* vmp  = Mbuf + BB * HH * LL;
  float* stp  = vmp + BB * DMM;
  float* stp2 = stp + DMM;
  float* wp   = stp2 + DMM;
  const int wsz[23] = {
      NELEM,
      NLL * DMM * DMM, NLL * DMM,
      NLL * DMM * DMM, NLL * DMM,
      NLL * DMM * DMM, NLL * DMM,
      NLL * DMM * DMM, NLL * DMM,
      NLL * ITR * DMM, NLL * ITR,
      NLL * DMM * ITR, NLL * DMM,
      NLL * DMM, NLL * DMM,
      NLL * DMM, NLL * DMM,
      (NLL - 1) * DMM * DMM * 3, (NLL - 1) * DMM,
      (NLL - 1) * DMM, (NLL - 1) * DMM,
      DMM, DMM
  };
  float* fptr[23];
  fptr[0] = xbuf;
  for (int i = 1; i < 23; ++i) { fptr[i] = wp; wp += wsz[i]; }
  float* pm = wp;
  float* pl = pm + 32 * UU * KC;
  float* po = pl + 32 * UU * KC;
  unsigned short* xbf   = (unsigned short*)(po + 32 * UU * KC * 32);
  unsigned short* xlo   = xbf + NELEM;
  unsigned short* vbf   = xlo + NELEM;
  unsigned short* wqbf  = vbf + NELEM;
  unsigned short* wkbf  = wqbf + NLL * DMM * DMM;
  unsigned short* wvbf  = wkbf + NLL * DMM * DMM;
  unsigned short* wobf  = wvbf + NLL * DMM * DMM;
  unsigned short* dcwT  = wobf + NLL * DMM * DMM;
  u64* cand = (u64*)(dcwT + (NLL - 1) * 3 * DMM * DMM);  // layout kept (unused now)
  int* topb = (int*)(cand + 256 * 40);                    // layout kept (unused now)
  int* flag = topb + BB * HH * UU;
  unsigned char* mapb = (unsigned char*)(flag + 1);  // 32*2048

  // ---- convert (+cheap inline dtype probe, +dcw repack, +vmp zero, +flag publish) ----
  CvtArgs ca;
  int totalBlk = 0;
  for (int i = 0; i < 23; ++i) {
    ca.src[i] = d_in[i];
    ca.dstF[i] = fptr[i];
    ca.dstB[i] = nullptr;
    ca.dstL[i] = nullptr;
    ca.n[i] = wsz[i];
    ca.blkStart[i] = totalBlk;
    totalBlk += (wsz[i] + 255) / 256;
  }
  ca.blkStart[23] = totalBlk;
  ca.dstB[0] = xbf;  ca.dstL[0] = xlo;
  ca.dstB[1] = wqbf;
  ca.dstB[3] = wkbf;
  ca.dstB[5] = wvbf;
  ca.dstB[7] = wobf;
  ca.dcwT = dcwT;
  ca.vmpZ = vmp;
  ca.flagOut = flag;
  mega_cvt<<<totalBlk + 1, 256, 0, stream>>>(ca);

  dim3 gqkv(ROWS / 128, DMM / 64, 3);
  dim3 g64(ROWS / 64, DMM / 64);

  for (int i = 0; i < NLL; ++i) {
    QKVArgs qa;
    qa.W[0] = wqbf + (size_t)i * DMM * DMM;
    qa.W[1] = wkbf + (size_t)i * DMM * DMM;
    qa.W[2] = wvbf + (size_t)i * DMM * DMM;
    qa.bias[0] = fptr[2] + i * DMM;
    qa.bias[1] = fptr[4] + i * DMM;
    qa.bias[2] = fptr[6] + i * DMM;
    qa.Cq = qb; qa.Ck = kb; qa.Cv = vbf;
    qa.vmp = vmp;
    gemm_qkv<<<gqkv, 256, 0, stream>>>(xbf, xlo, qa);

    uint32_t ki0, ki1, a0, a1, b0, b1;
    threefry2x32(0u, 42u, 0u, (uint32_t)i, &ki0, &ki1);
    threefry2x32(ki0, ki1, 0u, 2u, &a0, &a1);
    threefry2x32(ki0, ki1, 1u, 3u, &b0, &b1);
    (void)a0; (void)b0;

    m_kernel3<<<BB * 512, 256, 0, stream>>>(qb, kb, a1, b1, Mbuf);
    attn_part<<<dim3(KC, BB * HH), 256, 0, stream>>>(qb, kb, vbf, Mbuf, mapb,
                                                     pm, pl, po);

    bool last = (i == NLL - 1);
    oproj_tail<<<ROWS / OTR, 512, 0, stream>>>(
        vmp, mapb, pm, pl, po,
        wobf + (size_t)i * DMM * DMM, fptr[8] + i * DMM,
        xbf, xlo,
        fptr[13] + i * DMM, fptr[14] + i * DMM,
        fptr[9] + (size_t)i * ITR * DMM, fptr[10] + i * ITR,
        fptr[11] + (size_t)i * DMM * ITR, fptr[12] + i * DMM,
        fptr[15] + i * DMM, fptr[16] + i * DMM,
        xbf, xlo,
        fptr[21], fptr[22], last ? d_out : nullptr, flag, stp, stp2);

    if (!last) {
      gemm_conv<<<g64, 256, 0, stream>>>(xbf, dcwT + (size_t)i * 3 * DMM * DMM,
                                         fptr[18] + i * DMM, tmp, stp, stp2);
      bn_elu<<<NELEM / 256, 256, 0, stream>>>(tmp, stp, stp2, fptr[19] + i * DMM,
                                              fptr[20] + i * DMM, xbf, xlo, vmp);
    }
  }
}

// Round 20
// 430.567 us; speedup vs baseline: 1.2863x; 1.0050x over previous
//
#include <hip/hip_runtime.h>
#include <stdint.h>

#define BB 4
#define LL 2048
#define DMM 256
#define HH 8
#define EE 32
#define NLL 3
#define ITR 16
#define UU 40
#define KC 16                 // split-K chunks
#define KCH 128               // keys per chunk
#define ROWS (BB*LL)          // 8192
#define NELEM (ROWS*DMM)      // 2097152
#define OTR 32                // oproj_tail rows per block (32 -> 256 blocks, 512 thr each)
#define APAD 8                // As leading-dim pad (shorts): 264*2=528B = 132 dw = 4 mod 32
#define CPAD 4                // Cs leading-dim pad (floats): 260 dw = 4 mod 32
#define PSP 8                 // ps/VsT pad (shorts): 136*2=272B = 68 dw = 4 mod 32 -> 2-way
#define KQP 8                 // KsB/QsB pad (shorts): 40*2=80B = 20 dw = 20 mod 32 -> 2-way

typedef __attribute__((ext_vector_type(8))) short short8;
typedef __attribute__((ext_vector_type(4))) float f32x4;
typedef unsigned long long u64;

#define GLDS16(g, l)                                                        \
  __builtin_amdgcn_global_load_lds(                                         \
      (const __attribute__((address_space(1))) uint32_t*)(g),               \
      (__attribute__((address_space(3))) uint32_t*)(l), 16, 0, 0)

// ---------------- bf16 bit helpers (RNE) ----------------
__device__ __forceinline__ float bfbits(unsigned short u) {
  return __uint_as_float(((uint32_t)u) << 16);
}
__device__ __forceinline__ unsigned short f2b(float f) {
  uint32_t u = __float_as_uint(f);
  uint32_t r = (u + 0x7FFFu + ((u >> 16) & 1u)) >> 16;
  return (unsigned short)r;
}

// ---------------- threefry2x32 (exact JAX semantics) ----------------
__host__ __device__ inline void threefry2x32(uint32_t k0, uint32_t k1,
                                             uint32_t x0, uint32_t x1,
                                             uint32_t* o0, uint32_t* o1) {
  uint32_t ks2 = k0 ^ k1 ^ 0x1BD11BDAu;
  x0 += k0; x1 += k1;
#define TFR(r) { x0 += x1; x1 = (x1 << (r)) | (x1 >> (32 - (r))); x1 ^= x0; }
  TFR(13) TFR(15) TFR(26) TFR(6)
  x0 += k1;  x1 += ks2 + 1u;
  TFR(17) TFR(29) TFR(16) TFR(24)
  x0 += ks2; x1 += k0 + 2u;
  TFR(13) TFR(15) TFR(26) TFR(6)
  x0 += k0;  x1 += k1 + 3u;
  TFR(17) TFR(29) TFR(16) TFR(24)
  x0 += k1;  x1 += ks2 + 4u;
  TFR(13) TFR(15) TFR(26) TFR(6)
  x0 += ks2; x1 += k0 + 5u;
#undef TFR
  *o0 = x0; *o1 = x1;
}

__device__ __forceinline__ float wave_sum(float v) {
#pragma unroll
  for (int off = 32; off > 0; off >>= 1) v += __shfl_xor(v, off);
  return v;
}

// ---------------- mega convert (+hi/lo splits, +dcw repack, +vmp zero, +cheap inline probe) -
// R20: dstF is nullable; dead f32 copies (x, wq, wk, wv, wo, dcw ~ 12.7 MB) dropped.
struct CvtArgs {
  const void* src[23];
  float* dstF[23];
  unsigned short* dstB[23];
  unsigned short* dstL[23];
  int n[23];
  int blkStart[24];
  unsigned short* dcwT;
  float* vmpZ;     // zero BB*DMM floats
  int* flagOut;    // published dtype flag
};
__global__ __launch_bounds__(256) void mega_cvt(CvtArgs a) {
  // ---- inline dtype probe: 512 shorts (2/thread). bf16 data -> cnt~0; f32 data -> cnt~228.
  __shared__ int cnt;
  if (threadIdx.x == 0) cnt = 0;
  __syncthreads();
  {
    const unsigned short* u = (const unsigned short*)a.src[0];
    int bad = 0;
#pragma unroll
    for (int rep = 0; rep < 2; ++rep) {
      float v = bfbits(u[threadIdx.x + 256 * rep]);
      float av = fabsf(v);
      bool ok = (v == 0.0f) || (av > 1e-4f && av < 100.0f);
      if (!ok) bad++;
    }
    if (bad) atomicAdd(&cnt, bad);
  }
  __syncthreads();
  int isf32 = (cnt > 25) ? 1 : 0;

  int bid = blockIdx.x;
  if (bid == a.blkStart[23]) {
    for (int t = threadIdx.x; t < BB * DMM; t += 256) a.vmpZ[t] = 0.f;
    if (threadIdx.x == 0) *a.flagOut = isf32;
    return;
  }
  int i = 0;
  while (i < 22 && bid >= a.blkStart[i + 1]) ++i;
  int e = (bid - a.blkStart[i]) * 256 + (int)threadIdx.x;
  if (e >= a.n[i]) return;
  float v; unsigned short rw;
  if (isf32) { v = ((const float*)a.src[i])[e]; rw = f2b(v); }
  else       { rw = ((const unsigned short*)a.src[i])[e]; v = bfbits(rw); }
  if (a.dstF[i]) a.dstF[i][e] = v;
  if (a.dstB[i]) a.dstB[i][e] = rw;
  if (a.dstL[i]) a.dstL[i][e] = f2b(v - bfbits(rw));
  if (i == 17) {  // dcw: [ly][n][k][t] -> [ly][t][n][k] bf16
    int ly = e / 196608;
    int r = e - ly * 196608;
    int n = r / 768;
    int rem = r - n * 768;
    int k = rem / 3, t = rem - k * 3;
    a.dcwT[ly * 196608 + t * 65536 + n * 256 + k] = rw;
  }
}

// ---------------- QKV MFMA GEMM: z=0:Q 1:K (hi/lo 2-pass, f32 out) 2:V (bf16 out + vmean) --
// (round-0 proven version: BK=32, [128][32]/[64][32] LDS)
struct QKVArgs {
  const unsigned short* W[3];
  const float* bias[3];
  float* Cq;
  float* Ck;
  unsigned short* Cv;
  float* vmp;
};
__global__ __launch_bounds__(256) void gemm_qkv(const unsigned short* __restrict__ Ahi,
                                                const unsigned short* __restrict__ Alo,
                                                QKVArgs qa) {
  __shared__ __attribute__((aligned(16))) unsigned short AsH[128][32];
  __shared__ __attribute__((aligned(16))) unsigned short AsL[128][32];
  __shared__ __attribute__((aligned(16))) unsigned short Bs[64][32];
  int z = blockIdx.z;
  const unsigned short* W = qa.W[z];
  const float* bias = qa.bias[z];
  bool twoPass = (z < 2);
  int bm = blockIdx.x * 128, bn = blockIdx.y * 64;
  int tid = threadIdx.x;
  int wv = tid >> 6, lane = tid & 63;
  int wm = wv >> 1, wn = wv & 1;
  int l15 = lane & 15, quad = lane >> 4;
  int lrow = lane >> 2, lseg = lane & 3;
  f32x4 acc[4][2];
#pragma unroll
  for (int i = 0; i < 4; ++i)
#pragma unroll
    for (int j = 0; j < 2; ++j) acc[i][j] = (f32x4){0.f, 0.f, 0.f, 0.f};
  for (int k0 = 0; k0 < 256; k0 += 32) {
    __syncthreads();
#pragma unroll
    for (int s = 0; s < 2; ++s) {
      int brow = (wv + s * 4) * 16;
      size_t goff = (size_t)(bm + brow + lrow) * 256 + k0 + lseg * 8;
      GLDS16(Ahi + goff, &AsH[brow][0]);
      if (twoPass) GLDS16(Alo + goff, &AsL[brow][0]);
    }
    {
      int brow = wv * 16;
      GLDS16(W + (size_t)(bn + brow + lrow) * 256 + k0 + lseg * 8, &Bs[brow][0]);
    }
    __syncthreads();
    short8 ah[4], bfr[2];
#pragma unroll
    for (int mt = 0; mt < 4; ++mt)
      ah[mt] = *(const short8*)(&AsH[wm * 64 + mt * 16 + l15][quad * 8]);
#pragma unroll
    for (int nt = 0; nt < 2; ++nt)
      bfr[nt] = *(const short8*)(&Bs[wn * 32 + nt * 16 + l15][quad * 8]);
#pragma unroll
    for (int mt = 0; mt < 4; ++mt)
#pragma unroll
      for (int nt = 0; nt < 2; ++nt)
        acc[mt][nt] = __builtin_amdgcn_mfma_f32_16x16x32_bf16(ah[mt], bfr[nt],
                                                              acc[mt][nt], 0, 0, 0);
    if (twoPass) {
      short8 al[4];
#pragma unroll
      for (int mt = 0; mt < 4; ++mt)
        al[mt] = *(const short8*)(&AsL[wm * 64 + mt * 16 + l15][quad * 8]);
#pragma unroll
      for (int mt = 0; mt < 4; ++mt)
#pragma unroll
        for (int nt = 0; nt < 2; ++nt)
          acc[mt][nt] = __builtin_amdgcn_mfma_f32_16x16x32_bf16(al[mt], bfr[nt],
                                                                acc[mt][nt], 0, 0, 0);
    }
  }
  float* C = (z == 0) ? qa.Cq : qa.Ck;
#pragma unroll
  for (int nt = 0; nt < 2; ++nt) {
    int n = bn + wn * 32 + nt * 16 + l15;
    float bv = bias[n];
    float csum = 0.f;
#pragma unroll
    for (int mt = 0; mt < 4; ++mt)
#pragma unroll
      for (int r = 0; r < 4; ++r) {
        int m = bm + wm * 64 + mt * 16 + quad * 4 + r;
        float val = acc[mt][nt][r] + bv;
        if (z < 2) {
          C[(size_t)m * 256 + n] = val;
        } else {
          qa.Cv[(size_t)m * 256 + n] = f2b(val);
          csum += val;
        }
      }
    if (z == 2) {
      csum += __shfl_xor(csum, 16);
      csum += __shfl_xor(csum, 32);
      if (quad == 0) {
        int b = bm >> 11;
        atomicAdd(&qa.vmp[b * DMM + n], csum);
      }
    }
  }
}

// ---------------- FUSED O-proj GEMM (32x256, 512 thr) + tail (R19: bf16 residual) ---------
__global__ __launch_bounds__(512) void oproj_tail(const float* __restrict__ vmp,
                                                  const unsigned char* __restrict__ mapb,
                                                  const float* __restrict__ pm,
                                                  const float* __restrict__ pl,
                                                  const float* __restrict__ po,
                                                  const unsigned short* __restrict__ W,
                                                  const float* __restrict__ bias,
                                                  const unsigned short* __restrict__ XBin,
                                                  const unsigned short* __restrict__ XLin,
                                                  const float* __restrict__ g1,
                                                  const float* __restrict__ b1ln,
                                                  const float* __restrict__ w1,
                                                  const float* __restrict__ b1,
                                                  const float* __restrict__ w2,
                                                  const float* __restrict__ b2,
                                                  const float* __restrict__ g2,
                                                  const float* __restrict__ b2ln,
                                                  unsigned short* __restrict__ OutB,
                                                  unsigned short* __restrict__ OutL,
                                                  const float* __restrict__ fing,
                                                  const float* __restrict__ finb,
                                                  void* __restrict__ finOut,
                                                  const int* __restrict__ flag,
                                                  float* __restrict__ stpZ,
                                                  float* __restrict__ stp2Z) {
  __shared__ __attribute__((aligned(16))) unsigned short As[OTR][DMM + APAD];
  __shared__ __attribute__((aligned(16))) unsigned short Bs[256][32];
  __shared__ float Cs[OTR][DMM + CPAD];
  __shared__ float xs[8][DMM];
  int tid = threadIdx.x;
  if (blockIdx.x == 0 && tid < DMM) {
    stpZ[tid] = 0.f;
    stp2Z[tid] = 0.f;
  }
  int bm = blockIdx.x * OTR;
  int wv = tid >> 6, lane = tid & 63;
  int l15 = lane & 15, quad = lane >> 4;
  int b = bm >> 11, l0 = bm & 2047;
  const float invL = 1.0f / (float)LL;

  // ---- phase 1: ctx A-panel for all 8 heads, once, full-block parallel ----
#pragma unroll
  for (int uu = 0; uu < 2; ++uu) {
    int u = tid * 2 + uu;            // 0..1023
    int arow = u >> 5;               // 32 rows
    int sub = u & 31;
    int h = sub >> 2, adg = sub & 3; // 8 heads x 4 col-groups
    int bh = b * HH + h;
    int l = l0 + arow;
    int q = (int)mapb[bh * 2048 + l];
    unsigned short outv[8];
    if (q) {
      size_t base = ((size_t)bh * UU + (q - 1)) * KC;
      float Mx = -1e30f;
#pragma unroll
      for (int kc = 0; kc < KC; ++kc) Mx = fmaxf(Mx, pm[base + kc]);
      float Ls = 0.f;
      float sc[KC];
#pragma unroll
      for (int kc = 0; kc < KC; ++kc) {
        sc[kc] = expf(pm[base + kc] - Mx);
        Ls += pl[base + kc] * sc[kc];
      }
      float inv = 1.0f / Ls;
#pragma unroll
      for (int j = 0; j < 8; ++j) {
        int dl = adg * 8 + j;
        float o = 0.f;
#pragma unroll
        for (int kc = 0; kc < KC; ++kc) o += po[(base + kc) * 32 + dl] * sc[kc];
        outv[j] = f2b(o * inv);
      }
    } else {
      const float* vp = vmp + b * DMM + h * EE + adg * 8;
#pragma unroll
      for (int j = 0; j < 8; ++j) outv[j] = f2b(vp[j] * invL);
    }
    *(uint4*)(&As[arow][h * EE + adg * 8]) = *(const uint4*)outv;
  }
  __syncthreads();

  // ---- phase 2: GEMM loop (pure stage+MFMA) ----
  f32x4 acc[2][2];
#pragma unroll
  for (int i = 0; i < 2; ++i)
#pragma unroll
    for (int j = 0; j < 2; ++j) acc[i][j] = (f32x4){0.f, 0.f, 0.f, 0.f};
  for (int k0 = 0; k0 < 256; k0 += 32) {
    if (k0) __syncthreads();
    {  // stage all 256 B-rows once per block (8 waves x 2 rounds x 16 rows)
      int lrw = lane >> 2, lsg = lane & 3;
#pragma unroll
      for (int s = 0; s < 2; ++s) {
        int brow = s * 128 + wv * 16;
        GLDS16(W + (size_t)(brow + lrw) * 256 + k0 + lsg * 8, &Bs[brow][0]);
      }
    }
    __syncthreads();
    short8 af[2], bfr[2];
#pragma unroll
    for (int mt = 0; mt < 2; ++mt)
      af[mt] = *(const short8*)(&As[mt * 16 + l15][k0 + quad * 8]);
#pragma unroll
    for (int nt = 0; nt < 2; ++nt)
      bfr[nt] = *(const short8*)(&Bs[wv * 32 + nt * 16 + l15][quad * 8]);
#pragma unroll
    for (int mt = 0; mt < 2; ++mt)
#pragma unroll
      for (int nt = 0; nt < 2; ++nt)
        acc[mt][nt] = __builtin_amdgcn_mfma_f32_16x16x32_bf16(af[mt], bfr[nt],
                                                              acc[mt][nt], 0, 0, 0);
  }
  // epilogue -> LDS (replaces tmp)
#pragma unroll
  for (int nt = 0; nt < 2; ++nt) {
    int n = wv * 32 + nt * 16 + l15;
    float bv = bias[n];
#pragma unroll
    for (int mt = 0; mt < 2; ++mt)
#pragma unroll
      for (int r = 0; r < 4; ++r)
        Cs[mt * 16 + quad * 4 + r][n] = acc[mt][nt][r] + bv;
  }
  __syncthreads();
  // ---- enc_tail body, 4 rows per wave; residual from bf16 hi+lo ----
  for (int rr = 0; rr < 4; ++rr) {
    int lr = wv * 4 + rr;
    size_t row = (size_t)bm + lr;
    const unsigned short* xbr = XBin + row * DMM;
    const unsigned short* xlr = XLin + row * DMM;
    const float* tr = Cs[lr];
    float v[4];
#pragma unroll
    for (int i = 0; i < 4; ++i) {
      int d = lane + 64 * i;
      v[i] = bfbits(xbr[d]) + bfbits(xlr[d]) + tr[d];
    }
    float s = wave_sum(v[0] + v[1] + v[2] + v[3]);
    float m = s * (1.0f / (float)DMM);
    float sq = 0.f;
#pragma unroll
    for (int i = 0; i < 4; ++i) { float d = v[i] - m; sq += d * d; }
    sq = wave_sum(sq);
    float rstd = rsqrtf(sq * (1.0f / (float)DMM) + 1e-5f);
    float xv[4];
#pragma unroll
    for (int i = 0; i < 4; ++i) {
      int d = lane + 64 * i;
      xv[i] = (v[i] - m) * rstd * g1[d] + b1ln[d];
      xs[wv][d] = xv[i];
    }
    __syncthreads();
    int f = lane & 15, qtr = lane >> 4;
    const float* w1p = w1 + f * DMM + qtr * 64;
    const float* xq = &xs[wv][qtr * 64];
    float pacc = 0.f;
#pragma unroll 8
    for (int d = 0; d < 64; ++d) pacc += xq[d] * w1p[d];
    pacc += __shfl_xor(pacc, 16);
    pacc += __shfl_xor(pacc, 32);
    float y1 = fmaxf(pacc + b1[f], 0.0f);
    float y1v[16];
#pragma unroll
    for (int ff = 0; ff < 16; ++ff) y1v[ff] = __shfl(y1, ff);
#pragma unroll
    for (int i = 0; i < 4; ++i) {
      int d = lane + 64 * i;
      const float* w2p = w2 + d * ITR;
      float a = b2[d];
#pragma unroll
      for (int ff = 0; ff < 16; ++ff) a += y1v[ff] * w2p[ff];
      v[i] = xv[i] + a;
    }
    s = wave_sum(v[0] + v[1] + v[2] + v[3]);
    m = s * (1.0f / (float)DMM);
    sq = 0.f;
#pragma unroll
    for (int i = 0; i < 4; ++i) { float d = v[i] - m; sq += d * d; }
    sq = wave_sum(sq);
    rstd = rsqrtf(sq * (1.0f / (float)DMM) + 1e-5f);
    float vv[4];
#pragma unroll
    for (int i = 0; i < 4; ++i) {
      int d = lane + 64 * i;
      float val = (v[i] - m) * rstd * g2[d] + b2ln[d];
      vv[i] = val;
      unsigned short hi = f2b(val);
      OutB[row * DMM + d] = hi;
      OutL[row * DMM + d] = f2b(val - bfbits(hi));
    }
    if (finOut) {
      s = wave_sum(vv[0] + vv[1] + vv[2] + vv[3]);
      m = s * (1.0f / (float)DMM);
      sq = 0.f;
#pragma unroll
      for (int i = 0; i < 4; ++i) { float d = vv[i] - m; sq += d * d; }
      sq = wave_sum(sq);
      rstd = rsqrtf(sq * (1.0f / (float)DMM) + 1e-5f);
      int isf32 = *flag;
#pragma unroll
      for (int i = 0; i < 4; ++i) {
        int d = lane + 64 * i;
        float val = (vv[i] - m) * rstd * fing[d] + finb[d];
        if (isf32) ((float*)finOut)[row * DMM + d] = val;
        else       ((unsigned short*)finOut)[row * DMM + d] = f2b(val);
      }
    }
  }
}

// ---------------- conv GEMM: A window staged once per k0, 3 taps from LDS ----------------
__global__ __launch_bounds__(256) void gemm_conv(const unsigned short* __restrict__ A,
                                                 const unsigned short* __restrict__ W,
                                                 const float* __restrict__ bias,
                                                 float* __restrict__ C,
                                                 float* __restrict__ stp,
                                                 float* __restrict__ stp2) {
  __shared__ __attribute__((aligned(16))) unsigned short As[80][32];
  __shared__ __attribute__((aligned(16))) unsigned short Bs[192][32];
  int bm = blockIdx.x * 64, bn = blockIdx.y * 64;
  int tid = threadIdx.x;
  int wv = tid >> 6, lane = tid & 63;
  int wm = wv >> 1, wn = wv & 1;
  int l15 = lane & 15, quad = lane >> 4;
  int lrow = lane >> 2, lseg = lane & 3;
  int bbase = bm & ~2047, l0 = bm & 2047;
  f32x4 acc[2][2];
#pragma unroll
  for (int i = 0; i < 2; ++i)
#pragma unroll
    for (int j = 0; j < 2; ++j) acc[i][j] = (f32x4){0.f, 0.f, 0.f, 0.f};
  for (int k0 = 0; k0 < 256; k0 += 32) {
    __syncthreads();
    for (int c = wv; c < 5; c += 4) {
      int i0 = c * 16;
      int l = (l0 - 1 + i0 + lrow + 2048) & 2047;
      GLDS16(A + (size_t)(bbase | l) * 256 + k0 + lseg * 8, &As[i0][0]);
    }
    for (int c = wv; c < 12; c += 4) {
      int i0 = c * 16;
      int tap = c >> 2, brow = (c & 3) * 16;
      GLDS16(W + (size_t)tap * 65536 + (size_t)(bn + brow + lrow) * 256 + k0 + lseg * 8,
             &Bs[i0][0]);
    }
    __syncthreads();
#pragma unroll
    for (int tap = 0; tap < 3; ++tap) {
      short8 af[2], bfr[2];
#pragma unroll
      for (int mt = 0; mt < 2; ++mt)
        af[mt] = *(const short8*)(&As[wm * 32 + mt * 16 + l15 + tap][quad * 8]);
#pragma unroll
      for (int nt = 0; nt < 2; ++nt)
        bfr[nt] = *(const short8*)(&Bs[tap * 64 + wn * 32 + nt * 16 + l15][quad * 8]);
#pragma unroll
      for (int mt = 0; mt < 2; ++mt)
#pragma unroll
        for (int nt = 0; nt < 2; ++nt)
          acc[mt][nt] = __builtin_amdgcn_mfma_f32_16x16x32_bf16(af[mt], bfr[nt],
                                                                acc[mt][nt], 0, 0, 0);
    }
  }
#pragma unroll
  for (int nt = 0; nt < 2; ++nt) {
    int n = bn + wn * 32 + nt * 16 + l15;
    float bv = bias[n];
    float s = 0.f, s2 = 0.f;
#pragma unroll
    for (int mt = 0; mt < 2; ++mt)
#pragma unroll
      for (int r = 0; r < 4; ++r) {
        int m = bm + wm * 32 + mt * 16 + quad * 4 + r;
        float val = acc[mt][nt][r] + bv;
        C[(size_t)m * 256 + n] = val;
        s += val;
        s2 += val * val;
      }
    s  += __shfl_xor(s, 16);   s  += __shfl_xor(s, 32);
    s2 += __shfl_xor(s2, 16);  s2 += __shfl_xor(s2, 32);
    if (quad == 0) {
      atomicAdd(&stp[n], s);
      atomicAdd(&stp2[n], s2);
    }
  }
}

// ---------------- M scores: wave per (b,l), inline threefry, XCD-affinity swizzle ----------
__global__ __launch_bounds__(256) void m_kernel3(const float* __restrict__ Q,
                                                 const float* __restrict__ K,
                                                 uint32_t k20, uint32_t k21,
                                                 float* __restrict__ M) {
  int bid = blockIdx.x;
  int blk = (bid & 7) * 256 + (bid >> 3);   // XCD-affinity remap (pure perf, no semantics)
  int b = blk >> 9, lc = blk & 511;
  int wave = threadIdx.x >> 6, lane = threadIdx.x & 63;
  int l = lc * 4 + wave;
  int myidx = 0;
  if (lane < UU) {
    int j = l * UU + lane;
    uint32_t o0, o1;
    const int half = (LL * UU) / 2;  // 40960
    if (j < half) {
      threefry2x32(k20, k21, (uint32_t)j, (uint32_t)(j + half), &o0, &o1);
      myidx = (int)(o0 & (LL - 1));
    } else {
      threefry2x32(k20, k21, (uint32_t)(j - half), (uint32_t)j, &o0, &o1);
      myidx = (int)(o1 & (LL - 1));
    }
  }
  float4 q4 = *(const float4*)(Q + ((size_t)(b * LL + l)) * DMM + lane * 4);
  const float* Kb = K + (size_t)b * LL * DMM;
  float mx = -1e30f, sm = 0.f;
#pragma unroll 8
  for (int u = 0; u < UU; ++u) {
    int kidx = __shfl(myidx, u);
    float4 k4 = *(const float4*)(Kb + (size_t)kidx * DMM + lane * 4);
    float s = q4.x * k4.x + q4.y * k4.y + q4.z * k4.z + q4.w * k4.w;
    s += __shfl_xor(s, 1);
    s += __shfl_xor(s, 2);
    s += __shfl_xor(s, 4);
    mx = fmaxf(mx, s);
    sm += s;
  }
  if ((lane & 7) == 0) {
    int h = lane >> 3;
    M[((size_t)(b * HH + h)) * LL + l] = mx - sm * (1.0f / (float)LL);
  }
}

// ---------------- fused topk + split-K flash attention (R18-proven, padded) ---------------
__global__ __launch_bounds__(256) void attn_part(const float* __restrict__ Q,
                                                 const float* __restrict__ K,
                                                 const unsigned short* __restrict__ Vbf,
                                                 const float* __restrict__ M,
                                                 unsigned char* __restrict__ mapb,
                                                 float* __restrict__ pm,
                                                 float* __restrict__ pl,
                                                 float* __restrict__ po) {
  __shared__ __attribute__((aligned(16))) unsigned short QsB[48][32 + KQP];
  __shared__ __attribute__((aligned(16))) unsigned short KsB[KCH][32 + KQP];
  __shared__ __attribute__((aligned(16))) unsigned short ps[48][KCH + PSP];
  __shared__ __attribute__((aligned(16))) unsigned short VsT[EE][KCH + PSP];
  __shared__ int qrows[40];
  __shared__ unsigned int hist[256];
  __shared__ unsigned int sA[256];
  __shared__ unsigned int wtot[4];
  __shared__ unsigned int tbv;
  int kc = blockIdx.x, bh = blockIdx.y;
  int h = bh & 7, b = bh >> 3;
  int tid = threadIdx.x;
  int wv = tid >> 6, lane = tid & 63;
  int l15 = lane & 15, quad = lane >> 4;

  // ---- independent V/K loads issued first (overlap with radix latency) ----
  {
    int row = tid >> 1, half = tid & 1;
    const unsigned short* vsrc =
        Vbf + (size_t)(b * LL + kc * KCH + row) * DMM + h * EE + half * 16;
    unsigned short tv[16];
    *(uint4*)(&tv[0]) = *(const uint4*)vsrc;
    *(uint4*)(&tv[8]) = *(const uint4*)(vsrc + 8);
#pragma unroll
    for (int j = 0; j < 16; ++j) VsT[half * 16 + j][row] = tv[j];
    // K: f32 -> bf16 into B-operand layout [key][dim]
    const float* ksrc = K + ((size_t)(b * LL + kc * KCH + row)) * DMM + h * EE + half * 16;
    unsigned short tk[16];
#pragma unroll
    for (int j = 0; j < 16; ++j) tk[j] = f2b(ksrc[j]);
    *(uint4*)(&KsB[row][half * 16]) = *(const uint4*)(&tk[0]);
    *(uint4*)(&KsB[row][half * 16 + 8]) = *(const uint4*)(&tk[8]);
  }

  // ---- exact top-40 radix select on M[bh]: packed 43-bit keys, 6 rounds (R14-proven) ----
  u64 kreg[8];
#pragma unroll
  for (int r = 0; r < 8; ++r) {
    int l = tid + 256 * r;
    float v = M[(size_t)bh * LL + l];
    uint32_t bits = __float_as_uint(v);
    uint32_t kv = (bits & 0x80000000u) ? ~bits : (bits | 0x80000000u);
    kreg[r] = ((u64)kv << 11) | (uint32_t)(2047 - l);
  }
  u64 prefix = 0;
  int rank = UU;
  for (int round = 0; round < 6; ++round) {
    int shift = 40 - 8 * round;
    u64 maskTop = (round == 0) ? 0ull : (~0ull << (48 - 8 * round));
    hist[tid] = 0;
    __syncthreads();
#pragma unroll
    for (int r = 0; r < 8; ++r) {
      u64 k = kreg[r];
      if ((k & maskTop) == prefix)
        atomicAdd(&hist[(unsigned int)((k >> shift) & 0xFFu)], 1u);
    }
    __syncthreads();
    unsigned int s = hist[tid];
#pragma unroll
    for (int off = 1; off < 64; off <<= 1) {
      unsigned int t = __shfl_down(s, off);
      if (lane + off < 64) s += t;
    }
    if (lane == 0) wtot[wv] = s;
    __syncthreads();
    unsigned int add = 0;
#pragma unroll
    for (int w = 0; w < 4; ++w)
      if (w > wv) add += wtot[w];
    sA[tid] = s + add;
    __syncthreads();
    unsigned int Sb = sA[tid];
    unsigned int Snext = (tid < 255) ? sA[tid + 1] : 0u;
    if (Sb >= (unsigned int)rank && Snext < (unsigned int)rank) tbv = (unsigned int)tid;
    __syncthreads();
    unsigned int tb = tbv;
    unsigned int above = (tb < 255u) ? sA[tb + 1] : 0u;
    rank -= (int)above;
    prefix |= ((u64)tb) << shift;
  }
  u64 T = prefix;   // exact 40th-largest packed key
  // ---- deterministic rank: in-wave prefix + cross-wave totals (exclusive over tid) ----
  int myCnt = 0;
#pragma unroll
  for (int r = 0; r < 8; ++r) myCnt += (kreg[r] >= T) ? 1 : 0;
  {
    unsigned int p = (unsigned int)myCnt;
#pragma unroll
    for (int off = 1; off < 64; off <<= 1) {
      unsigned int t = __shfl_up(p, off);
      if (lane >= off) p += t;
    }
    if (lane == 63) wtot[wv] = p;
    __syncthreads();
    unsigned int addp = 0;
#pragma unroll
    for (int w = 0; w < 4; ++w)
      if (w < wv) addp += wtot[w];
    int pos = (int)(p + addp) - myCnt;   // exclusive prefix
    bool wmap = (kc == 0);
#pragma unroll
    for (int r = 0; r < 8; ++r) {
      u64 k = kreg[r];
      int l = 2047 - (int)(uint32_t)(k & 0x7FFu);
      unsigned char mv = 0;
      if (k >= T) {
        qrows[pos] = l;
        mv = (unsigned char)(pos + 1);
        pos++;
      }
      if (wmap) mapb[bh * 2048 + l] = mv;
    }
  }
  __syncthreads();

  // ---- Q staging (bf16, A-operand layout) for the 40 selected rows; rows 40-47 zero ----
  for (int t = tid; t < 40 * 32; t += 256) {
    int q = t >> 5, d = t & 31;
    QsB[q][d] = f2b(Q[((size_t)(b * LL + qrows[q])) * DMM + h * EE + d]);
  }
  {
    int q = 40 + (tid >> 5), d = tid & 31;
    if (q < 48) QsB[q][d] = 0;   // tid 0..255 covers exactly rows 40..47
  }
  __syncthreads();
  // ---- scores via MFMA: waves 0..2, one 16-q tile x 128 keys each ----
  if (wv < 3) {
    const float scale = 0.17677669529663687f;
    short8 aq = *(const short8*)(&QsB[wv * 16 + l15][quad * 8]);
    f32x4 sacc[8];
#pragma unroll
    for (int nt = 0; nt < 8; ++nt) {
      short8 bk = *(const short8*)(&KsB[nt * 16 + l15][quad * 8]);
      sacc[nt] = __builtin_amdgcn_mfma_f32_16x16x32_bf16(
          aq, bk, (f32x4){0.f, 0.f, 0.f, 0.f}, 0, 0, 0);
    }
#pragma unroll
    for (int nt = 0; nt < 8; ++nt)
#pragma unroll
      for (int r = 0; r < 4; ++r)
        ps[wv * 16 + quad * 4 + r][nt * 16 + l15] = f2b(sacc[nt][r] * scale);
  }
  __syncthreads();
  // ---- softmax (max + exp + sum per row; writes exp back to ps; pm/pl) ----
  for (int qq = 0; qq < 10; ++qq) {
    int q = wv * 10 + qq;
    float mx = fmaxf(bfbits(ps[q][lane]), bfbits(ps[q][lane + 64]));
#pragma unroll
    for (int off = 32; off > 0; off >>= 1) mx = fmaxf(mx, __shfl_xor(mx, off));
    float e0 = expf(bfbits(ps[q][lane]) - mx);
    float e1 = expf(bfbits(ps[q][lane + 64]) - mx);
    ps[q][lane] = f2b(e0);
    ps[q][lane + 64] = f2b(e1);
    float sum = wave_sum(e0 + e1);
    size_t base = ((size_t)bh * UU + q) * KC + kc;
    if (lane == 0) { pm[base] = mx; pl[base] = sum; }
  }
  __syncthreads();
  // ---- PV via MFMA: waves 0..2 each compute one 16-row q-tile x 32 cols (R15-proven) ----
  if (wv < 3) {
    f32x4 pacc[2];
#pragma unroll
    for (int nt = 0; nt < 2; ++nt) pacc[nt] = (f32x4){0.f, 0.f, 0.f, 0.f};
#pragma unroll
    for (int kch = 0; kch < 4; ++kch) {
      short8 af = *(const short8*)(&ps[wv * 16 + l15][kch * 32 + quad * 8]);
#pragma unroll
      for (int nt = 0; nt < 2; ++nt) {
        short8 bfr = *(const short8*)(&VsT[nt * 16 + l15][kch * 32 + quad * 8]);
        pacc[nt] = __builtin_amdgcn_mfma_f32_16x16x32_bf16(af, bfr, pacc[nt], 0, 0, 0);
      }
    }
#pragma unroll
    for (int nt = 0; nt < 2; ++nt) {
      int d = nt * 16 + l15;
#pragma unroll
      for (int r = 0; r < 4; ++r) {
        int q = wv * 16 + quad * 4 + r;
        if (q < UU) {
          size_t base = ((size_t)bh * UU + q) * KC + kc;
          po[base * 32 + d] = pacc[nt][r];
        }
      }
    }
  }
}

// ---------------- bn+elu from atomic stats (bf16 hi+lo out only; +vmp zero) ---------------
__global__ __launch_bounds__(256) void bn_elu(const float* __restrict__ Y,
                                              const float* __restrict__ stp,
                                              const float* __restrict__ stp2,
                                              const float* __restrict__ g,
                                              const float* __restrict__ bb,
                                              unsigned short* __restrict__ XB,
                                              unsigned short* __restrict__ XL,
                                              float* __restrict__ vmpZ) {
  int gid = blockIdx.x * 256 + threadIdx.x;
  if (gid < BB * DMM) vmpZ[gid] = 0.f;
  int d = gid & 255;
  float mean = stp[d] * (1.0f / (float)ROWS);
  float var = stp2[d] * (1.0f / (float)ROWS) - mean * mean;
  float rstd = rsqrtf(var + 1e-5f);
  float v = (Y[gid] - mean) * rstd * g[d] + bb[d];
  float r = v > 0.f ? v : expm1f(v);
  unsigned short hi = f2b(r);
  XB[gid] = hi;
  XL[gid] = f2b(r - bfbits(hi));
}

extern "C" void kernel_launch(void* const* d_in, const int* in_sizes, int n_in,
                              void* d_out, int out_size, void* d_ws, size_t ws_size,
                              hipStream_t stream) {
  (void)in_sizes; (void)n_in; (void)out_size; (void)ws_size;

  // ---- workspace layout (unchanged; some f32 slots now unwritten/dead) ----
  float* xbuf = (float*)d_ws;
  float* kb   = xbuf + NELEM;
  float* qb   = kb + NELEM;   // aliases tmp (Q dead after attn_part)
  float* tmp  = qb;
  float* Mbuf = qb + NELEM;
  float* vmp  = Mbuf + BB * HH * LL;
  float* stp  = vmp + BB * DMM;
  float* stp2 = stp + DMM;
  float* wp   = stp2 + DMM;
  const int wsz[23] = {
      NELEM,
      NLL * DMM * DMM, NLL * DMM,
      NLL * DMM * DMM, NLL * DMM,
      NLL * DMM * DMM, NLL * DMM,
      NLL * DMM * DMM, NLL * DMM,
      NLL * ITR * DMM, NLL * ITR,
      NLL * DMM * ITR, NLL * DMM,
      NLL * DMM, NLL * DMM,
      NLL * DMM, NLL * DMM,
      (NLL - 1) * DMM * DMM * 3, (NLL - 1) * DMM,
      (NLL - 1) * DMM, (NLL - 1) * DMM,
      DMM, DMM
  };
  float* fptr[23];
  fptr[0] = xbuf;
  for (int i = 1; i < 23; ++i) { fptr[i] = wp; wp += wsz[i]; }
  float* pm = wp;
  float* pl = pm + 32 * UU * KC;
  float* po = pl + 32 * UU * KC;
  unsigned short* xbf   = (unsigned short*)(po + 32 * UU * KC * 32);
  unsigned short* xlo   = xbf + NELEM;
  unsigned short* vbf   = xlo + NELEM;
  unsigned short* wqbf  = vbf + NELEM;
  unsigned short* wkbf  = wqbf + NLL * DMM * DMM;
  unsigned short* wvbf  = wkbf + NLL * DMM * DMM;
  unsigned short* wobf  = wvbf + NLL * DMM * DMM;
  unsigned short* dcwT  = wobf + NLL * DMM * DMM;
  u64* cand = (u64*)(dcwT + (NLL - 1) * 3 * DMM * DMM);  // layout kept (unused now)
  int* topb = (int*)(cand + 256 * 40);                    // layout kept (unused now)
  int* flag = topb + BB * HH * UU;
  unsigned char* mapb = (unsigned char*)(flag + 1);  // 32*2048

  // ---- convert (+cheap inline dtype probe, +dcw repack, +vmp zero, +flag publish) ----
  CvtArgs ca;
  int totalBlk = 0;
  for (int i = 0; i < 23; ++i) {
    ca.src[i] = d_in[i];
    ca.dstF[i] = fptr[i];
    ca.dstB[i] = nullptr;
    ca.dstL[i] = nullptr;
    ca.n[i] = wsz[i];
    ca.blkStart[i] = totalBlk;
    totalBlk += (wsz[i] + 255) / 256;
  }
  ca.blkStart[23] = totalBlk;
  // R20: drop dead f32 copies (consumers all use the bf16 versions)
  ca.dstF[0] = nullptr;   // x       -> xbf/xlo
  ca.dstF[1] = nullptr;   // wq      -> wqbf
  ca.dstF[3] = nullptr;   // wk      -> wkbf
  ca.dstF[5] = nullptr;   // wv      -> wvbf
  ca.dstF[7] = nullptr;   // wo      -> wobf
  ca.dstF[17] = nullptr;  // dcw     -> dcwT
  ca.dstB[0] = xbf;  ca.dstL[0] = xlo;
  ca.dstB[1] = wqbf;
  ca.dstB[3] = wkbf;
  ca.dstB[5] = wvbf;
  ca.dstB[7] = wobf;
  ca.dcwT = dcwT;
  ca.vmpZ = vmp;
  ca.flagOut = flag;
  mega_cvt<<<totalBlk + 1, 256, 0, stream>>>(ca);

  dim3 gqkv(ROWS / 128, DMM / 64, 3);
  dim3 g64(ROWS / 64, DMM / 64);

  for (int i = 0; i < NLL; ++i) {
    QKVArgs qa;
    qa.W[0] = wqbf + (size_t)i * DMM * DMM;
    qa.W[1] = wkbf + (size_t)i * DMM * DMM;
    qa.W[2] = wvbf + (size_t)i * DMM * DMM;
    qa.bias[0] = fptr[2] + i * DMM;
    qa.bias[1] = fptr[4] + i * DMM;
    qa.bias[2] = fptr[6] + i * DMM;
    qa.Cq = qb; qa.Ck = kb; qa.Cv = vbf;
    qa.vmp = vmp;
    gemm_qkv<<<gqkv, 256, 0, stream>>>(xbf, xlo, qa);

    uint32_t ki0, ki1, a0, a1, b0, b1;
    threefry2x32(0u, 42u, 0u, (uint32_t)i, &ki0, &ki1);
    threefry2x32(ki0, ki1, 0u, 2u, &a0, &a1);
    threefry2x32(ki0, ki1, 1u, 3u, &b0, &b1);
    (void)a0; (void)b0;

    m_kernel3<<<BB * 512, 256, 0, stream>>>(qb, kb, a1, b1, Mbuf);
    attn_part<<<dim3(KC, BB * HH), 256, 0, stream>>>(qb, kb, vbf, Mbuf, mapb,
                                                     pm, pl, po);

    bool last = (i == NLL - 1);
    oproj_tail<<<ROWS / OTR, 512, 0, stream>>>(
        vmp, mapb, pm, pl, po,
        wobf + (size_t)i * DMM * DMM, fptr[8] + i * DMM,
        xbf, xlo,
        fptr[13] + i * DMM, fptr[14] + i * DMM,
        fptr[9] + (size_t)i * ITR * DMM, fptr[10] + i * ITR,
        fptr[11] + (size_t)i * DMM * ITR, fptr[12] + i * DMM,
        fptr[15] + i * DMM, fptr[16] + i * DMM,
        xbf, xlo,
        fptr[21], fptr[22], last ? d_out : nullptr, flag, stp, stp2);

    if (!last) {
      gemm_conv<<<g64, 256, 0, stream>>>(xbf, dcwT + (size_t)i * 3 * DMM * DMM,
                                         fptr[18] + i * DMM, tmp, stp, stp2);
      bn_elu<<<NELEM / 256, 256, 0, stream>>>(tmp, stp, stp2, fptr[19] + i * DMM,
                                              fptr[20] + i * DMM, xbf, xlo, vmp);
    }
  }
}